// Round 1
// baseline (2050.867 us; speedup 1.0000x reference)
//
#include <hip/hip_runtime.h>
#include <hip/hip_bf16.h>
#include <math.h>

typedef __bf16 bf16;
typedef __bf16 bf16x8 __attribute__((ext_vector_type(8)));
typedef float floatx4 __attribute__((ext_vector_type(4)));

#define BB 2
#define LL 1024
#define DD 768
#define DI 1536
#define MROWS 2048   // B*L
#define NXP 80       // dt_rank + 2*d_state
#define DTRANK 48
#define DSTATE 16

// ---------------------------------------------------------------- cvt f32->bf16
__global__ __launch_bounds__(256) void cvt_k(const float* __restrict__ in,
                                             bf16* __restrict__ out, int n) {
    int i = blockIdx.x * 256 + threadIdx.x;
    if (i < n) out[i] = (bf16)in[i];
}

// ---------------------------------------------------------------- rmsnorm -> bf16
__global__ __launch_bounds__(256) void rmsnorm_k(const float* __restrict__ x,
                                                 const float* __restrict__ w,
                                                 bf16* __restrict__ out) {
    int row = blockIdx.x;
    const float* xr = x + (size_t)row * DD;
    int tid = threadIdx.x;
    float v[3]; float ss = 0.f;
    for (int j = 0; j < 3; j++) { v[j] = xr[tid + j * 256]; ss += v[j] * v[j]; }
    for (int o = 1; o < 64; o <<= 1) ss += __shfl_xor(ss, o, 64);
    __shared__ float sred[4];
    if ((tid & 63) == 0) sred[tid >> 6] = ss;
    __syncthreads();
    float scale = rsqrtf((sred[0] + sred[1] + sred[2] + sred[3]) / (float)DD + 1e-6f);
    for (int j = 0; j < 3; j++) {
        int c = tid + j * 256;
        out[(size_t)row * DD + c] = (bf16)(v[j] * scale * w[c]);
    }
}

// ---------------------------------------------------------------- GEMM: C = A @ W^T
// A: M x K bf16 row-major, W: N x K bf16 row-major. M % 128 == 0. N,K guarded.
// MODE 0: store f32 | MODE 1: store bf16 | MODE 2: +bias, softplus, f32 | MODE 3: +resid, f32
template <int MODE>
__global__ __launch_bounds__(256) void gemm_bt(const bf16* __restrict__ A,
                                               const bf16* __restrict__ W,
                                               float* __restrict__ Cf,
                                               bf16* __restrict__ Cb,
                                               const float* __restrict__ bias,
                                               const float* __restrict__ resid,
                                               int M, int N, int K) {
    __shared__ bf16 As[128][40];
    __shared__ bf16 Ws[128][40];
    const int tid  = threadIdx.x;
    const int m0   = blockIdx.x * 128;
    const int n0   = blockIdx.y * 128;
    const int wave = tid >> 6;
    const int lane = tid & 63;
    const int wm   = (wave >> 1) * 64;
    const int wn   = (wave & 1) * 64;
    const int lrow = lane & 15;
    const int quad = lane >> 4;

    floatx4 acc[4][4];
    for (int mi = 0; mi < 4; mi++)
        for (int ni = 0; ni < 4; ni++) acc[mi][ni] = (floatx4){0.f, 0.f, 0.f, 0.f};

    const int r0  = tid >> 2;        // 0..63
    const int r1  = r0 + 64;         // 64..127
    const int seg = (tid & 3) * 8;   // 0,8,16,24

    for (int kb = 0; kb < K; kb += 32) {
        int gk = kb + seg;
        bf16x8 va0, va1, vb0, vb1;
        {
            const bf16* p0 = A + (size_t)(m0 + r0) * K + gk;
            const bf16* p1 = A + (size_t)(m0 + r1) * K + gk;
            if (gk + 8 <= K) { va0 = *(const bf16x8*)p0; va1 = *(const bf16x8*)p1; }
            else {
                for (int j = 0; j < 8; j++) {
                    bool in = (gk + j) < K;
                    va0[j] = in ? p0[j] : (bf16)0.f;
                    va1[j] = in ? p1[j] : (bf16)0.f;
                }
            }
        }
        {
            int gn0 = n0 + r0, gn1 = n0 + r1;
            const bf16* q0 = W + (size_t)gn0 * K + gk;
            const bf16* q1 = W + (size_t)gn1 * K + gk;
            if (gk + 8 <= K) {
                if (gn0 < N) vb0 = *(const bf16x8*)q0; else for (int j = 0; j < 8; j++) vb0[j] = (bf16)0.f;
                if (gn1 < N) vb1 = *(const bf16x8*)q1; else for (int j = 0; j < 8; j++) vb1[j] = (bf16)0.f;
            } else {
                for (int j = 0; j < 8; j++) {
                    bool in = (gk + j) < K;
                    vb0[j] = (in && gn0 < N) ? q0[j] : (bf16)0.f;
                    vb1[j] = (in && gn1 < N) ? q1[j] : (bf16)0.f;
                }
            }
        }
        __syncthreads();   // previous iteration's LDS reads done
        *(bf16x8*)&As[r0][seg] = va0;
        *(bf16x8*)&As[r1][seg] = va1;
        *(bf16x8*)&Ws[r0][seg] = vb0;
        *(bf16x8*)&Ws[r1][seg] = vb1;
        __syncthreads();
        bf16x8 af[4], wf[4];
        for (int mi = 0; mi < 4; mi++) af[mi] = *(const bf16x8*)&As[wm + mi * 16 + lrow][quad * 8];
        for (int ni = 0; ni < 4; ni++) wf[ni] = *(const bf16x8*)&Ws[wn + ni * 16 + lrow][quad * 8];
        for (int mi = 0; mi < 4; mi++)
            for (int ni = 0; ni < 4; ni++)
                acc[mi][ni] = __builtin_amdgcn_mfma_f32_16x16x32_bf16(af[mi], wf[ni], acc[mi][ni], 0, 0, 0);
    }
    // epilogue: D row = quad*4 + r, col = lrow (verified gfx950 C/D layout)
    for (int mi = 0; mi < 4; mi++) {
        int rowb = m0 + wm + mi * 16 + quad * 4;
        for (int ni = 0; ni < 4; ni++) {
            int col = n0 + wn + ni * 16 + lrow;
            if (col >= N) continue;
            for (int r = 0; r < 4; r++) {
                int row = rowb + r;
                float v = acc[mi][ni][r];
                if constexpr (MODE == 2) {
                    v += bias[col];
                    v = (v > 20.f) ? v : log1pf(__expf(v));
                }
                if constexpr (MODE == 3) { v += resid[(size_t)row * N + col]; }
                if constexpr (MODE == 1) Cb[(size_t)row * N + col] = (bf16)v;
                else                     Cf[(size_t)row * N + col] = v;
            }
        }
    }
}

// ---------------------------------------------------------------- causal depthwise conv + silu
__global__ __launch_bounds__(256) void conv_silu_k(const bf16* __restrict__ xz,
                                                   const float* __restrict__ cw,
                                                   const float* __restrict__ cb,
                                                   float* __restrict__ xc,
                                                   bf16* __restrict__ xcb) {
    int idx = blockIdx.x * 256 + threadIdx.x;
    if (idx >= MROWS * DI) return;
    int d = idx % DI;
    int m = idx / DI;
    int l = m & (LL - 1);
    float acc = cb[d];
    for (int k = 0; k < 4; k++) {
        int lp = l - 3 + k;
        if (lp >= 0) acc += (float)xz[(size_t)(m - 3 + k) * (2 * DI) + d] * cw[d * 4 + k];
    }
    float s = acc / (1.f + __expf(-acc));
    xc[idx]  = s;
    xcb[idx] = (bf16)s;
}

// ---------------------------------------------------------------- dt columns -> bf16 compact
__global__ __launch_bounds__(256) void dtcvt_k(const float* __restrict__ xdbl,
                                               bf16* __restrict__ dtbf) {
    int idx = blockIdx.x * 256 + threadIdx.x;
    if (idx >= MROWS * DTRANK) return;
    int m = idx / DTRANK, c = idx % DTRANK;
    dtbf[idx] = (bf16)xdbl[(size_t)m * NXP + c];
}

// ---------------------------------------------------------------- selective scan + skip + gate
// block: (d-tile of 16) x (b);  256 threads = 16 d_local x 16 n
#define CL 64
__global__ __launch_bounds__(256) void scan_k(const float* __restrict__ delta,
                                              const float* __restrict__ xc,
                                              const bf16* __restrict__ xz,
                                              const float* __restrict__ xdbl,
                                              const float* __restrict__ A_log,
                                              const float* __restrict__ Dskip,
                                              bf16* __restrict__ ybf) {
    int b  = blockIdx.y;
    int d0 = blockIdx.x * 16;
    int tid = threadIdx.x;
    int dl = tid >> 4;
    int n  = tid & 15;
    int d  = d0 + dl;
    float a     = -__expf(A_log[d * DSTATE + n]);
    float dskip = Dskip[d];
    float h = 0.f;
    __shared__ float sdelta[CL][16];
    __shared__ float sxc[CL][16];
    __shared__ float sz[CL][16];
    __shared__ float sbc[CL][32];
    for (int l0 = 0; l0 < LL; l0 += CL) {
        __syncthreads();
        for (int idx = tid; idx < CL * 16; idx += 256) {
            int i = idx >> 4, dd = idx & 15;
            size_t row = (size_t)(b * LL + l0 + i);
            sdelta[i][dd] = delta[row * DI + d0 + dd];
            sxc[i][dd]    = xc[row * DI + d0 + dd];
            sz[i][dd]     = (float)xz[row * (2 * DI) + DI + d0 + dd];
        }
        for (int idx = tid; idx < CL * 32; idx += 256) {
            int i = idx >> 5, c = idx & 31;
            sbc[i][c] = xdbl[(size_t)(b * LL + l0 + i) * NXP + DTRANK + c];
        }
        __syncthreads();
        for (int i = 0; i < CL; i++) {
            float dv = sdelta[i][dl];
            float xv = sxc[i][dl];
            float Bv = sbc[i][n];
            float Cv = sbc[i][16 + n];
            float dA = __expf(dv * a);
            h = dA * h + dv * Bv * xv;
            float yp = h * Cv;
            yp += __shfl_xor(yp, 1, 64);
            yp += __shfl_xor(yp, 2, 64);
            yp += __shfl_xor(yp, 4, 64);
            yp += __shfl_xor(yp, 8, 64);
            if (n == 0) {
                float zv = sz[i][dl];
                float yv = (yp + xv * dskip) * (zv / (1.f + __expf(-zv)));
                ybf[(size_t)(b * LL + l0 + i) * DI + d] = (bf16)yv;
            }
        }
    }
}

// ---------------------------------------------------------------- head (only last token matters)
__global__ __launch_bounds__(256) void head_k(const float* __restrict__ x,
                                              const float* __restrict__ fnw,
                                              const float* __restrict__ h1w,
                                              const float* __restrict__ h1b,
                                              const float* __restrict__ hnw,
                                              const float* __restrict__ h2w,
                                              const float* __restrict__ h2b,
                                              float* __restrict__ out) {
    int b = blockIdx.x;
    int tid = threadIdx.x;
    __shared__ float xn[DD];
    __shared__ float hh[DD];
    __shared__ float sred[4];
    const float* xr = x + ((size_t)b * LL + (LL - 1)) * DD;
    float ss = 0.f;
    for (int c = tid; c < DD; c += 256) { float v = xr[c]; ss += v * v; }
    for (int o = 1; o < 64; o <<= 1) ss += __shfl_xor(ss, o, 64);
    if ((tid & 63) == 0) sred[tid >> 6] = ss;
    __syncthreads();
    float scale = rsqrtf((sred[0] + sred[1] + sred[2] + sred[3]) / (float)DD + 1e-6f);
    for (int c = tid; c < DD; c += 256) xn[c] = xr[c] * scale * fnw[c];
    __syncthreads();
    for (int o = tid; o < DD; o += 256) {
        float acc = h1b[o];
        const float* wrow = h1w + (size_t)o * DD;
        for (int c = 0; c < DD; c++) acc += xn[c] * wrow[c];
        hh[o] = acc;
    }
    __syncthreads();
    float ss2 = 0.f;
    for (int c = tid; c < DD; c += 256) { float v = hh[c]; ss2 += v * v; }
    for (int o = 1; o < 64; o <<= 1) ss2 += __shfl_xor(ss2, o, 64);
    __syncthreads();
    if ((tid & 63) == 0) sred[tid >> 6] = ss2;
    __syncthreads();
    float sc2 = rsqrtf((sred[0] + sred[1] + sred[2] + sred[3]) / (float)DD + 1e-6f);
    for (int c = tid; c < DD; c += 256) {
        float v = hh[c] * sc2 * hnw[c];
        hh[c] = 0.5f * v * (1.f + erff(v * 0.70710678118f));   // exact gelu
    }
    __syncthreads();
    int w = tid >> 6, lane = tid & 63;
    for (int j = w; j < 10; j += 4) {
        float acc = 0.f;
        const float* wrow = h2w + (size_t)j * DD;
        for (int c = lane; c < DD; c += 64) acc += hh[c] * wrow[c];
        for (int o = 1; o < 64; o <<= 1) acc += __shfl_xor(acc, o, 64);
        if (lane == 0) out[b * 10 + j] = acc + h2b[j];
    }
}

// ----------------------------------------------------------------
extern "C" void kernel_launch(void* const* d_in, const int* in_sizes, int n_in,
                              void* d_out, int out_size, void* d_ws, size_t ws_size,
                              hipStream_t stream) {
    const float* x_in      = (const float*)d_in[0];
    const float* norm_w    = (const float*)d_in[1];
    const float* in_proj_w = (const float*)d_in[2];
    const float* conv_w    = (const float*)d_in[3];
    const float* conv_b    = (const float*)d_in[4];
    const float* x_proj_w  = (const float*)d_in[5];
    const float* dt_proj_w = (const float*)d_in[6];
    const float* dt_proj_b = (const float*)d_in[7];
    const float* A_log     = (const float*)d_in[8];
    const float* D_skip    = (const float*)d_in[9];
    const float* out_proj_w= (const float*)d_in[10];
    const float* fnw       = (const float*)d_in[11];
    const float* h1w       = (const float*)d_in[12];
    const float* h1b       = (const float*)d_in[13];
    const float* hnw       = (const float*)d_in[14];
    const float* h2w       = (const float*)d_in[15];
    const float* h2b       = (const float*)d_in[16];
    float* out = (float*)d_out;

    char* ws = (char*)d_ws;
    size_t off = 0;
    auto alloc = [&](size_t bytes) -> void* {
        void* p = ws + off;
        off += (bytes + 255) & ~(size_t)255;
        return p;
    };
    bf16* w_in  = (bf16*)alloc((size_t)4 * 3072 * 768 * 2);
    bf16* w_xp  = (bf16*)alloc((size_t)4 * NXP * DI * 2);
    bf16* w_dt  = (bf16*)alloc((size_t)4 * DI * DTRANK * 2);
    bf16* w_out = (bf16*)alloc((size_t)4 * DD * DI * 2);
    bf16* xn_bf = (bf16*)alloc((size_t)MROWS * DD * 2);
    bf16* xz_bf = (bf16*)alloc((size_t)MROWS * 2 * DI * 2);
    float* xc_f = (float*)alloc((size_t)MROWS * DI * 4);
    bf16* xc_bf = (bf16*)alloc((size_t)MROWS * DI * 2);
    float* xdbl = (float*)alloc((size_t)MROWS * NXP * 4);
    bf16* dt_bf = (bf16*)alloc((size_t)MROWS * DTRANK * 2);
    float* delta= (float*)alloc((size_t)MROWS * DI * 4);
    bf16* y_bf  = (bf16*)alloc((size_t)MROWS * DI * 2);
    float* x_buf= (float*)alloc((size_t)MROWS * DD * 4);

    // convert all weights to bf16 (every call; ws is re-poisoned between calls)
    {
        int n1 = 4 * 3072 * 768;   cvt_k<<<(n1 + 255) / 256, 256, 0, stream>>>(in_proj_w,  w_in,  n1);
        int n2 = 4 * NXP * DI;     cvt_k<<<(n2 + 255) / 256, 256, 0, stream>>>(x_proj_w,   w_xp,  n2);
        int n3 = 4 * DI * DTRANK;  cvt_k<<<(n3 + 255) / 256, 256, 0, stream>>>(dt_proj_w,  w_dt,  n3);
        int n4 = 4 * DD * DI;      cvt_k<<<(n4 + 255) / 256, 256, 0, stream>>>(out_proj_w, w_out, n4);
    }

    for (int i = 0; i < 4; i++) {
        const float* x_src = (i == 0) ? x_in : x_buf;
        // 1. rmsnorm -> bf16
        rmsnorm_k<<<MROWS, 256, 0, stream>>>(x_src, norm_w + i * DD, xn_bf);
        // 2. in_proj: (2048 x 3072) = xn @ in_w^T, bf16 out
        gemm_bt<1><<<dim3(MROWS / 128, 3072 / 128), 256, 0, stream>>>(
            xn_bf, w_in + (size_t)i * 3072 * 768, nullptr, xz_bf, nullptr, nullptr,
            MROWS, 2 * DI, DD);
        // 3. causal conv + silu
        conv_silu_k<<<(MROWS * DI + 255) / 256, 256, 0, stream>>>(
            xz_bf, conv_w + (size_t)i * DI * 4, conv_b + (size_t)i * DI, xc_f, xc_bf);
        // 4. x_proj: (2048 x 80) = xc @ xp_w^T, f32 out
        gemm_bt<0><<<dim3(MROWS / 128, 1), 256, 0, stream>>>(
            xc_bf, w_xp + (size_t)i * NXP * DI, xdbl, nullptr, nullptr, nullptr,
            MROWS, NXP, DI);
        // 5. compact dt -> bf16
        dtcvt_k<<<(MROWS * DTRANK + 255) / 256, 256, 0, stream>>>(xdbl, dt_bf);
        // 6. dt_proj + bias + softplus -> delta
        gemm_bt<2><<<dim3(MROWS / 128, DI / 128), 256, 0, stream>>>(
            dt_bf, w_dt + (size_t)i * DI * DTRANK, delta, nullptr,
            dt_proj_b + (size_t)i * DI, nullptr, MROWS, DI, DTRANK);
        // 7. selective scan + D-skip + silu(z) gate -> y bf16
        scan_k<<<dim3(DI / 16, BB), 256, 0, stream>>>(
            delta, xc_f, xz_bf, xdbl, A_log + (size_t)i * DI * DSTATE,
            D_skip + (size_t)i * DI, y_bf);
        // 8. out_proj + residual -> x_buf
        gemm_bt<3><<<dim3(MROWS / 128, DD / 128), 256, 0, stream>>>(
            y_bf, w_out + (size_t)i * DD * DI, x_buf, nullptr, nullptr, x_src,
            MROWS, DD, DI);
    }

    head_k<<<BB, 256, 0, stream>>>(x_buf, fnw, h1w, h1b, hnw, h2w, h2b, out);
}

// Round 3
// 1160.100 us; speedup vs baseline: 1.7678x; 1.7678x over previous
//
#include <hip/hip_runtime.h>
#include <hip/hip_bf16.h>
#include <math.h>

typedef __bf16 bf16;
typedef __bf16 bf16x8 __attribute__((ext_vector_type(8)));
typedef float floatx4 __attribute__((ext_vector_type(4)));

#define BB 2
#define LL 1024
#define DD 768
#define DI 1536
#define MROWS 2048   // B*L
#define NXP 80       // dt_rank + 2*d_state
#define DTRANK 48
#define DSTATE 16
#define NC 16        // scan chunks
#define CLEN 64      // scan chunk length (NC*CLEN == LL)

// ---------------------------------------------------------------- cvt f32->bf16
__global__ __launch_bounds__(256) void cvt_k(const float* __restrict__ in,
                                             bf16* __restrict__ out, int n) {
    int i = blockIdx.x * 256 + threadIdx.x;
    if (i < n) out[i] = (bf16)in[i];
}

// ---------------------------------------------------------------- rmsnorm -> bf16
__global__ __launch_bounds__(256) void rmsnorm_k(const float* __restrict__ x,
                                                 const float* __restrict__ w,
                                                 bf16* __restrict__ out) {
    int row = blockIdx.x;
    const float* xr = x + (size_t)row * DD;
    int tid = threadIdx.x;
    float v[3]; float ss = 0.f;
    for (int j = 0; j < 3; j++) { v[j] = xr[tid + j * 256]; ss += v[j] * v[j]; }
    for (int o = 1; o < 64; o <<= 1) ss += __shfl_xor(ss, o, 64);
    __shared__ float sred[4];
    if ((tid & 63) == 0) sred[tid >> 6] = ss;
    __syncthreads();
    float scale = rsqrtf((sred[0] + sred[1] + sred[2] + sred[3]) / (float)DD + 1e-6f);
    for (int j = 0; j < 3; j++) {
        int c = tid + j * 256;
        out[(size_t)row * DD + c] = (bf16)(v[j] * scale * w[c]);
    }
}

// ---------------------------------------------------------------- GEMM: C = A @ W^T
// A: M x K bf16 row-major, W: N x K bf16 row-major. M % 128 == 0. N,K guarded.
// MODE 0: store f32 | MODE 1: store bf16 | MODE 2: +bias, softplus, f32 | MODE 3: +resid, f32
template <int MODE>
__global__ __launch_bounds__(256) void gemm_bt(const bf16* __restrict__ A,
                                               const bf16* __restrict__ W,
                                               float* __restrict__ Cf,
                                               bf16* __restrict__ Cb,
                                               const float* __restrict__ bias,
                                               const float* __restrict__ resid,
                                               int M, int N, int K) {
    __shared__ bf16 As[128][40];
    __shared__ bf16 Ws[128][40];
    const int tid  = threadIdx.x;
    const int m0   = blockIdx.x * 128;
    const int n0   = blockIdx.y * 128;
    const int wave = tid >> 6;
    const int lane = tid & 63;
    const int wm   = (wave >> 1) * 64;
    const int wn   = (wave & 1) * 64;
    const int lrow = lane & 15;
    const int quad = lane >> 4;

    floatx4 acc[4][4];
    for (int mi = 0; mi < 4; mi++)
        for (int ni = 0; ni < 4; ni++) acc[mi][ni] = (floatx4){0.f, 0.f, 0.f, 0.f};

    const int r0  = tid >> 2;        // 0..63
    const int r1  = r0 + 64;         // 64..127
    const int seg = (tid & 3) * 8;   // 0,8,16,24

    for (int kb = 0; kb < K; kb += 32) {
        int gk = kb + seg;
        bf16x8 va0, va1, vb0, vb1;
        {
            const bf16* p0 = A + (size_t)(m0 + r0) * K + gk;
            const bf16* p1 = A + (size_t)(m0 + r1) * K + gk;
            if (gk + 8 <= K) { va0 = *(const bf16x8*)p0; va1 = *(const bf16x8*)p1; }
            else {
                for (int j = 0; j < 8; j++) {
                    bool in = (gk + j) < K;
                    va0[j] = in ? p0[j] : (bf16)0.f;
                    va1[j] = in ? p1[j] : (bf16)0.f;
                }
            }
        }
        {
            int gn0 = n0 + r0, gn1 = n0 + r1;
            const bf16* q0 = W + (size_t)gn0 * K + gk;
            const bf16* q1 = W + (size_t)gn1 * K + gk;
            if (gk + 8 <= K) {
                if (gn0 < N) vb0 = *(const bf16x8*)q0; else for (int j = 0; j < 8; j++) vb0[j] = (bf16)0.f;
                if (gn1 < N) vb1 = *(const bf16x8*)q1; else for (int j = 0; j < 8; j++) vb1[j] = (bf16)0.f;
            } else {
                for (int j = 0; j < 8; j++) {
                    bool in = (gk + j) < K;
                    vb0[j] = (in && gn0 < N) ? q0[j] : (bf16)0.f;
                    vb1[j] = (in && gn1 < N) ? q1[j] : (bf16)0.f;
                }
            }
        }
        __syncthreads();   // previous iteration's LDS reads done
        *(bf16x8*)&As[r0][seg] = va0;
        *(bf16x8*)&As[r1][seg] = va1;
        *(bf16x8*)&Ws[r0][seg] = vb0;
        *(bf16x8*)&Ws[r1][seg] = vb1;
        __syncthreads();
        bf16x8 af[4], wf[4];
        for (int mi = 0; mi < 4; mi++) af[mi] = *(const bf16x8*)&As[wm + mi * 16 + lrow][quad * 8];
        for (int ni = 0; ni < 4; ni++) wf[ni] = *(const bf16x8*)&Ws[wn + ni * 16 + lrow][quad * 8];
        for (int mi = 0; mi < 4; mi++)
            for (int ni = 0; ni < 4; ni++)
                acc[mi][ni] = __builtin_amdgcn_mfma_f32_16x16x32_bf16(af[mi], wf[ni], acc[mi][ni], 0, 0, 0);
    }
    // epilogue: D row = quad*4 + r, col = lrow (verified gfx950 C/D layout)
    for (int mi = 0; mi < 4; mi++) {
        int rowb = m0 + wm + mi * 16 + quad * 4;
        for (int ni = 0; ni < 4; ni++) {
            int col = n0 + wn + ni * 16 + lrow;
            if (col >= N) continue;
            for (int r = 0; r < 4; r++) {
                int row = rowb + r;
                float v = acc[mi][ni][r];
                if constexpr (MODE == 2) {
                    v += bias[col];
                    v = (v > 20.f) ? v : log1pf(__expf(v));
                }
                if constexpr (MODE == 3) { v += resid[(size_t)row * N + col]; }
                if constexpr (MODE == 1) Cb[(size_t)row * N + col] = (bf16)v;
                else                     Cf[(size_t)row * N + col] = v;
            }
        }
    }
}

// ---------------------------------------------------------------- causal depthwise conv + silu
__global__ __launch_bounds__(256) void conv_silu_k(const bf16* __restrict__ xz,
                                                   const float* __restrict__ cw,
                                                   const float* __restrict__ cb,
                                                   float* __restrict__ xc,
                                                   bf16* __restrict__ xcb) {
    int idx = blockIdx.x * 256 + threadIdx.x;
    if (idx >= MROWS * DI) return;
    int d = idx % DI;
    int m = idx / DI;
    int l = m & (LL - 1);
    float acc = cb[d];
    for (int k = 0; k < 4; k++) {
        int lp = l - 3 + k;
        if (lp >= 0) acc += (float)xz[(size_t)(m - 3 + k) * (2 * DI) + d] * cw[d * 4 + k];
    }
    float s = acc / (1.f + __expf(-acc));
    xc[idx]  = s;
    xcb[idx] = (bf16)s;
}

// ---------------------------------------------------------------- dt columns -> bf16 compact
__global__ __launch_bounds__(256) void dtcvt_k(const float* __restrict__ xdbl,
                                               bf16* __restrict__ dtbf) {
    int idx = blockIdx.x * 256 + threadIdx.x;
    if (idx >= MROWS * DTRANK) return;
    int m = idx / DTRANK, c = idx % DTRANK;
    dtbf[idx] = (bf16)xdbl[(size_t)m * NXP + c];
}

// ---------------------------------------------------------------- chunk-parallel selective scan
// Linear diagonal recurrence h_t = dA_t h_{t-1} + dBu_t composes over chunks:
// chunk transfer h_out = P*h_in + S, with P = exp(a * sum(delta)) closed-form.
// Phase 1: per (chunk, b, d-tile): local scan from 0 -> (P, S).
__global__ __launch_bounds__(256) void scan1_k(const float* __restrict__ delta,
                                               const float* __restrict__ xc,
                                               const float* __restrict__ xdbl,
                                               const float* __restrict__ A_log,
                                               float* __restrict__ Pbuf,
                                               float* __restrict__ Sbuf) {
    int b  = blockIdx.y;
    int d0 = blockIdx.x * 16;
    int c  = blockIdx.z;
    int tid = threadIdx.x;
    int dl = tid >> 4;
    int n  = tid & 15;
    int d  = d0 + dl;
    float a = -__expf(A_log[d * DSTATE + n]);
    __shared__ float sdelta[CLEN][16];
    __shared__ float sxc[CLEN][16];
    __shared__ float sb[CLEN][16];
    int l0 = c * CLEN;
    for (int idx = tid; idx < CLEN * 16; idx += 256) {
        int i = idx >> 4, dd = idx & 15;
        size_t row = (size_t)(b * LL + l0 + i);
        sdelta[i][dd] = delta[row * DI + d0 + dd];
        sxc[i][dd]    = xc[row * DI + d0 + dd];
        sb[i][dd]     = xdbl[row * NXP + DTRANK + dd];   // B-state column dd
    }
    __syncthreads();
    float h = 0.f, sd = 0.f;
    for (int i = 0; i < CLEN; i++) {
        float dv = sdelta[i][dl];
        float xv = sxc[i][dl];
        float Bv = sb[i][n];
        h = __expf(dv * a) * h + dv * Bv * xv;
        sd += dv;
    }
    size_t o = (((size_t)c * BB + b) * DI + d) * DSTATE + n;
    Pbuf[o] = __expf(a * sd);
    Sbuf[o] = h;
}

// Phase 2: compose h_in from previous chunks' (P,S), re-run local scan, emit y.
__global__ __launch_bounds__(256) void scan2_k(const float* __restrict__ delta,
                                               const float* __restrict__ xc,
                                               const bf16* __restrict__ xz,
                                               const float* __restrict__ xdbl,
                                               const float* __restrict__ A_log,
                                               const float* __restrict__ Dskip,
                                               const float* __restrict__ Pbuf,
                                               const float* __restrict__ Sbuf,
                                               bf16* __restrict__ ybf) {
    int b  = blockIdx.y;
    int d0 = blockIdx.x * 16;
    int c  = blockIdx.z;
    int tid = threadIdx.x;
    int dl = tid >> 4;
    int n  = tid & 15;
    int d  = d0 + dl;
    float a     = -__expf(A_log[d * DSTATE + n]);
    float dskip = Dskip[d];
    // compose initial state across preceding chunks (<=15 fma, coalesced loads)
    float h = 0.f;
    {
        size_t stride = (size_t)BB * DI * DSTATE;
        size_t base   = ((size_t)b * DI + d) * DSTATE + n;
        for (int j = 0; j < c; j++)
            h = Pbuf[(size_t)j * stride + base] * h + Sbuf[(size_t)j * stride + base];
    }
    __shared__ float sdelta[CLEN][16];
    __shared__ float sxc[CLEN][16];
    __shared__ float sz[CLEN][16];
    __shared__ float sbc[CLEN][32];
    int l0 = c * CLEN;
    for (int idx = tid; idx < CLEN * 16; idx += 256) {
        int i = idx >> 4, dd = idx & 15;
        size_t row = (size_t)(b * LL + l0 + i);
        sdelta[i][dd] = delta[row * DI + d0 + dd];
        sxc[i][dd]    = xc[row * DI + d0 + dd];
        sz[i][dd]     = (float)xz[row * (2 * DI) + DI + d0 + dd];
    }
    for (int idx = tid; idx < CLEN * 32; idx += 256) {
        int i = idx >> 5, cc = idx & 31;
        sbc[i][cc] = xdbl[(size_t)(b * LL + l0 + i) * NXP + DTRANK + cc];
    }
    __syncthreads();
    for (int i = 0; i < CLEN; i++) {
        float dv = sdelta[i][dl];
        float xv = sxc[i][dl];
        float Bv = sbc[i][n];
        float Cv = sbc[i][16 + n];
        h = __expf(dv * a) * h + dv * Bv * xv;
        float yp = h * Cv;
        yp += __shfl_xor(yp, 1, 64);
        yp += __shfl_xor(yp, 2, 64);
        yp += __shfl_xor(yp, 4, 64);
        yp += __shfl_xor(yp, 8, 64);
        if (n == 0) {
            float zv = sz[i][dl];
            float yv = (yp + xv * dskip) * (zv / (1.f + __expf(-zv)));
            ybf[(size_t)(b * LL + l0 + i) * DI + d] = (bf16)yv;
        }
    }
}

// ---------------------------------------------------------------- head (only last token matters)
__global__ __launch_bounds__(256) void head_k(const float* __restrict__ x,
                                              const float* __restrict__ fnw,
                                              const float* __restrict__ h1w,
                                              const float* __restrict__ h1b,
                                              const float* __restrict__ hnw,
                                              const float* __restrict__ h2w,
                                              const float* __restrict__ h2b,
                                              float* __restrict__ out) {
    int b = blockIdx.x;
    int tid = threadIdx.x;
    __shared__ float xn[DD];
    __shared__ float hh[DD];
    __shared__ float sred[4];
    const float* xr = x + ((size_t)b * LL + (LL - 1)) * DD;
    float ss = 0.f;
    for (int c = tid; c < DD; c += 256) { float v = xr[c]; ss += v * v; }
    for (int o = 1; o < 64; o <<= 1) ss += __shfl_xor(ss, o, 64);
    if ((tid & 63) == 0) sred[tid >> 6] = ss;
    __syncthreads();
    float scale = rsqrtf((sred[0] + sred[1] + sred[2] + sred[3]) / (float)DD + 1e-6f);
    for (int c = tid; c < DD; c += 256) xn[c] = xr[c] * scale * fnw[c];
    __syncthreads();
    for (int o = tid; o < DD; o += 256) {
        float acc = h1b[o];
        const float* wrow = h1w + (size_t)o * DD;
        for (int c = 0; c < DD; c++) acc += xn[c] * wrow[c];
        hh[o] = acc;
    }
    __syncthreads();
    float ss2 = 0.f;
    for (int c = tid; c < DD; c += 256) { float v = hh[c]; ss2 += v * v; }
    for (int o = 1; o < 64; o <<= 1) ss2 += __shfl_xor(ss2, o, 64);
    __syncthreads();
    if ((tid & 63) == 0) sred[tid >> 6] = ss2;
    __syncthreads();
    float sc2 = rsqrtf((sred[0] + sred[1] + sred[2] + sred[3]) / (float)DD + 1e-6f);
    for (int c = tid; c < DD; c += 256) {
        float v = hh[c] * sc2 * hnw[c];
        hh[c] = 0.5f * v * (1.f + erff(v * 0.70710678118f));   // exact gelu
    }
    __syncthreads();
    int w = tid >> 6, lane = tid & 63;
    for (int j = w; j < 10; j += 4) {
        float acc = 0.f;
        const float* wrow = h2w + (size_t)j * DD;
        for (int c = lane; c < DD; c += 64) acc += hh[c] * wrow[c];
        for (int o = 1; o < 64; o <<= 1) acc += __shfl_xor(acc, o, 64);
        if (lane == 0) out[b * 10 + j] = acc + h2b[j];
    }
}

// ----------------------------------------------------------------
extern "C" void kernel_launch(void* const* d_in, const int* in_sizes, int n_in,
                              void* d_out, int out_size, void* d_ws, size_t ws_size,
                              hipStream_t stream) {
    const float* x_in      = (const float*)d_in[0];
    const float* norm_w    = (const float*)d_in[1];
    const float* in_proj_w = (const float*)d_in[2];
    const float* conv_w    = (const float*)d_in[3];
    const float* conv_b    = (const float*)d_in[4];
    const float* x_proj_w  = (const float*)d_in[5];
    const float* dt_proj_w = (const float*)d_in[6];
    const float* dt_proj_b = (const float*)d_in[7];
    const float* A_log     = (const float*)d_in[8];
    const float* D_skip    = (const float*)d_in[9];
    const float* out_proj_w= (const float*)d_in[10];
    const float* fnw       = (const float*)d_in[11];
    const float* h1w       = (const float*)d_in[12];
    const float* h1b       = (const float*)d_in[13];
    const float* hnw       = (const float*)d_in[14];
    const float* h2w       = (const float*)d_in[15];
    const float* h2b       = (const float*)d_in[16];
    float* out = (float*)d_out;

    char* ws = (char*)d_ws;
    size_t off = 0;
    auto alloc = [&](size_t bytes) -> void* {
        void* p = ws + off;
        off += (bytes + 255) & ~(size_t)255;
        return p;
    };
    bf16* w_in  = (bf16*)alloc((size_t)4 * 3072 * 768 * 2);
    bf16* w_xp  = (bf16*)alloc((size_t)4 * NXP * DI * 2);
    bf16* w_dt  = (bf16*)alloc((size_t)4 * DI * DTRANK * 2);
    bf16* w_out = (bf16*)alloc((size_t)4 * DD * DI * 2);
    bf16* xn_bf = (bf16*)alloc((size_t)MROWS * DD * 2);
    bf16* xz_bf = (bf16*)alloc((size_t)MROWS * 2 * DI * 2);
    float* xc_f = (float*)alloc((size_t)MROWS * DI * 4);
    bf16* xc_bf = (bf16*)alloc((size_t)MROWS * DI * 2);
    float* xdbl = (float*)alloc((size_t)MROWS * NXP * 4);
    bf16* dt_bf = (bf16*)alloc((size_t)MROWS * DTRANK * 2);
    float* delta= (float*)alloc((size_t)MROWS * DI * 4);
    bf16* y_bf  = (bf16*)alloc((size_t)MROWS * DI * 2);
    float* x_buf= (float*)alloc((size_t)MROWS * DD * 4);
    float* Pbuf = (float*)alloc((size_t)NC * BB * DI * DSTATE * 4);
    float* Sbuf = (float*)alloc((size_t)NC * BB * DI * DSTATE * 4);

    // convert all weights to bf16 (every call; ws is re-poisoned between calls)
    {
        int n1 = 4 * 3072 * 768;   cvt_k<<<(n1 + 255) / 256, 256, 0, stream>>>(in_proj_w,  w_in,  n1);
        int n2 = 4 * NXP * DI;     cvt_k<<<(n2 + 255) / 256, 256, 0, stream>>>(x_proj_w,   w_xp,  n2);
        int n3 = 4 * DI * DTRANK;  cvt_k<<<(n3 + 255) / 256, 256, 0, stream>>>(dt_proj_w,  w_dt,  n3);
        int n4 = 4 * DD * DI;      cvt_k<<<(n4 + 255) / 256, 256, 0, stream>>>(out_proj_w, w_out, n4);
    }

    for (int i = 0; i < 4; i++) {
        const float* x_src = (i == 0) ? x_in : x_buf;
        // 1. rmsnorm -> bf16
        rmsnorm_k<<<MROWS, 256, 0, stream>>>(x_src, norm_w + i * DD, xn_bf);
        // 2. in_proj: (2048 x 3072) = xn @ in_w^T, bf16 out
        gemm_bt<1><<<dim3(MROWS / 128, 3072 / 128), 256, 0, stream>>>(
            xn_bf, w_in + (size_t)i * 3072 * 768, nullptr, xz_bf, nullptr, nullptr,
            MROWS, 2 * DI, DD);
        // 3. causal conv + silu
        conv_silu_k<<<(MROWS * DI + 255) / 256, 256, 0, stream>>>(
            xz_bf, conv_w + (size_t)i * DI * 4, conv_b + (size_t)i * DI, xc_f, xc_bf);
        // 4. x_proj: (2048 x 80) = xc @ xp_w^T, f32 out
        gemm_bt<0><<<dim3(MROWS / 128, 1), 256, 0, stream>>>(
            xc_bf, w_xp + (size_t)i * NXP * DI, xdbl, nullptr, nullptr, nullptr,
            MROWS, NXP, DI);
        // 5. compact dt -> bf16
        dtcvt_k<<<(MROWS * DTRANK + 255) / 256, 256, 0, stream>>>(xdbl, dt_bf);
        // 6. dt_proj + bias + softplus -> delta
        gemm_bt<2><<<dim3(MROWS / 128, DI / 128), 256, 0, stream>>>(
            dt_bf, w_dt + (size_t)i * DI * DTRANK, delta, nullptr,
            dt_proj_b + (size_t)i * DI, nullptr, MROWS, DI, DTRANK);
        // 7a. chunk-local scans -> (P, S)
        scan1_k<<<dim3(DI / 16, BB, NC), 256, 0, stream>>>(
            delta, xc_f, xdbl, A_log + (size_t)i * DI * DSTATE, Pbuf, Sbuf);
        // 7b. compose + local scan + D-skip + silu(z) gate -> y bf16
        scan2_k<<<dim3(DI / 16, BB, NC), 256, 0, stream>>>(
            delta, xc_f, xz_bf, xdbl, A_log + (size_t)i * DI * DSTATE,
            D_skip + (size_t)i * DI, Pbuf, Sbuf, y_bf);
        // 8. out_proj + residual -> x_buf
        gemm_bt<3><<<dim3(MROWS / 128, DD / 128), 256, 0, stream>>>(
            y_bf, w_out + (size_t)i * DD * DI, x_buf, nullptr, nullptr, x_src,
            MROWS, DD, DI);
    }

    head_k<<<BB, 256, 0, stream>>>(x_buf, fnw, h1w, h1b, hnw, h2w, h2b, out);
}

// Round 4
// 1084.472 us; speedup vs baseline: 1.8911x; 1.0697x over previous
//
#include <hip/hip_runtime.h>
#include <hip/hip_bf16.h>
#include <math.h>

typedef __bf16 bf16;
typedef __bf16 bf16x8 __attribute__((ext_vector_type(8)));
typedef float floatx4 __attribute__((ext_vector_type(4)));

#define BB 2
#define LL 1024
#define DD 768
#define DI 1536
#define MROWS 2048   // B*L
#define NXP 80       // dt_rank + 2*d_state
#define DTRANK 48
#define DSTATE 16
#define NC 16        // scan chunks
#define CLEN 64      // scan chunk length (NC*CLEN == LL)

// ---------------------------------------------------------------- cvt f32->bf16
__global__ __launch_bounds__(256) void cvt_k(const float* __restrict__ in,
                                             bf16* __restrict__ out, int n) {
    int i = blockIdx.x * 256 + threadIdx.x;
    if (i < n) out[i] = (bf16)in[i];
}

// ---------------------------------------------------------------- rmsnorm -> bf16
__global__ __launch_bounds__(256) void rmsnorm_k(const float* __restrict__ x,
                                                 const float* __restrict__ w,
                                                 bf16* __restrict__ out) {
    int row = blockIdx.x;
    const float* xr = x + (size_t)row * DD;
    int tid = threadIdx.x;
    float v[3]; float ss = 0.f;
    for (int j = 0; j < 3; j++) { v[j] = xr[tid + j * 256]; ss += v[j] * v[j]; }
    for (int o = 1; o < 64; o <<= 1) ss += __shfl_xor(ss, o, 64);
    __shared__ float sred[4];
    if ((tid & 63) == 0) sred[tid >> 6] = ss;
    __syncthreads();
    float scale = rsqrtf((sred[0] + sred[1] + sred[2] + sred[3]) / (float)DD + 1e-6f);
    for (int j = 0; j < 3; j++) {
        int c = tid + j * 256;
        out[(size_t)row * DD + c] = (bf16)(v[j] * scale * w[c]);
    }
}

// ---------------------------------------------------------------- GEMM: C = A @ W^T
// A: M x K bf16 row-major, W: N x K bf16 row-major. M % 128 == 0. N,K guarded.
// MODE 0: store f32 | MODE 1: store bf16 | MODE 2: +bias, softplus, f32
// MODE 3: +resid, f32 | MODE 4: f32 + compact bf16 for cols < DTRANK
template <int MODE>
__global__ __launch_bounds__(256) void gemm_bt(const bf16* __restrict__ A,
                                               const bf16* __restrict__ W,
                                               float* __restrict__ Cf,
                                               bf16* __restrict__ Cb,
                                               const float* __restrict__ bias,
                                               const float* __restrict__ resid,
                                               int M, int N, int K) {
    __shared__ bf16 As[128][40];
    __shared__ bf16 Ws[128][40];
    const int tid  = threadIdx.x;
    const int m0   = blockIdx.x * 128;
    const int n0   = blockIdx.y * 128;
    const int wave = tid >> 6;
    const int lane = tid & 63;
    const int wm   = (wave >> 1) * 64;
    const int wn   = (wave & 1) * 64;
    const int lrow = lane & 15;
    const int quad = lane >> 4;

    floatx4 acc[4][4];
    for (int mi = 0; mi < 4; mi++)
        for (int ni = 0; ni < 4; ni++) acc[mi][ni] = (floatx4){0.f, 0.f, 0.f, 0.f};

    const int r0  = tid >> 2;        // 0..63
    const int r1  = r0 + 64;         // 64..127
    const int seg = (tid & 3) * 8;   // 0,8,16,24

    for (int kb = 0; kb < K; kb += 32) {
        int gk = kb + seg;
        bf16x8 va0, va1, vb0, vb1;
        {
            const bf16* p0 = A + (size_t)(m0 + r0) * K + gk;
            const bf16* p1 = A + (size_t)(m0 + r1) * K + gk;
            if (gk + 8 <= K) { va0 = *(const bf16x8*)p0; va1 = *(const bf16x8*)p1; }
            else {
                for (int j = 0; j < 8; j++) {
                    bool in = (gk + j) < K;
                    va0[j] = in ? p0[j] : (bf16)0.f;
                    va1[j] = in ? p1[j] : (bf16)0.f;
                }
            }
        }
        {
            int gn0 = n0 + r0, gn1 = n0 + r1;
            const bf16* q0 = W + (size_t)gn0 * K + gk;
            const bf16* q1 = W + (size_t)gn1 * K + gk;
            if (gk + 8 <= K) {
                if (gn0 < N) vb0 = *(const bf16x8*)q0; else for (int j = 0; j < 8; j++) vb0[j] = (bf16)0.f;
                if (gn1 < N) vb1 = *(const bf16x8*)q1; else for (int j = 0; j < 8; j++) vb1[j] = (bf16)0.f;
            } else {
                for (int j = 0; j < 8; j++) {
                    bool in = (gk + j) < K;
                    vb0[j] = (in && gn0 < N) ? q0[j] : (bf16)0.f;
                    vb1[j] = (in && gn1 < N) ? q1[j] : (bf16)0.f;
                }
            }
        }
        __syncthreads();   // previous iteration's LDS reads done
        *(bf16x8*)&As[r0][seg] = va0;
        *(bf16x8*)&As[r1][seg] = va1;
        *(bf16x8*)&Ws[r0][seg] = vb0;
        *(bf16x8*)&Ws[r1][seg] = vb1;
        __syncthreads();
        bf16x8 af[4], wf[4];
        for (int mi = 0; mi < 4; mi++) af[mi] = *(const bf16x8*)&As[wm + mi * 16 + lrow][quad * 8];
        for (int ni = 0; ni < 4; ni++) wf[ni] = *(const bf16x8*)&Ws[wn + ni * 16 + lrow][quad * 8];
        for (int mi = 0; mi < 4; mi++)
            for (int ni = 0; ni < 4; ni++)
                acc[mi][ni] = __builtin_amdgcn_mfma_f32_16x16x32_bf16(af[mi], wf[ni], acc[mi][ni], 0, 0, 0);
    }
    // epilogue: D row = quad*4 + r, col = lrow (verified gfx950 C/D layout)
    for (int mi = 0; mi < 4; mi++) {
        int rowb = m0 + wm + mi * 16 + quad * 4;
        for (int ni = 0; ni < 4; ni++) {
            int col = n0 + wn + ni * 16 + lrow;
            if (col >= N) continue;
            for (int r = 0; r < 4; r++) {
                int row = rowb + r;
                float v = acc[mi][ni][r];
                if constexpr (MODE == 2) {
                    v += bias[col];
                    v = (v > 20.f) ? v : log1pf(__expf(v));
                }
                if constexpr (MODE == 3) { v += resid[(size_t)row * N + col]; }
                if constexpr (MODE == 1) Cb[(size_t)row * N + col] = (bf16)v;
                else                     Cf[(size_t)row * N + col] = v;
                if constexpr (MODE == 4) {
                    if (col < DTRANK) Cb[(size_t)row * DTRANK + col] = (bf16)v;
                }
            }
        }
    }
}

// ---------------------------------------------------------------- causal depthwise conv + silu
__global__ __launch_bounds__(256) void conv_silu_k(const bf16* __restrict__ xz,
                                                   const float* __restrict__ cw,
                                                   const float* __restrict__ cb,
                                                   float* __restrict__ xc,
                                                   bf16* __restrict__ xcb) {
    int idx = blockIdx.x * 256 + threadIdx.x;
    if (idx >= MROWS * DI) return;
    int d = idx % DI;
    int m = idx / DI;
    int l = m & (LL - 1);
    float acc = cb[d];
    for (int k = 0; k < 4; k++) {
        int lp = l - 3 + k;
        if (lp >= 0) acc += (float)xz[(size_t)(m - 3 + k) * (2 * DI) + d] * cw[d * 4 + k];
    }
    float s = acc / (1.f + __expf(-acc));
    xc[idx]  = s;
    xcb[idx] = (bf16)s;
}

// ---------------------------------------------------------------- chunk-parallel selective scan
// Phase 1: per (chunk, b, d-tile): local scan from 0 -> (P, S), P = exp(a*sum(delta)).
__global__ __launch_bounds__(256) void scan1_k(const float* __restrict__ delta,
                                               const float* __restrict__ xc,
                                               const float* __restrict__ xdbl,
                                               const float* __restrict__ A_log,
                                               float* __restrict__ Pbuf,
                                               float* __restrict__ Sbuf) {
    int b  = blockIdx.y;
    int d0 = blockIdx.x * 16;
    int c  = blockIdx.z;
    int tid = threadIdx.x;
    int dl = tid >> 4;
    int n  = tid & 15;
    int d  = d0 + dl;
    float a = -__expf(A_log[d * DSTATE + n]);
    __shared__ float sdelta[CLEN][16];
    __shared__ float sxc[CLEN][16];
    __shared__ float sb[CLEN][16];
    int l0 = c * CLEN;
    for (int idx = tid; idx < CLEN * 16; idx += 256) {
        int i = idx >> 4, dd = idx & 15;
        size_t row = (size_t)(b * LL + l0 + i);
        sdelta[i][dd] = delta[row * DI + d0 + dd];
        sxc[i][dd]    = xc[row * DI + d0 + dd];
        sb[i][dd]     = xdbl[row * NXP + DTRANK + dd];   // B-state column dd
    }
    __syncthreads();
    float h = 0.f, sd = 0.f;
    for (int i = 0; i < CLEN; i++) {
        float dv = sdelta[i][dl];
        float xv = sxc[i][dl];
        float Bv = sb[i][n];
        h = __expf(dv * a) * h + dv * Bv * xv;
        sd += dv;
    }
    size_t o = (((size_t)c * BB + b) * DI + d) * DSTATE + n;
    Pbuf[o] = __expf(a * sd);
    Sbuf[o] = h;
}

// Phase 2: compose h_in from previous chunks' (P,S), re-run local scan, emit y.
__global__ __launch_bounds__(256) void scan2_k(const float* __restrict__ delta,
                                               const float* __restrict__ xc,
                                               const bf16* __restrict__ xz,
                                               const float* __restrict__ xdbl,
                                               const float* __restrict__ A_log,
                                               const float* __restrict__ Dskip,
                                               const float* __restrict__ Pbuf,
                                               const float* __restrict__ Sbuf,
                                               bf16* __restrict__ ybf) {
    int b  = blockIdx.y;
    int d0 = blockIdx.x * 16;
    int c  = blockIdx.z;
    int tid = threadIdx.x;
    int dl = tid >> 4;
    int n  = tid & 15;
    int d  = d0 + dl;
    float a     = -__expf(A_log[d * DSTATE + n]);
    float dskip = Dskip[d];
    // compose initial state across preceding chunks (<=15 fma, coalesced loads)
    float h = 0.f;
    {
        size_t stride = (size_t)BB * DI * DSTATE;
        size_t base   = ((size_t)b * DI + d) * DSTATE + n;
        for (int j = 0; j < c; j++)
            h = Pbuf[(size_t)j * stride + base] * h + Sbuf[(size_t)j * stride + base];
    }
    __shared__ float sdelta[CLEN][16];
    __shared__ float sxc[CLEN][16];
    __shared__ float sz[CLEN][16];
    __shared__ float sbc[CLEN][32];
    int l0 = c * CLEN;
    for (int idx = tid; idx < CLEN * 16; idx += 256) {
        int i = idx >> 4, dd = idx & 15;
        size_t row = (size_t)(b * LL + l0 + i);
        sdelta[i][dd] = delta[row * DI + d0 + dd];
        sxc[i][dd]    = xc[row * DI + d0 + dd];
        sz[i][dd]     = (float)xz[row * (2 * DI) + DI + d0 + dd];
    }
    for (int idx = tid; idx < CLEN * 32; idx += 256) {
        int i = idx >> 5, cc = idx & 31;
        sbc[i][cc] = xdbl[(size_t)(b * LL + l0 + i) * NXP + DTRANK + cc];
    }
    __syncthreads();
    for (int i = 0; i < CLEN; i++) {
        float dv = sdelta[i][dl];
        float xv = sxc[i][dl];
        float Bv = sbc[i][n];
        float Cv = sbc[i][16 + n];
        h = __expf(dv * a) * h + dv * Bv * xv;
        float yp = h * Cv;
        yp += __shfl_xor(yp, 1, 64);
        yp += __shfl_xor(yp, 2, 64);
        yp += __shfl_xor(yp, 4, 64);
        yp += __shfl_xor(yp, 8, 64);
        if (n == 0) {
            float zv = sz[i][dl];
            float yv = (yp + xv * dskip) * (zv / (1.f + __expf(-zv)));
            ybf[(size_t)(b * LL + l0 + i) * DI + d] = (bf16)yv;
        }
    }
}

// ---------------------------------------------------------------- head, stage 1: final rmsnorm of last token (f32 out)
__global__ __launch_bounds__(256) void head_norm_k(const float* __restrict__ x,
                                                   const float* __restrict__ fnw,
                                                   float* __restrict__ xn_buf) {
    int b = blockIdx.x;
    int tid = threadIdx.x;
    const float* xr = x + ((size_t)b * LL + (LL - 1)) * DD;
    __shared__ float sred[4];
    float v[3]; float ss = 0.f;
    for (int j = 0; j < 3; j++) { v[j] = xr[tid + j * 256]; ss += v[j] * v[j]; }
    for (int o = 1; o < 64; o <<= 1) ss += __shfl_xor(ss, o, 64);
    if ((tid & 63) == 0) sred[tid >> 6] = ss;
    __syncthreads();
    float scale = rsqrtf((sred[0] + sred[1] + sred[2] + sred[3]) / (float)DD + 1e-6f);
    for (int j = 0; j < 3; j++) {
        int c = tid + j * 256;
        xn_buf[(size_t)b * DD + c] = v[j] * scale * fnw[c];
    }
}

// ---------------------------------------------------------------- head, stage 2: h1 matvec (coalesced, wave-per-output)
__global__ __launch_bounds__(256) void head_h1_k(const float* __restrict__ xn_buf,
                                                 const float* __restrict__ h1w,
                                                 const float* __restrict__ h1b,
                                                 float* __restrict__ h_buf) {
    int b  = blockIdx.x;
    int o0 = blockIdx.y * 64;
    int tid = threadIdx.x;
    __shared__ float sx[DD];
    for (int c = tid; c < DD; c += 256) sx[c] = xn_buf[(size_t)b * DD + c];
    __syncthreads();
    int wave = tid >> 6, lane = tid & 63;
    for (int j = 0; j < 16; j++) {
        int o = o0 + wave * 16 + j;
        const float* wrow = h1w + (size_t)o * DD;
        float acc = 0.f;
        for (int k = 0; k < 12; k++) {
            int c = lane + 64 * k;
            acc += wrow[c] * sx[c];
        }
        for (int off = 1; off < 64; off <<= 1) acc += __shfl_xor(acc, off, 64);
        if (lane == 0) h_buf[(size_t)b * DD + o] = acc + h1b[o];
    }
}

// ---------------------------------------------------------------- head, stage 3: rmsnorm + gelu + h2 matvec
__global__ __launch_bounds__(256) void head_out_k(const float* __restrict__ h_buf,
                                                  const float* __restrict__ hnw,
                                                  const float* __restrict__ h2w,
                                                  const float* __restrict__ h2b,
                                                  float* __restrict__ out) {
    int b = blockIdx.x;
    int tid = threadIdx.x;
    __shared__ float hh[DD];
    __shared__ float sred[4];
    const float* hr = h_buf + (size_t)b * DD;
    float ss = 0.f;
    for (int c = tid; c < DD; c += 256) { float v = hr[c]; ss += v * v; }
    for (int o = 1; o < 64; o <<= 1) ss += __shfl_xor(ss, o, 64);
    if ((tid & 63) == 0) sred[tid >> 6] = ss;
    __syncthreads();
    float sc = rsqrtf((sred[0] + sred[1] + sred[2] + sred[3]) / (float)DD + 1e-6f);
    for (int c = tid; c < DD; c += 256) {
        float v = hr[c] * sc * hnw[c];
        hh[c] = 0.5f * v * (1.f + erff(v * 0.70710678118f));   // exact gelu
    }
    __syncthreads();
    int w = tid >> 6, lane = tid & 63;
    for (int j = w; j < 10; j += 4) {
        float acc = 0.f;
        const float* wrow = h2w + (size_t)j * DD;
        for (int c = lane; c < DD; c += 64) acc += hh[c] * wrow[c];
        for (int o = 1; o < 64; o <<= 1) acc += __shfl_xor(acc, o, 64);
        if (lane == 0) out[b * 10 + j] = acc + h2b[j];
    }
}

// ----------------------------------------------------------------
extern "C" void kernel_launch(void* const* d_in, const int* in_sizes, int n_in,
                              void* d_out, int out_size, void* d_ws, size_t ws_size,
                              hipStream_t stream) {
    const float* x_in      = (const float*)d_in[0];
    const float* norm_w    = (const float*)d_in[1];
    const float* in_proj_w = (const float*)d_in[2];
    const float* conv_w    = (const float*)d_in[3];
    const float* conv_b    = (const float*)d_in[4];
    const float* x_proj_w  = (const float*)d_in[5];
    const float* dt_proj_w = (const float*)d_in[6];
    const float* dt_proj_b = (const float*)d_in[7];
    const float* A_log     = (const float*)d_in[8];
    const float* D_skip    = (const float*)d_in[9];
    const float* out_proj_w= (const float*)d_in[10];
    const float* fnw       = (const float*)d_in[11];
    const float* h1w       = (const float*)d_in[12];
    const float* h1b       = (const float*)d_in[13];
    const float* hnw       = (const float*)d_in[14];
    const float* h2w       = (const float*)d_in[15];
    const float* h2b       = (const float*)d_in[16];
    float* out = (float*)d_out;

    char* ws = (char*)d_ws;
    size_t off = 0;
    auto alloc = [&](size_t bytes) -> void* {
        void* p = ws + off;
        off += (bytes + 255) & ~(size_t)255;
        return p;
    };
    bf16* w_in  = (bf16*)alloc((size_t)4 * 3072 * 768 * 2);
    bf16* w_xp  = (bf16*)alloc((size_t)4 * NXP * DI * 2);
    bf16* w_dt  = (bf16*)alloc((size_t)4 * DI * DTRANK * 2);
    bf16* w_out = (bf16*)alloc((size_t)4 * DD * DI * 2);
    bf16* xn_bf = (bf16*)alloc((size_t)MROWS * DD * 2);
    bf16* xz_bf = (bf16*)alloc((size_t)MROWS * 2 * DI * 2);
    float* xc_f = (float*)alloc((size_t)MROWS * DI * 4);
    bf16* xc_bf = (bf16*)alloc((size_t)MROWS * DI * 2);
    float* xdbl = (float*)alloc((size_t)MROWS * NXP * 4);
    bf16* dt_bf = (bf16*)alloc((size_t)MROWS * DTRANK * 2);
    float* delta= (float*)alloc((size_t)MROWS * DI * 4);
    bf16* y_bf  = (bf16*)alloc((size_t)MROWS * DI * 2);
    float* x_buf= (float*)alloc((size_t)MROWS * DD * 4);
    float* Pbuf = (float*)alloc((size_t)NC * BB * DI * DSTATE * 4);
    float* Sbuf = (float*)alloc((size_t)NC * BB * DI * DSTATE * 4);
    float* xnl  = (float*)alloc((size_t)BB * DD * 4);
    float* hbuf = (float*)alloc((size_t)BB * DD * 4);

    // convert all weights to bf16 (every call; ws is re-poisoned between calls)
    {
        int n1 = 4 * 3072 * 768;   cvt_k<<<(n1 + 255) / 256, 256, 0, stream>>>(in_proj_w,  w_in,  n1);
        int n2 = 4 * NXP * DI;     cvt_k<<<(n2 + 255) / 256, 256, 0, stream>>>(x_proj_w,   w_xp,  n2);
        int n3 = 4 * DI * DTRANK;  cvt_k<<<(n3 + 255) / 256, 256, 0, stream>>>(dt_proj_w,  w_dt,  n3);
        int n4 = 4 * DD * DI;      cvt_k<<<(n4 + 255) / 256, 256, 0, stream>>>(out_proj_w, w_out, n4);
    }

    for (int i = 0; i < 4; i++) {
        const float* x_src = (i == 0) ? x_in : x_buf;
        // 1. rmsnorm -> bf16
        rmsnorm_k<<<MROWS, 256, 0, stream>>>(x_src, norm_w + i * DD, xn_bf);
        // 2. in_proj: (2048 x 3072) = xn @ in_w^T, bf16 out
        gemm_bt<1><<<dim3(MROWS / 128, 3072 / 128), 256, 0, stream>>>(
            xn_bf, w_in + (size_t)i * 3072 * 768, nullptr, xz_bf, nullptr, nullptr,
            MROWS, 2 * DI, DD);
        // 3. causal conv + silu
        conv_silu_k<<<(MROWS * DI + 255) / 256, 256, 0, stream>>>(
            xz_bf, conv_w + (size_t)i * DI * 4, conv_b + (size_t)i * DI, xc_f, xc_bf);
        // 4. x_proj: (2048 x 80) = xc @ xp_w^T, f32 out + compact bf16 dt
        gemm_bt<4><<<dim3(MROWS / 128, 1), 256, 0, stream>>>(
            xc_bf, w_xp + (size_t)i * NXP * DI, xdbl, dt_bf, nullptr, nullptr,
            MROWS, NXP, DI);
        // 5. dt_proj + bias + softplus -> delta
        gemm_bt<2><<<dim3(MROWS / 128, DI / 128), 256, 0, stream>>>(
            dt_bf, w_dt + (size_t)i * DI * DTRANK, delta, nullptr,
            dt_proj_b + (size_t)i * DI, nullptr, MROWS, DI, DTRANK);
        // 6a. chunk-local scans -> (P, S)
        scan1_k<<<dim3(DI / 16, BB, NC), 256, 0, stream>>>(
            delta, xc_f, xdbl, A_log + (size_t)i * DI * DSTATE, Pbuf, Sbuf);
        // 6b. compose + local scan + D-skip + silu(z) gate -> y bf16
        scan2_k<<<dim3(DI / 16, BB, NC), 256, 0, stream>>>(
            delta, xc_f, xz_bf, xdbl, A_log + (size_t)i * DI * DSTATE,
            D_skip + (size_t)i * DI, Pbuf, Sbuf, y_bf);
        // 7. out_proj + residual -> x_buf
        gemm_bt<3><<<dim3(MROWS / 128, DD / 128), 256, 0, stream>>>(
            y_bf, w_out + (size_t)i * DD * DI, x_buf, nullptr, nullptr, x_src,
            MROWS, DD, DI);
    }

    head_norm_k<<<BB, 256, 0, stream>>>(x_buf, fnw, xnl);
    head_h1_k<<<dim3(BB, DD / 64), 256, 0, stream>>>(xnl, h1w, h1b, hbuf);
    head_out_k<<<BB, 256, 0, stream>>>(hbuf, hnw, h2w, h2b, out);
}

// Round 5
// 1021.616 us; speedup vs baseline: 2.0075x; 1.0615x over previous
//
#include <hip/hip_runtime.h>
#include <hip/hip_bf16.h>
#include <math.h>

typedef __bf16 bf16;
typedef __bf16 bf16x8 __attribute__((ext_vector_type(8)));
typedef float floatx4 __attribute__((ext_vector_type(4)));

#define BB 2
#define LL 1024
#define DD 768
#define DI 1536
#define MROWS 2048   // B*L
#define NXP 80       // dt_rank + 2*d_state
#define DTRANK 48
#define DSTATE 16
#define NC 16        // scan chunks
#define CLEN 64      // scan chunk length (NC*CLEN == LL)

// DPP row-reduce over 16 lanes (one DPP row): after shr 1/2/4/8 adds, lane 0
// of each 16-lane row holds the row sum. VALU-pipe only (no DS ops).
__device__ __forceinline__ float row16_sum(float x) {
    float t;
    t = __int_as_float(__builtin_amdgcn_update_dpp(0, __float_as_int(x), 0x111, 0xF, 0xF, true)); x += t;
    t = __int_as_float(__builtin_amdgcn_update_dpp(0, __float_as_int(x), 0x112, 0xF, 0xF, true)); x += t;
    t = __int_as_float(__builtin_amdgcn_update_dpp(0, __float_as_int(x), 0x114, 0xF, 0xF, true)); x += t;
    t = __int_as_float(__builtin_amdgcn_update_dpp(0, __float_as_int(x), 0x118, 0xF, 0xF, true)); x += t;
    return x;
}

// ---------------------------------------------------------------- cvt f32->bf16
__global__ __launch_bounds__(256) void cvt_k(const float* __restrict__ in,
                                             bf16* __restrict__ out, int n) {
    int i = blockIdx.x * 256 + threadIdx.x;
    if (i < n) out[i] = (bf16)in[i];
}

// ---------------------------------------------------------------- rmsnorm -> bf16
__global__ __launch_bounds__(256) void rmsnorm_k(const float* __restrict__ x,
                                                 const float* __restrict__ w,
                                                 bf16* __restrict__ out) {
    int row = blockIdx.x;
    const float* xr = x + (size_t)row * DD;
    int tid = threadIdx.x;
    float v[3]; float ss = 0.f;
    for (int j = 0; j < 3; j++) { v[j] = xr[tid + j * 256]; ss += v[j] * v[j]; }
    for (int o = 1; o < 64; o <<= 1) ss += __shfl_xor(ss, o, 64);
    __shared__ float sred[4];
    if ((tid & 63) == 0) sred[tid >> 6] = ss;
    __syncthreads();
    float scale = rsqrtf((sred[0] + sred[1] + sred[2] + sred[3]) / (float)DD + 1e-6f);
    for (int j = 0; j < 3; j++) {
        int c = tid + j * 256;
        out[(size_t)row * DD + c] = (bf16)(v[j] * scale * w[c]);
    }
}

// ---------------------------------------------------------------- GEMM: C = A @ W^T
// A: M x K bf16 row-major, W: N x K bf16 row-major. M % 128 == 0. N,K guarded.
// MODE 0: store f32 | MODE 1: store bf16 | MODE 2: +bias, softplus, f32
// MODE 3: +resid, f32 | MODE 4: f32 + compact bf16 for cols < DTRANK
template <int MODE>
__global__ __launch_bounds__(256) void gemm_bt(const bf16* __restrict__ A,
                                               const bf16* __restrict__ W,
                                               float* __restrict__ Cf,
                                               bf16* __restrict__ Cb,
                                               const float* __restrict__ bias,
                                               const float* __restrict__ resid,
                                               int M, int N, int K) {
    __shared__ bf16 As[128][40];
    __shared__ bf16 Ws[128][40];
    const int tid  = threadIdx.x;
    const int m0   = blockIdx.x * 128;
    const int n0   = blockIdx.y * 128;
    const int wave = tid >> 6;
    const int lane = tid & 63;
    const int wm   = (wave >> 1) * 64;
    const int wn   = (wave & 1) * 64;
    const int lrow = lane & 15;
    const int quad = lane >> 4;

    floatx4 acc[4][4];
    for (int mi = 0; mi < 4; mi++)
        for (int ni = 0; ni < 4; ni++) acc[mi][ni] = (floatx4){0.f, 0.f, 0.f, 0.f};

    const int r0  = tid >> 2;        // 0..63
    const int r1  = r0 + 64;         // 64..127
    const int seg = (tid & 3) * 8;   // 0,8,16,24

    for (int kb = 0; kb < K; kb += 32) {
        int gk = kb + seg;
        bf16x8 va0, va1, vb0, vb1;
        {
            const bf16* p0 = A + (size_t)(m0 + r0) * K + gk;
            const bf16* p1 = A + (size_t)(m0 + r1) * K + gk;
            if (gk + 8 <= K) { va0 = *(const bf16x8*)p0; va1 = *(const bf16x8*)p1; }
            else {
                for (int j = 0; j < 8; j++) {
                    bool in = (gk + j) < K;
                    va0[j] = in ? p0[j] : (bf16)0.f;
                    va1[j] = in ? p1[j] : (bf16)0.f;
                }
            }
        }
        {
            int gn0 = n0 + r0, gn1 = n0 + r1;
            const bf16* q0 = W + (size_t)gn0 * K + gk;
            const bf16* q1 = W + (size_t)gn1 * K + gk;
            if (gk + 8 <= K) {
                if (gn0 < N) vb0 = *(const bf16x8*)q0; else for (int j = 0; j < 8; j++) vb0[j] = (bf16)0.f;
                if (gn1 < N) vb1 = *(const bf16x8*)q1; else for (int j = 0; j < 8; j++) vb1[j] = (bf16)0.f;
            } else {
                for (int j = 0; j < 8; j++) {
                    bool in = (gk + j) < K;
                    vb0[j] = (in && gn0 < N) ? q0[j] : (bf16)0.f;
                    vb1[j] = (in && gn1 < N) ? q1[j] : (bf16)0.f;
                }
            }
        }
        __syncthreads();   // previous iteration's LDS reads done
        *(bf16x8*)&As[r0][seg] = va0;
        *(bf16x8*)&As[r1][seg] = va1;
        *(bf16x8*)&Ws[r0][seg] = vb0;
        *(bf16x8*)&Ws[r1][seg] = vb1;
        __syncthreads();
        bf16x8 af[4], wf[4];
        for (int mi = 0; mi < 4; mi++) af[mi] = *(const bf16x8*)&As[wm + mi * 16 + lrow][quad * 8];
        for (int ni = 0; ni < 4; ni++) wf[ni] = *(const bf16x8*)&Ws[wn + ni * 16 + lrow][quad * 8];
        for (int mi = 0; mi < 4; mi++)
            for (int ni = 0; ni < 4; ni++)
                acc[mi][ni] = __builtin_amdgcn_mfma_f32_16x16x32_bf16(af[mi], wf[ni], acc[mi][ni], 0, 0, 0);
    }
    // epilogue: D row = quad*4 + r, col = lrow (verified gfx950 C/D layout)
    for (int mi = 0; mi < 4; mi++) {
        int rowb = m0 + wm + mi * 16 + quad * 4;
        for (int ni = 0; ni < 4; ni++) {
            int col = n0 + wn + ni * 16 + lrow;
            if (col >= N) continue;
            for (int r = 0; r < 4; r++) {
                int row = rowb + r;
                float v = acc[mi][ni][r];
                if constexpr (MODE == 2) {
                    v += bias[col];
                    v = (v > 20.f) ? v : log1pf(__expf(v));
                }
                if constexpr (MODE == 3) { v += resid[(size_t)row * N + col]; }
                if constexpr (MODE == 1) Cb[(size_t)row * N + col] = (bf16)v;
                else                     Cf[(size_t)row * N + col] = v;
                if constexpr (MODE == 4) {
                    if (col < DTRANK) Cb[(size_t)row * DTRANK + col] = (bf16)v;
                }
            }
        }
    }
}

// ---------------------------------------------------------------- causal depthwise conv + silu
__global__ __launch_bounds__(256) void conv_silu_k(const bf16* __restrict__ xz,
                                                   const float* __restrict__ cw,
                                                   const float* __restrict__ cb,
                                                   float* __restrict__ xc,
                                                   bf16* __restrict__ xcb) {
    int idx = blockIdx.x * 256 + threadIdx.x;
    if (idx >= MROWS * DI) return;
    int d = idx % DI;
    int m = idx / DI;
    int l = m & (LL - 1);
    float acc = cb[d];
    for (int k = 0; k < 4; k++) {
        int lp = l - 3 + k;
        if (lp >= 0) acc += (float)xz[(size_t)(m - 3 + k) * (2 * DI) + d] * cw[d * 4 + k];
    }
    float s = acc / (1.f + __expf(-acc));
    xc[idx]  = s;
    xcb[idx] = (bf16)s;
}

// ---------------------------------------------------------------- chunk-parallel selective scan
// Phase 1: per (chunk, b, d-tile): local scan from 0 -> (P, S), P = exp(a*sum(delta)).
__global__ __launch_bounds__(256) void scan1_k(const float* __restrict__ delta,
                                               const float* __restrict__ xc,
                                               const float* __restrict__ xdbl,
                                               const float* __restrict__ A_log,
                                               float* __restrict__ Pbuf,
                                               float* __restrict__ Sbuf) {
    int b  = blockIdx.y;
    int d0 = blockIdx.x * 16;
    int c  = blockIdx.z;
    int tid = threadIdx.x;
    int dl = tid >> 4;
    int n  = tid & 15;
    int d  = d0 + dl;
    float a = -__expf(A_log[d * DSTATE + n]);
    __shared__ float2 sdx[CLEN][16];   // (delta, xc)
    __shared__ float  sb[CLEN][16];
    int l0 = c * CLEN;
    for (int idx = tid; idx < CLEN * 16; idx += 256) {
        int i = idx >> 4, dd = idx & 15;
        size_t row = (size_t)(b * LL + l0 + i);
        sdx[i][dd] = make_float2(delta[row * DI + d0 + dd], xc[row * DI + d0 + dd]);
        sb[i][dd]  = xdbl[row * NXP + DTRANK + dd];   // B-state column dd
    }
    __syncthreads();
    float h = 0.f, sd = 0.f;
    for (int i = 0; i < CLEN; i++) {
        float2 dx = sdx[i][dl];
        float Bv  = sb[i][n];
        h = __expf(dx.x * a) * h + dx.x * Bv * dx.y;
        sd += dx.x;
    }
    size_t o = (((size_t)c * BB + b) * DI + d) * DSTATE + n;
    Pbuf[o] = __expf(a * sd);
    Sbuf[o] = h;
}

// Phase 2: compose h_in from previous chunks' (P,S), re-run local scan, emit y.
__global__ __launch_bounds__(256) void scan2_k(const float* __restrict__ delta,
                                               const float* __restrict__ xc,
                                               const bf16* __restrict__ xz,
                                               const float* __restrict__ xdbl,
                                               const float* __restrict__ A_log,
                                               const float* __restrict__ Dskip,
                                               const float* __restrict__ Pbuf,
                                               const float* __restrict__ Sbuf,
                                               bf16* __restrict__ ybf) {
    int b  = blockIdx.y;
    int d0 = blockIdx.x * 16;
    int c  = blockIdx.z;
    int tid = threadIdx.x;
    int dl = tid >> 4;
    int n  = tid & 15;
    int d  = d0 + dl;
    float a     = -__expf(A_log[d * DSTATE + n]);
    float dskip = Dskip[d];
    // compose initial state across preceding chunks (<=15 fma, coalesced loads)
    float h = 0.f;
    {
        size_t stride = (size_t)BB * DI * DSTATE;
        size_t base   = ((size_t)b * DI + d) * DSTATE + n;
        for (int j = 0; j < c; j++)
            h = Pbuf[(size_t)j * stride + base] * h + Sbuf[(size_t)j * stride + base];
    }
    __shared__ float4 sdxz[CLEN][16];   // (delta, xc, z, pad)
    __shared__ float2 sbc2[CLEN][16];   // (B_n, C_n)
    int l0 = c * CLEN;
    for (int idx = tid; idx < CLEN * 16; idx += 256) {
        int i = idx >> 4, dd = idx & 15;
        size_t row = (size_t)(b * LL + l0 + i);
        sdxz[i][dd] = make_float4(delta[row * DI + d0 + dd],
                                  xc[row * DI + d0 + dd],
                                  (float)xz[row * (2 * DI) + DI + d0 + dd],
                                  0.f);
        sbc2[i][dd] = make_float2(xdbl[row * NXP + DTRANK + dd],
                                  xdbl[row * NXP + DTRANK + DSTATE + dd]);
    }
    __syncthreads();
    for (int i = 0; i < CLEN; i++) {
        float4 dxz = sdxz[i][dl];
        float2 bc  = sbc2[i][n];
        h = __expf(dxz.x * a) * h + dxz.x * bc.x * dxz.y;
        float yp = row16_sum(h * bc.y);   // DPP reduce, lane n==0 gets sum
        if (n == 0) {
            float zv = dxz.z;
            float yv = (yp + dxz.y * dskip) * (zv / (1.f + __expf(-zv)));
            ybf[(size_t)(b * LL + l0 + i) * DI + d] = (bf16)yv;
        }
    }
}

// ---------------------------------------------------------------- head, stage 1: final rmsnorm of last token (f32 out)
__global__ __launch_bounds__(256) void head_norm_k(const float* __restrict__ x,
                                                   const float* __restrict__ fnw,
                                                   float* __restrict__ xn_buf) {
    int b = blockIdx.x;
    int tid = threadIdx.x;
    const float* xr = x + ((size_t)b * LL + (LL - 1)) * DD;
    __shared__ float sred[4];
    float v[3]; float ss = 0.f;
    for (int j = 0; j < 3; j++) { v[j] = xr[tid + j * 256]; ss += v[j] * v[j]; }
    for (int o = 1; o < 64; o <<= 1) ss += __shfl_xor(ss, o, 64);
    if ((tid & 63) == 0) sred[tid >> 6] = ss;
    __syncthreads();
    float scale = rsqrtf((sred[0] + sred[1] + sred[2] + sred[3]) / (float)DD + 1e-6f);
    for (int j = 0; j < 3; j++) {
        int c = tid + j * 256;
        xn_buf[(size_t)b * DD + c] = v[j] * scale * fnw[c];
    }
}

// ---------------------------------------------------------------- head, stage 2: h1 matvec (coalesced, wave-per-output)
__global__ __launch_bounds__(256) void head_h1_k(const float* __restrict__ xn_buf,
                                                 const float* __restrict__ h1w,
                                                 const float* __restrict__ h1b,
                                                 float* __restrict__ h_buf) {
    int b  = blockIdx.x;
    int o0 = blockIdx.y * 64;
    int tid = threadIdx.x;
    __shared__ float sx[DD];
    for (int c = tid; c < DD; c += 256) sx[c] = xn_buf[(size_t)b * DD + c];
    __syncthreads();
    int wave = tid >> 6, lane = tid & 63;
    for (int j = 0; j < 16; j++) {
        int o = o0 + wave * 16 + j;
        const float* wrow = h1w + (size_t)o * DD;
        float acc = 0.f;
        for (int k = 0; k < 12; k++) {
            int c = lane + 64 * k;
            acc += wrow[c] * sx[c];
        }
        for (int off = 1; off < 64; off <<= 1) acc += __shfl_xor(acc, off, 64);
        if (lane == 0) h_buf[(size_t)b * DD + o] = acc + h1b[o];
    }
}

// ---------------------------------------------------------------- head, stage 3: rmsnorm + gelu + h2 matvec
__global__ __launch_bounds__(256) void head_out_k(const float* __restrict__ h_buf,
                                                  const float* __restrict__ hnw,
                                                  const float* __restrict__ h2w,
                                                  const float* __restrict__ h2b,
                                                  float* __restrict__ out) {
    int b = blockIdx.x;
    int tid = threadIdx.x;
    __shared__ float hh[DD];
    __shared__ float sred[4];
    const float* hr = h_buf + (size_t)b * DD;
    float ss = 0.f;
    for (int c = tid; c < DD; c += 256) { float v = hr[c]; ss += v * v; }
    for (int o = 1; o < 64; o <<= 1) ss += __shfl_xor(ss, o, 64);
    if ((tid & 63) == 0) sred[tid >> 6] = ss;
    __syncthreads();
    float sc = rsqrtf((sred[0] + sred[1] + sred[2] + sred[3]) / (float)DD + 1e-6f);
    for (int c = tid; c < DD; c += 256) {
        float v = hr[c] * sc * hnw[c];
        hh[c] = 0.5f * v * (1.f + erff(v * 0.70710678118f));   // exact gelu
    }
    __syncthreads();
    int w = tid >> 6, lane = tid & 63;
    for (int j = w; j < 10; j += 4) {
        float acc = 0.f;
        const float* wrow = h2w + (size_t)j * DD;
        for (int c = lane; c < DD; c += 64) acc += hh[c] * wrow[c];
        for (int o = 1; o < 64; o <<= 1) acc += __shfl_xor(acc, o, 64);
        if (lane == 0) out[b * 10 + j] = acc + h2b[j];
    }
}

// ----------------------------------------------------------------
extern "C" void kernel_launch(void* const* d_in, const int* in_sizes, int n_in,
                              void* d_out, int out_size, void* d_ws, size_t ws_size,
                              hipStream_t stream) {
    const float* x_in      = (const float*)d_in[0];
    const float* norm_w    = (const float*)d_in[1];
    const float* in_proj_w = (const float*)d_in[2];
    const float* conv_w    = (const float*)d_in[3];
    const float* conv_b    = (const float*)d_in[4];
    const float* x_proj_w  = (const float*)d_in[5];
    const float* dt_proj_w = (const float*)d_in[6];
    const float* dt_proj_b = (const float*)d_in[7];
    const float* A_log     = (const float*)d_in[8];
    const float* D_skip    = (const float*)d_in[9];
    const float* out_proj_w= (const float*)d_in[10];
    const float* fnw       = (const float*)d_in[11];
    const float* h1w       = (const float*)d_in[12];
    const float* h1b       = (const float*)d_in[13];
    const float* hnw       = (const float*)d_in[14];
    const float* h2w       = (const float*)d_in[15];
    const float* h2b       = (const float*)d_in[16];
    float* out = (float*)d_out;

    char* ws = (char*)d_ws;
    size_t off = 0;
    auto alloc = [&](size_t bytes) -> void* {
        void* p = ws + off;
        off += (bytes + 255) & ~(size_t)255;
        return p;
    };
    bf16* w_in  = (bf16*)alloc((size_t)4 * 3072 * 768 * 2);
    bf16* w_xp  = (bf16*)alloc((size_t)4 * NXP * DI * 2);
    bf16* w_dt  = (bf16*)alloc((size_t)4 * DI * DTRANK * 2);
    bf16* w_out = (bf16*)alloc((size_t)4 * DD * DI * 2);
    bf16* xn_bf = (bf16*)alloc((size_t)MROWS * DD * 2);
    bf16* xz_bf = (bf16*)alloc((size_t)MROWS * 2 * DI * 2);
    float* xc_f = (float*)alloc((size_t)MROWS * DI * 4);
    bf16* xc_bf = (bf16*)alloc((size_t)MROWS * DI * 2);
    float* xdbl = (float*)alloc((size_t)MROWS * NXP * 4);
    bf16* dt_bf = (bf16*)alloc((size_t)MROWS * DTRANK * 2);
    float* delta= (float*)alloc((size_t)MROWS * DI * 4);
    bf16* y_bf  = (bf16*)alloc((size_t)MROWS * DI * 2);
    float* x_buf= (float*)alloc((size_t)MROWS * DD * 4);
    float* Pbuf = (float*)alloc((size_t)NC * BB * DI * DSTATE * 4);
    float* Sbuf = (float*)alloc((size_t)NC * BB * DI * DSTATE * 4);
    float* xnl  = (float*)alloc((size_t)BB * DD * 4);
    float* hbuf = (float*)alloc((size_t)BB * DD * 4);

    // convert all weights to bf16 (every call; ws is re-poisoned between calls)
    {
        int n1 = 4 * 3072 * 768;   cvt_k<<<(n1 + 255) / 256, 256, 0, stream>>>(in_proj_w,  w_in,  n1);
        int n2 = 4 * NXP * DI;     cvt_k<<<(n2 + 255) / 256, 256, 0, stream>>>(x_proj_w,   w_xp,  n2);
        int n3 = 4 * DI * DTRANK;  cvt_k<<<(n3 + 255) / 256, 256, 0, stream>>>(dt_proj_w,  w_dt,  n3);
        int n4 = 4 * DD * DI;      cvt_k<<<(n4 + 255) / 256, 256, 0, stream>>>(out_proj_w, w_out, n4);
    }

    for (int i = 0; i < 4; i++) {
        const float* x_src = (i == 0) ? x_in : x_buf;
        // 1. rmsnorm -> bf16
        rmsnorm_k<<<MROWS, 256, 0, stream>>>(x_src, norm_w + i * DD, xn_bf);
        // 2. in_proj: (2048 x 3072) = xn @ in_w^T, bf16 out
        gemm_bt<1><<<dim3(MROWS / 128, 3072 / 128), 256, 0, stream>>>(
            xn_bf, w_in + (size_t)i * 3072 * 768, nullptr, xz_bf, nullptr, nullptr,
            MROWS, 2 * DI, DD);
        // 3. causal conv + silu
        conv_silu_k<<<(MROWS * DI + 255) / 256, 256, 0, stream>>>(
            xz_bf, conv_w + (size_t)i * DI * 4, conv_b + (size_t)i * DI, xc_f, xc_bf);
        // 4. x_proj: (2048 x 80) = xc @ xp_w^T, f32 out + compact bf16 dt
        gemm_bt<4><<<dim3(MROWS / 128, 1), 256, 0, stream>>>(
            xc_bf, w_xp + (size_t)i * NXP * DI, xdbl, dt_bf, nullptr, nullptr,
            MROWS, NXP, DI);
        // 5. dt_proj + bias + softplus -> delta
        gemm_bt<2><<<dim3(MROWS / 128, DI / 128), 256, 0, stream>>>(
            dt_bf, w_dt + (size_t)i * DI * DTRANK, delta, nullptr,
            dt_proj_b + (size_t)i * DI, nullptr, MROWS, DI, DTRANK);
        // 6a. chunk-local scans -> (P, S)
        scan1_k<<<dim3(DI / 16, BB, NC), 256, 0, stream>>>(
            delta, xc_f, xdbl, A_log + (size_t)i * DI * DSTATE, Pbuf, Sbuf);
        // 6b. compose + local scan + D-skip + silu(z) gate -> y bf16
        scan2_k<<<dim3(DI / 16, BB, NC), 256, 0, stream>>>(
            delta, xc_f, xz_bf, xdbl, A_log + (size_t)i * DI * DSTATE,
            D_skip + (size_t)i * DI, Pbuf, Sbuf, y_bf);
        // 7. out_proj + residual -> x_buf
        gemm_bt<3><<<dim3(MROWS / 128, DD / 128), 256, 0, stream>>>(
            y_bf, w_out + (size_t)i * DD * DI, x_buf, nullptr, nullptr, x_src,
            MROWS, DD, DI);
    }

    head_norm_k<<<BB, 256, 0, stream>>>(x_buf, fnw, xnl);
    head_h1_k<<<dim3(BB, DD / 64), 256, 0, stream>>>(xnl, h1w, h1b, hbuf);
    head_out_k<<<BB, 256, 0, stream>>>(hbuf, hnw, h2w, h2b, out);
}

// Round 6
// 973.383 us; speedup vs baseline: 2.1069x; 1.0496x over previous
//
#include <hip/hip_runtime.h>
#include <hip/hip_bf16.h>
#include <math.h>

typedef __bf16 bf16;
typedef __bf16 bf16x8 __attribute__((ext_vector_type(8)));
typedef float floatx4 __attribute__((ext_vector_type(4)));

#define BB 2
#define LL 1024
#define DD 768
#define DI 1536
#define MROWS 2048   // B*L
#define NXP 80       // dt_rank + 2*d_state
#define DTRANK 48
#define DSTATE 16
#define NC 16        // scan chunks
#define CLEN 64      // scan chunk length (NC*CLEN == LL)

// DPP row-reduce over 16 lanes (one DPP row): after shr 1/2/4/8 adds, lane 0
// of each 16-lane row holds the row sum. VALU-pipe only (no DS ops).
__device__ __forceinline__ float row16_sum(float x) {
    float t;
    t = __int_as_float(__builtin_amdgcn_update_dpp(0, __float_as_int(x), 0x111, 0xF, 0xF, true)); x += t;
    t = __int_as_float(__builtin_amdgcn_update_dpp(0, __float_as_int(x), 0x112, 0xF, 0xF, true)); x += t;
    t = __int_as_float(__builtin_amdgcn_update_dpp(0, __float_as_int(x), 0x114, 0xF, 0xF, true)); x += t;
    t = __int_as_float(__builtin_amdgcn_update_dpp(0, __float_as_int(x), 0x118, 0xF, 0xF, true)); x += t;
    return x;
}

// ---------------------------------------------------------------- cvt f32->bf16
__global__ __launch_bounds__(256) void cvt_k(const float* __restrict__ in,
                                             bf16* __restrict__ out, int n) {
    int i = blockIdx.x * 256 + threadIdx.x;
    if (i < n) out[i] = (bf16)in[i];
}

// ---------------------------------------------------------------- rmsnorm -> bf16
__global__ __launch_bounds__(256) void rmsnorm_k(const float* __restrict__ x,
                                                 const float* __restrict__ w,
                                                 bf16* __restrict__ out) {
    int row = blockIdx.x;
    const float* xr = x + (size_t)row * DD;
    int tid = threadIdx.x;
    float v[3]; float ss = 0.f;
    for (int j = 0; j < 3; j++) { v[j] = xr[tid + j * 256]; ss += v[j] * v[j]; }
    for (int o = 1; o < 64; o <<= 1) ss += __shfl_xor(ss, o, 64);
    __shared__ float sred[4];
    if ((tid & 63) == 0) sred[tid >> 6] = ss;
    __syncthreads();
    float scale = rsqrtf((sred[0] + sred[1] + sred[2] + sred[3]) / (float)DD + 1e-6f);
    for (int j = 0; j < 3; j++) {
        int c = tid + j * 256;
        out[(size_t)row * DD + c] = (bf16)(v[j] * scale * w[c]);
    }
}

// ---------------------------------------------------------------- GEMM: C = A @ W^T
// A: M x K bf16 row-major, W: N x K bf16 row-major. M % 128 == 0. N,K guarded.
// MODE 0: store f32 | MODE 1: store bf16 | MODE 2: +bias, softplus, f32
// MODE 3: +resid, f32 | MODE 4: f32 + compact bf16 for cols < DTRANK
template <int MODE>
__global__ __launch_bounds__(256) void gemm_bt(const bf16* __restrict__ A,
                                               const bf16* __restrict__ W,
                                               float* __restrict__ Cf,
                                               bf16* __restrict__ Cb,
                                               const float* __restrict__ bias,
                                               const float* __restrict__ resid,
                                               int M, int N, int K) {
    __shared__ bf16 As[128][40];
    __shared__ bf16 Ws[128][40];
    const int tid  = threadIdx.x;
    const int m0   = blockIdx.x * 128;
    const int n0   = blockIdx.y * 128;
    const int wave = tid >> 6;
    const int lane = tid & 63;
    const int wm   = (wave >> 1) * 64;
    const int wn   = (wave & 1) * 64;
    const int lrow = lane & 15;
    const int quad = lane >> 4;

    floatx4 acc[4][4];
    for (int mi = 0; mi < 4; mi++)
        for (int ni = 0; ni < 4; ni++) acc[mi][ni] = (floatx4){0.f, 0.f, 0.f, 0.f};

    const int r0  = tid >> 2;        // 0..63
    const int r1  = r0 + 64;         // 64..127
    const int seg = (tid & 3) * 8;   // 0,8,16,24

    for (int kb = 0; kb < K; kb += 32) {
        int gk = kb + seg;
        bf16x8 va0, va1, vb0, vb1;
        {
            const bf16* p0 = A + (size_t)(m0 + r0) * K + gk;
            const bf16* p1 = A + (size_t)(m0 + r1) * K + gk;
            if (gk + 8 <= K) { va0 = *(const bf16x8*)p0; va1 = *(const bf16x8*)p1; }
            else {
                for (int j = 0; j < 8; j++) {
                    bool in = (gk + j) < K;
                    va0[j] = in ? p0[j] : (bf16)0.f;
                    va1[j] = in ? p1[j] : (bf16)0.f;
                }
            }
        }
        {
            int gn0 = n0 + r0, gn1 = n0 + r1;
            const bf16* q0 = W + (size_t)gn0 * K + gk;
            const bf16* q1 = W + (size_t)gn1 * K + gk;
            if (gk + 8 <= K) {
                if (gn0 < N) vb0 = *(const bf16x8*)q0; else for (int j = 0; j < 8; j++) vb0[j] = (bf16)0.f;
                if (gn1 < N) vb1 = *(const bf16x8*)q1; else for (int j = 0; j < 8; j++) vb1[j] = (bf16)0.f;
            } else {
                for (int j = 0; j < 8; j++) {
                    bool in = (gk + j) < K;
                    vb0[j] = (in && gn0 < N) ? q0[j] : (bf16)0.f;
                    vb1[j] = (in && gn1 < N) ? q1[j] : (bf16)0.f;
                }
            }
        }
        __syncthreads();   // previous iteration's LDS reads done
        *(bf16x8*)&As[r0][seg] = va0;
        *(bf16x8*)&As[r1][seg] = va1;
        *(bf16x8*)&Ws[r0][seg] = vb0;
        *(bf16x8*)&Ws[r1][seg] = vb1;
        __syncthreads();
        bf16x8 af[4], wf[4];
        for (int mi = 0; mi < 4; mi++) af[mi] = *(const bf16x8*)&As[wm + mi * 16 + lrow][quad * 8];
        for (int ni = 0; ni < 4; ni++) wf[ni] = *(const bf16x8*)&Ws[wn + ni * 16 + lrow][quad * 8];
        for (int mi = 0; mi < 4; mi++)
            for (int ni = 0; ni < 4; ni++)
                acc[mi][ni] = __builtin_amdgcn_mfma_f32_16x16x32_bf16(af[mi], wf[ni], acc[mi][ni], 0, 0, 0);
    }
    // epilogue: D row = quad*4 + r, col = lrow (verified gfx950 C/D layout)
    for (int mi = 0; mi < 4; mi++) {
        int rowb = m0 + wm + mi * 16 + quad * 4;
        for (int ni = 0; ni < 4; ni++) {
            int col = n0 + wn + ni * 16 + lrow;
            if (col >= N) continue;
            for (int r = 0; r < 4; r++) {
                int row = rowb + r;
                float v = acc[mi][ni][r];
                if constexpr (MODE == 2) {
                    v += bias[col];
                    v = (v > 20.f) ? v : log1pf(__expf(v));
                }
                if constexpr (MODE == 3) { v += resid[(size_t)row * N + col]; }
                if constexpr (MODE == 1) Cb[(size_t)row * N + col] = (bf16)v;
                else                     Cf[(size_t)row * N + col] = v;
                if constexpr (MODE == 4) {
                    if (col < DTRANK) Cb[(size_t)row * DTRANK + col] = (bf16)v;
                }
            }
        }
    }
}

// ---------------------------------------------------------------- causal depthwise conv + silu + gate precompute
__global__ __launch_bounds__(256) void conv_silu_k(const bf16* __restrict__ xz,
                                                   const float* __restrict__ cw,
                                                   const float* __restrict__ cb,
                                                   float* __restrict__ xc,
                                                   bf16* __restrict__ xcb,
                                                   float* __restrict__ gz) {
    int idx = blockIdx.x * 256 + threadIdx.x;
    if (idx >= MROWS * DI) return;
    int d = idx % DI;
    int m = idx / DI;
    int l = m & (LL - 1);
    float acc = cb[d];
    for (int k = 0; k < 4; k++) {
        int lp = l - 3 + k;
        if (lp >= 0) acc += (float)xz[(size_t)(m - 3 + k) * (2 * DI) + d] * cw[d * 4 + k];
    }
    float s = acc / (1.f + __expf(-acc));
    xc[idx]  = s;
    xcb[idx] = (bf16)s;
    // silu(z) gate, hoisted out of the scan's serial loop (saves exp+div per step)
    float zv = (float)xz[(size_t)m * (2 * DI) + DI + d];
    gz[idx] = zv / (1.f + __expf(-zv));
}

// ---------------------------------------------------------------- chunk-parallel selective scan
// Phase 1: per (chunk, b, d-tile): local scan from 0 -> (P, S), P = exp(a*sum(delta)).
__global__ __launch_bounds__(256) void scan1_k(const float* __restrict__ delta,
                                               const float* __restrict__ xc,
                                               const float* __restrict__ xdbl,
                                               const float* __restrict__ A_log,
                                               float* __restrict__ Pbuf,
                                               float* __restrict__ Sbuf) {
    int b  = blockIdx.y;
    int d0 = blockIdx.x * 16;
    int c  = blockIdx.z;
    int tid = threadIdx.x;
    int dl = tid >> 4;
    int n  = tid & 15;
    int d  = d0 + dl;
    float a = -__expf(A_log[d * DSTATE + n]);
    __shared__ float2 sdx[CLEN][16];   // (delta, xc)
    __shared__ float  sb[CLEN][16];
    int l0 = c * CLEN;
    for (int idx = tid; idx < CLEN * 16; idx += 256) {
        int i = idx >> 4, dd = idx & 15;
        size_t row = (size_t)(b * LL + l0 + i);
        sdx[i][dd] = make_float2(delta[row * DI + d0 + dd], xc[row * DI + d0 + dd]);
        sb[i][dd]  = xdbl[row * NXP + DTRANK + dd];   // B-state column dd
    }
    __syncthreads();
    float h = 0.f, sd = 0.f;
    for (int i = 0; i < CLEN; i++) {
        float2 dx = sdx[i][dl];
        float Bv  = sb[i][n];
        h = __expf(dx.x * a) * h + dx.x * Bv * dx.y;
        sd += dx.x;
    }
    size_t o = (((size_t)c * BB + b) * DI + d) * DSTATE + n;
    Pbuf[o] = __expf(a * sd);
    Sbuf[o] = h;
}

// Phase 2: compose h_in from previous chunks' (P,S), re-run local scan, emit y.
__global__ __launch_bounds__(256) void scan2_k(const float* __restrict__ delta,
                                               const float* __restrict__ xc,
                                               const float* __restrict__ gz,
                                               const float* __restrict__ xdbl,
                                               const float* __restrict__ A_log,
                                               const float* __restrict__ Dskip,
                                               const float* __restrict__ Pbuf,
                                               const float* __restrict__ Sbuf,
                                               bf16* __restrict__ ybf) {
    int b  = blockIdx.y;
    int d0 = blockIdx.x * 16;
    int c  = blockIdx.z;
    int tid = threadIdx.x;
    int dl = tid >> 4;
    int n  = tid & 15;
    int d  = d0 + dl;
    float a     = -__expf(A_log[d * DSTATE + n]);
    float dskip = Dskip[d];
    // compose initial state across preceding chunks (<=15 fma, coalesced loads)
    float h = 0.f;
    {
        size_t stride = (size_t)BB * DI * DSTATE;
        size_t base   = ((size_t)b * DI + d) * DSTATE + n;
        for (int j = 0; j < c; j++)
            h = Pbuf[(size_t)j * stride + base] * h + Sbuf[(size_t)j * stride + base];
    }
    __shared__ float4 sdxz[CLEN][16];   // (delta, xc, gz, pad)
    __shared__ float2 sbc2[CLEN][16];   // (B_n, C_n)
    int l0 = c * CLEN;
    for (int idx = tid; idx < CLEN * 16; idx += 256) {
        int i = idx >> 4, dd = idx & 15;
        size_t row = (size_t)(b * LL + l0 + i);
        sdxz[i][dd] = make_float4(delta[row * DI + d0 + dd],
                                  xc[row * DI + d0 + dd],
                                  gz[row * DI + d0 + dd],
                                  0.f);
        sbc2[i][dd] = make_float2(xdbl[row * NXP + DTRANK + dd],
                                  xdbl[row * NXP + DTRANK + DSTATE + dd]);
    }
    __syncthreads();
    for (int i = 0; i < CLEN; i++) {
        float4 dxz = sdxz[i][dl];
        float2 bc  = sbc2[i][n];
        h = __expf(dxz.x * a) * h + dxz.x * bc.x * dxz.y;
        float yp = row16_sum(h * bc.y);   // DPP reduce, lane n==0 gets sum
        if (n == 0) {
            float yv = (yp + dxz.y * dskip) * dxz.z;   // gate precomputed
            ybf[(size_t)(b * LL + l0 + i) * DI + d] = (bf16)yv;
        }
    }
}

// ---------------------------------------------------------------- head, stage 1: final rmsnorm of last token (f32 out)
__global__ __launch_bounds__(256) void head_norm_k(const float* __restrict__ x,
                                                   const float* __restrict__ fnw,
                                                   float* __restrict__ xn_buf) {
    int b = blockIdx.x;
    int tid = threadIdx.x;
    const float* xr = x + ((size_t)b * LL + (LL - 1)) * DD;
    __shared__ float sred[4];
    float v[3]; float ss = 0.f;
    for (int j = 0; j < 3; j++) { v[j] = xr[tid + j * 256]; ss += v[j] * v[j]; }
    for (int o = 1; o < 64; o <<= 1) ss += __shfl_xor(ss, o, 64);
    if ((tid & 63) == 0) sred[tid >> 6] = ss;
    __syncthreads();
    float scale = rsqrtf((sred[0] + sred[1] + sred[2] + sred[3]) / (float)DD + 1e-6f);
    for (int j = 0; j < 3; j++) {
        int c = tid + j * 256;
        xn_buf[(size_t)b * DD + c] = v[j] * scale * fnw[c];
    }
}

// ---------------------------------------------------------------- head, stage 2: h1 matvec (coalesced, wave-per-output)
__global__ __launch_bounds__(256) void head_h1_k(const float* __restrict__ xn_buf,
                                                 const float* __restrict__ h1w,
                                                 const float* __restrict__ h1b,
                                                 float* __restrict__ h_buf) {
    int b  = blockIdx.x;
    int o0 = blockIdx.y * 64;
    int tid = threadIdx.x;
    __shared__ float sx[DD];
    for (int c = tid; c < DD; c += 256) sx[c] = xn_buf[(size_t)b * DD + c];
    __syncthreads();
    int wave = tid >> 6, lane = tid & 63;
    for (int j = 0; j < 16; j++) {
        int o = o0 + wave * 16 + j;
        const float* wrow = h1w + (size_t)o * DD;
        float acc = 0.f;
        for (int k = 0; k < 12; k++) {
            int c = lane + 64 * k;
            acc += wrow[c] * sx[c];
        }
        for (int off = 1; off < 64; off <<= 1) acc += __shfl_xor(acc, off, 64);
        if (lane == 0) h_buf[(size_t)b * DD + o] = acc + h1b[o];
    }
}

// ---------------------------------------------------------------- head, stage 3: rmsnorm + gelu + h2 matvec
__global__ __launch_bounds__(256) void head_out_k(const float* __restrict__ h_buf,
                                                  const float* __restrict__ hnw,
                                                  const float* __restrict__ h2w,
                                                  const float* __restrict__ h2b,
                                                  float* __restrict__ out) {
    int b = blockIdx.x;
    int tid = threadIdx.x;
    __shared__ float hh[DD];
    __shared__ float sred[4];
    const float* hr = h_buf + (size_t)b * DD;
    float ss = 0.f;
    for (int c = tid; c < DD; c += 256) { float v = hr[c]; ss += v * v; }
    for (int o = 1; o < 64; o <<= 1) ss += __shfl_xor(ss, o, 64);
    if ((tid & 63) == 0) sred[tid >> 6] = ss;
    __syncthreads();
    float sc = rsqrtf((sred[0] + sred[1] + sred[2] + sred[3]) / (float)DD + 1e-6f);
    for (int c = tid; c < DD; c += 256) {
        float v = hr[c] * sc * hnw[c];
        hh[c] = 0.5f * v * (1.f + erff(v * 0.70710678118f));   // exact gelu
    }
    __syncthreads();
    int w = tid >> 6, lane = tid & 63;
    for (int j = w; j < 10; j += 4) {
        float acc = 0.f;
        const float* wrow = h2w + (size_t)j * DD;
        for (int c = lane; c < DD; c += 64) acc += hh[c] * wrow[c];
        for (int o = 1; o < 64; o <<= 1) acc += __shfl_xor(acc, o, 64);
        if (lane == 0) out[b * 10 + j] = acc + h2b[j];
    }
}

// ----------------------------------------------------------------
extern "C" void kernel_launch(void* const* d_in, const int* in_sizes, int n_in,
                              void* d_out, int out_size, void* d_ws, size_t ws_size,
                              hipStream_t stream) {
    const float* x_in      = (const float*)d_in[0];
    const float* norm_w    = (const float*)d_in[1];
    const float* in_proj_w = (const float*)d_in[2];
    const float* conv_w    = (const float*)d_in[3];
    const float* conv_b    = (const float*)d_in[4];
    const float* x_proj_w  = (const float*)d_in[5];
    const float* dt_proj_w = (const float*)d_in[6];
    const float* dt_proj_b = (const float*)d_in[7];
    const float* A_log     = (const float*)d_in[8];
    const float* D_skip    = (const float*)d_in[9];
    const float* out_proj_w= (const float*)d_in[10];
    const float* fnw       = (const float*)d_in[11];
    const float* h1w       = (const float*)d_in[12];
    const float* h1b       = (const float*)d_in[13];
    const float* hnw       = (const float*)d_in[14];
    const float* h2w       = (const float*)d_in[15];
    const float* h2b       = (const float*)d_in[16];
    float* out = (float*)d_out;

    char* ws = (char*)d_ws;
    size_t off = 0;
    auto alloc = [&](size_t bytes) -> void* {
        void* p = ws + off;
        off += (bytes + 255) & ~(size_t)255;
        return p;
    };
    bf16* w_in  = (bf16*)alloc((size_t)4 * 3072 * 768 * 2);
    bf16* w_xp  = (bf16*)alloc((size_t)4 * NXP * DI * 2);
    bf16* w_dt  = (bf16*)alloc((size_t)4 * DI * DTRANK * 2);
    bf16* w_out = (bf16*)alloc((size_t)4 * DD * DI * 2);
    bf16* xn_bf = (bf16*)alloc((size_t)MROWS * DD * 2);
    bf16* xz_bf = (bf16*)alloc((size_t)MROWS * 2 * DI * 2);
    float* xc_f = (float*)alloc((size_t)MROWS * DI * 4);
    bf16* xc_bf = (bf16*)alloc((size_t)MROWS * DI * 2);
    float* gz_f = (float*)alloc((size_t)MROWS * DI * 4);
    float* xdbl = (float*)alloc((size_t)MROWS * NXP * 4);
    bf16* dt_bf = (bf16*)alloc((size_t)MROWS * DTRANK * 2);
    float* delta= (float*)alloc((size_t)MROWS * DI * 4);
    bf16* y_bf  = (bf16*)alloc((size_t)MROWS * DI * 2);
    float* x_buf= (float*)alloc((size_t)MROWS * DD * 4);
    float* Pbuf = (float*)alloc((size_t)NC * BB * DI * DSTATE * 4);
    float* Sbuf = (float*)alloc((size_t)NC * BB * DI * DSTATE * 4);
    float* xnl  = (float*)alloc((size_t)BB * DD * 4);
    float* hbuf = (float*)alloc((size_t)BB * DD * 4);

    // convert all weights to bf16 (every call; ws is re-poisoned between calls)
    {
        int n1 = 4 * 3072 * 768;   cvt_k<<<(n1 + 255) / 256, 256, 0, stream>>>(in_proj_w,  w_in,  n1);
        int n2 = 4 * NXP * DI;     cvt_k<<<(n2 + 255) / 256, 256, 0, stream>>>(x_proj_w,   w_xp,  n2);
        int n3 = 4 * DI * DTRANK;  cvt_k<<<(n3 + 255) / 256, 256, 0, stream>>>(dt_proj_w,  w_dt,  n3);
        int n4 = 4 * DD * DI;      cvt_k<<<(n4 + 255) / 256, 256, 0, stream>>>(out_proj_w, w_out, n4);
    }

    for (int i = 0; i < 4; i++) {
        const float* x_src = (i == 0) ? x_in : x_buf;
        // 1. rmsnorm -> bf16
        rmsnorm_k<<<MROWS, 256, 0, stream>>>(x_src, norm_w + i * DD, xn_bf);
        // 2. in_proj: (2048 x 3072) = xn @ in_w^T, bf16 out
        gemm_bt<1><<<dim3(MROWS / 128, 3072 / 128), 256, 0, stream>>>(
            xn_bf, w_in + (size_t)i * 3072 * 768, nullptr, xz_bf, nullptr, nullptr,
            MROWS, 2 * DI, DD);
        // 3. causal conv + silu + silu(z) gate precompute
        conv_silu_k<<<(MROWS * DI + 255) / 256, 256, 0, stream>>>(
            xz_bf, conv_w + (size_t)i * DI * 4, conv_b + (size_t)i * DI, xc_f, xc_bf, gz_f);
        // 4. x_proj: (2048 x 80) = xc @ xp_w^T, f32 out + compact bf16 dt
        gemm_bt<4><<<dim3(MROWS / 128, 1), 256, 0, stream>>>(
            xc_bf, w_xp + (size_t)i * NXP * DI, xdbl, dt_bf, nullptr, nullptr,
            MROWS, NXP, DI);
        // 5. dt_proj + bias + softplus -> delta
        gemm_bt<2><<<dim3(MROWS / 128, DI / 128), 256, 0, stream>>>(
            dt_bf, w_dt + (size_t)i * DI * DTRANK, delta, nullptr,
            dt_proj_b + (size_t)i * DI, nullptr, MROWS, DI, DTRANK);
        // 6a. chunk-local scans -> (P, S)
        scan1_k<<<dim3(DI / 16, BB, NC), 256, 0, stream>>>(
            delta, xc_f, xdbl, A_log + (size_t)i * DI * DSTATE, Pbuf, Sbuf);
        // 6b. compose + local scan + D-skip + precomputed gate -> y bf16
        scan2_k<<<dim3(DI / 16, BB, NC), 256, 0, stream>>>(
            delta, xc_f, gz_f, xdbl, A_log + (size_t)i * DI * DSTATE,
            D_skip + (size_t)i * DI, Pbuf, Sbuf, y_bf);
        // 7. out_proj + residual -> x_buf
        gemm_bt<3><<<dim3(MROWS / 128, DD / 128), 256, 0, stream>>>(
            y_bf, w_out + (size_t)i * DD * DI, x_buf, nullptr, nullptr, x_src,
            MROWS, DD, DI);
    }

    head_norm_k<<<BB, 256, 0, stream>>>(x_buf, fnw, xnl);
    head_h1_k<<<dim3(BB, DD / 64), 256, 0, stream>>>(xnl, h1w, h1b, hbuf);
    head_out_k<<<BB, 256, 0, stream>>>(hbuf, hnw, h2w, h2b, out);
}

// Round 7
// 874.015 us; speedup vs baseline: 2.3465x; 1.1137x over previous
//
#include <hip/hip_runtime.h>
#include <hip/hip_bf16.h>
#include <math.h>

typedef __bf16 bf16;
typedef __bf16 bf16x8 __attribute__((ext_vector_type(8)));
typedef float floatx4 __attribute__((ext_vector_type(4)));

#define BB 2
#define LL 1024
#define DD 768
#define DI 1536
#define MROWS 2048   // B*L
#define NXP 80       // dt_rank + 2*d_state
#define DTRANK 48
#define DSTATE 16
#define NC 16        // scan chunks
#define CLEN 64      // scan chunk length (NC*CLEN == LL)
#define KSPLIT 16    // x_proj split-K factor (K-seg = 96)

// DPP row-reduce over 16 lanes (one DPP row): after shr 1/2/4/8 adds, lane 0
// of each 16-lane row holds the row sum. VALU-pipe only (no DS ops).
__device__ __forceinline__ float row16_sum(float x) {
    float t;
    t = __int_as_float(__builtin_amdgcn_update_dpp(0, __float_as_int(x), 0x111, 0xF, 0xF, true)); x += t;
    t = __int_as_float(__builtin_amdgcn_update_dpp(0, __float_as_int(x), 0x112, 0xF, 0xF, true)); x += t;
    t = __int_as_float(__builtin_amdgcn_update_dpp(0, __float_as_int(x), 0x114, 0xF, 0xF, true)); x += t;
    t = __int_as_float(__builtin_amdgcn_update_dpp(0, __float_as_int(x), 0x118, 0xF, 0xF, true)); x += t;
    return x;
}

// ---------------------------------------------------------------- cvt f32->bf16
__global__ __launch_bounds__(256) void cvt_k(const float* __restrict__ in,
                                             bf16* __restrict__ out, int n) {
    int i = blockIdx.x * 256 + threadIdx.x;
    if (i < n) out[i] = (bf16)in[i];
}

// ---------------------------------------------------------------- rmsnorm -> bf16
__global__ __launch_bounds__(256) void rmsnorm_k(const float* __restrict__ x,
                                                 const float* __restrict__ w,
                                                 bf16* __restrict__ out) {
    int row = blockIdx.x;
    const float* xr = x + (size_t)row * DD;
    int tid = threadIdx.x;
    float v[3]; float ss = 0.f;
    for (int j = 0; j < 3; j++) { v[j] = xr[tid + j * 256]; ss += v[j] * v[j]; }
    for (int o = 1; o < 64; o <<= 1) ss += __shfl_xor(ss, o, 64);
    __shared__ float sred[4];
    if ((tid & 63) == 0) sred[tid >> 6] = ss;
    __syncthreads();
    float scale = rsqrtf((sred[0] + sred[1] + sred[2] + sred[3]) / (float)DD + 1e-6f);
    for (int j = 0; j < 3; j++) {
        int c = tid + j * 256;
        out[(size_t)row * DD + c] = (bf16)(v[j] * scale * w[c]);
    }
}

// ---------------------------------------------------------------- GEMM: C = A @ W^T
// A: M x K bf16 row-major, W: N x K bf16 row-major. M % 128 == 0. N,K guarded.
// MODE 0: store f32 | MODE 1: store bf16 | MODE 2: +bias, softplus, f32
// MODE 3: +resid, f32
template <int MODE>
__global__ __launch_bounds__(256) void gemm_bt(const bf16* __restrict__ A,
                                               const bf16* __restrict__ W,
                                               float* __restrict__ Cf,
                                               bf16* __restrict__ Cb,
                                               const float* __restrict__ bias,
                                               const float* __restrict__ resid,
                                               int M, int N, int K) {
    __shared__ bf16 As[128][40];
    __shared__ bf16 Ws[128][40];
    const int tid  = threadIdx.x;
    const int m0   = blockIdx.x * 128;
    const int n0   = blockIdx.y * 128;
    const int wave = tid >> 6;
    const int lane = tid & 63;
    const int wm   = (wave >> 1) * 64;
    const int wn   = (wave & 1) * 64;
    const int lrow = lane & 15;
    const int quad = lane >> 4;

    floatx4 acc[4][4];
    for (int mi = 0; mi < 4; mi++)
        for (int ni = 0; ni < 4; ni++) acc[mi][ni] = (floatx4){0.f, 0.f, 0.f, 0.f};

    const int r0  = tid >> 2;        // 0..63
    const int r1  = r0 + 64;         // 64..127
    const int seg = (tid & 3) * 8;   // 0,8,16,24

    for (int kb = 0; kb < K; kb += 32) {
        int gk = kb + seg;
        bf16x8 va0, va1, vb0, vb1;
        {
            const bf16* p0 = A + (size_t)(m0 + r0) * K + gk;
            const bf16* p1 = A + (size_t)(m0 + r1) * K + gk;
            if (gk + 8 <= K) { va0 = *(const bf16x8*)p0; va1 = *(const bf16x8*)p1; }
            else {
                for (int j = 0; j < 8; j++) {
                    bool in = (gk + j) < K;
                    va0[j] = in ? p0[j] : (bf16)0.f;
                    va1[j] = in ? p1[j] : (bf16)0.f;
                }
            }
        }
        {
            int gn0 = n0 + r0, gn1 = n0 + r1;
            const bf16* q0 = W + (size_t)gn0 * K + gk;
            const bf16* q1 = W + (size_t)gn1 * K + gk;
            if (gk + 8 <= K) {
                if (gn0 < N) vb0 = *(const bf16x8*)q0; else for (int j = 0; j < 8; j++) vb0[j] = (bf16)0.f;
                if (gn1 < N) vb1 = *(const bf16x8*)q1; else for (int j = 0; j < 8; j++) vb1[j] = (bf16)0.f;
            } else {
                for (int j = 0; j < 8; j++) {
                    bool in = (gk + j) < K;
                    vb0[j] = (in && gn0 < N) ? q0[j] : (bf16)0.f;
                    vb1[j] = (in && gn1 < N) ? q1[j] : (bf16)0.f;
                }
            }
        }
        __syncthreads();   // previous iteration's LDS reads done
        *(bf16x8*)&As[r0][seg] = va0;
        *(bf16x8*)&As[r1][seg] = va1;
        *(bf16x8*)&Ws[r0][seg] = vb0;
        *(bf16x8*)&Ws[r1][seg] = vb1;
        __syncthreads();
        bf16x8 af[4], wf[4];
        for (int mi = 0; mi < 4; mi++) af[mi] = *(const bf16x8*)&As[wm + mi * 16 + lrow][quad * 8];
        for (int ni = 0; ni < 4; ni++) wf[ni] = *(const bf16x8*)&Ws[wn + ni * 16 + lrow][quad * 8];
        for (int mi = 0; mi < 4; mi++)
            for (int ni = 0; ni < 4; ni++)
                acc[mi][ni] = __builtin_amdgcn_mfma_f32_16x16x32_bf16(af[mi], wf[ni], acc[mi][ni], 0, 0, 0);
    }
    // epilogue: D row = quad*4 + r, col = lrow (verified gfx950 C/D layout)
    for (int mi = 0; mi < 4; mi++) {
        int rowb = m0 + wm + mi * 16 + quad * 4;
        for (int ni = 0; ni < 4; ni++) {
            int col = n0 + wn + ni * 16 + lrow;
            if (col >= N) continue;
            for (int r = 0; r < 4; r++) {
                int row = rowb + r;
                float v = acc[mi][ni][r];
                if constexpr (MODE == 2) {
                    v += bias[col];
                    v = (v > 20.f) ? v : log1pf(__expf(v));
                }
                if constexpr (MODE == 3) { v += resid[(size_t)row * N + col]; }
                if constexpr (MODE == 1) Cb[(size_t)row * N + col] = (bf16)v;
                else                     Cf[(size_t)row * N + col] = v;
            }
        }
    }
}

// ---------------------------------------------------------------- x_proj split-K GEMM
// A: 2048 x 1536 bf16, W: 80 x 1536 bf16 -> part[ks][2048][80] f32.
// Grid (M/64, KSPLIT); each block: 64-row A tile x all 80 cols over a 96-K segment.
__global__ __launch_bounds__(256) void gemm_xp(const bf16* __restrict__ A,
                                               const bf16* __restrict__ W,
                                               float* __restrict__ part) {
    __shared__ bf16 As[64][40];
    __shared__ bf16 Ws[128][40];
    const int tid  = threadIdx.x;
    const int m0   = blockIdx.x * 64;
    const int ks   = blockIdx.y;
    const int k0   = ks * (DI / KSPLIT);   // 96-elem K segment
    const int wave = tid >> 6;
    const int lane = tid & 63;
    const int lrow = lane & 15;
    const int quad = lane >> 4;
    const int wm   = wave * 16;

    floatx4 acc[5];
    for (int ni = 0; ni < 5; ni++) acc[ni] = (floatx4){0.f, 0.f, 0.f, 0.f};

    const int ra  = tid >> 2;        // 0..63
    const int rw1 = ra + 64;         // 64..127
    const int seg = (tid & 3) * 8;

    for (int kb = 0; kb < DI / KSPLIT; kb += 32) {
        int gk = k0 + kb + seg;
        bf16x8 va = *(const bf16x8*)(A + (size_t)(m0 + ra) * DI + gk);
        bf16x8 vw0, vw1;
        if (ra < NXP) vw0 = *(const bf16x8*)(W + (size_t)ra * DI + gk);
        else          for (int j = 0; j < 8; j++) vw0[j] = (bf16)0.f;
        if (rw1 < NXP) vw1 = *(const bf16x8*)(W + (size_t)rw1 * DI + gk);
        else           for (int j = 0; j < 8; j++) vw1[j] = (bf16)0.f;
        __syncthreads();
        *(bf16x8*)&As[ra][seg]  = va;
        *(bf16x8*)&Ws[ra][seg]  = vw0;
        *(bf16x8*)&Ws[rw1][seg] = vw1;
        __syncthreads();
        bf16x8 af = *(const bf16x8*)&As[wm + lrow][quad * 8];
        for (int ni = 0; ni < 5; ni++) {
            bf16x8 wf = *(const bf16x8*)&Ws[ni * 16 + lrow][quad * 8];
            acc[ni] = __builtin_amdgcn_mfma_f32_16x16x32_bf16(af, wf, acc[ni], 0, 0, 0);
        }
    }
    float* pout = part + (size_t)ks * MROWS * NXP;
    for (int ni = 0; ni < 5; ni++) {
        int col = ni * 16 + lrow;                 // 0..79, no guard needed
        for (int r = 0; r < 4; r++) {
            int row = m0 + wm + quad * 4 + r;
            pout[(size_t)row * NXP + col] = acc[ni][r];
        }
    }
}

// reduce split-K partials -> xdbl f32 + compact bf16 dt (cols < DTRANK)
__global__ __launch_bounds__(256) void xp_reduce_k(const float* __restrict__ part,
                                                   float* __restrict__ xdbl,
                                                   bf16* __restrict__ dtbf) {
    int idx = blockIdx.x * 256 + threadIdx.x;
    if (idx >= MROWS * NXP) return;
    float s = 0.f;
    for (int j = 0; j < KSPLIT; j++) s += part[(size_t)j * MROWS * NXP + idx];
    xdbl[idx] = s;
    int m = idx / NXP, c = idx - m * NXP;
    if (c < DTRANK) dtbf[m * DTRANK + c] = (bf16)s;
}

// ---------------------------------------------------------------- causal depthwise conv + silu + gate precompute
__global__ __launch_bounds__(256) void conv_silu_k(const bf16* __restrict__ xz,
                                                   const float* __restrict__ cw,
                                                   const float* __restrict__ cb,
                                                   float* __restrict__ xc,
                                                   bf16* __restrict__ xcb,
                                                   float* __restrict__ gz) {
    int idx = blockIdx.x * 256 + threadIdx.x;
    if (idx >= MROWS * DI) return;
    int d = idx % DI;
    int m = idx / DI;
    int l = m & (LL - 1);
    float acc = cb[d];
    for (int k = 0; k < 4; k++) {
        int lp = l - 3 + k;
        if (lp >= 0) acc += (float)xz[(size_t)(m - 3 + k) * (2 * DI) + d] * cw[d * 4 + k];
    }
    float s = acc / (1.f + __expf(-acc));
    xc[idx]  = s;
    xcb[idx] = (bf16)s;
    // silu(z) gate, hoisted out of the scan's serial loop (saves exp+div per step)
    float zv = (float)xz[(size_t)m * (2 * DI) + DI + d];
    gz[idx] = zv / (1.f + __expf(-zv));
}

// ---------------------------------------------------------------- chunk-parallel selective scan
// Phase 1: per (chunk, b, d-tile): local scan from 0 -> (P, S), P = exp(a*sum(delta)).
__global__ __launch_bounds__(256) void scan1_k(const float* __restrict__ delta,
                                               const float* __restrict__ xc,
                                               const float* __restrict__ xdbl,
                                               const float* __restrict__ A_log,
                                               float* __restrict__ Pbuf,
                                               float* __restrict__ Sbuf) {
    int b  = blockIdx.y;
    int d0 = blockIdx.x * 16;
    int c  = blockIdx.z;
    int tid = threadIdx.x;
    int dl = tid >> 4;
    int n  = tid & 15;
    int d  = d0 + dl;
    float a = -__expf(A_log[d * DSTATE + n]);
    __shared__ float2 sdx[CLEN][16];   // (delta, xc)
    __shared__ float  sb[CLEN][16];
    int l0 = c * CLEN;
    for (int idx = tid; idx < CLEN * 16; idx += 256) {
        int i = idx >> 4, dd = idx & 15;
        size_t row = (size_t)(b * LL + l0 + i);
        sdx[i][dd] = make_float2(delta[row * DI + d0 + dd], xc[row * DI + d0 + dd]);
        sb[i][dd]  = xdbl[row * NXP + DTRANK + dd];   // B-state column dd
    }
    __syncthreads();
    float h = 0.f, sd = 0.f;
    for (int i = 0; i < CLEN; i++) {
        float2 dx = sdx[i][dl];
        float Bv  = sb[i][n];
        h = __expf(dx.x * a) * h + dx.x * Bv * dx.y;
        sd += dx.x;
    }
    size_t o = (((size_t)c * BB + b) * DI + d) * DSTATE + n;
    Pbuf[o] = __expf(a * sd);
    Sbuf[o] = h;
}

// Phase 2: compose h_in from previous chunks' (P,S), re-run local scan, emit y.
__global__ __launch_bounds__(256) void scan2_k(const float* __restrict__ delta,
                                               const float* __restrict__ xc,
                                               const float* __restrict__ gz,
                                               const float* __restrict__ xdbl,
                                               const float* __restrict__ A_log,
                                               const float* __restrict__ Dskip,
                                               const float* __restrict__ Pbuf,
                                               const float* __restrict__ Sbuf,
                                               bf16* __restrict__ ybf) {
    int b  = blockIdx.y;
    int d0 = blockIdx.x * 16;
    int c  = blockIdx.z;
    int tid = threadIdx.x;
    int dl = tid >> 4;
    int n  = tid & 15;
    int d  = d0 + dl;
    float a     = -__expf(A_log[d * DSTATE + n]);
    float dskip = Dskip[d];
    // compose initial state across preceding chunks (<=15 fma, coalesced loads)
    float h = 0.f;
    {
        size_t stride = (size_t)BB * DI * DSTATE;
        size_t base   = ((size_t)b * DI + d) * DSTATE + n;
        for (int j = 0; j < c; j++)
            h = Pbuf[(size_t)j * stride + base] * h + Sbuf[(size_t)j * stride + base];
    }
    __shared__ float4 sdxz[CLEN][16];   // (delta, xc, gz, pad)
    __shared__ float2 sbc2[CLEN][16];   // (B_n, C_n)
    int l0 = c * CLEN;
    for (int idx = tid; idx < CLEN * 16; idx += 256) {
        int i = idx >> 4, dd = idx & 15;
        size_t row = (size_t)(b * LL + l0 + i);
        sdxz[i][dd] = make_float4(delta[row * DI + d0 + dd],
                                  xc[row * DI + d0 + dd],
                                  gz[row * DI + d0 + dd],
                                  0.f);
        sbc2[i][dd] = make_float2(xdbl[row * NXP + DTRANK + dd],
                                  xdbl[row * NXP + DTRANK + DSTATE + dd]);
    }
    __syncthreads();
    for (int i = 0; i < CLEN; i++) {
        float4 dxz = sdxz[i][dl];
        float2 bc  = sbc2[i][n];
        h = __expf(dxz.x * a) * h + dxz.x * bc.x * dxz.y;
        float yp = row16_sum(h * bc.y);   // DPP reduce, lane n==0 gets sum
        if (n == 0) {
            float yv = (yp + dxz.y * dskip) * dxz.z;   // gate precomputed
            ybf[(size_t)(b * LL + l0 + i) * DI + d] = (bf16)yv;
        }
    }
}

// ---------------------------------------------------------------- head, stage 1: final rmsnorm of last token (f32 out)
__global__ __launch_bounds__(256) void head_norm_k(const float* __restrict__ x,
                                                   const float* __restrict__ fnw,
                                                   float* __restrict__ xn_buf) {
    int b = blockIdx.x;
    int tid = threadIdx.x;
    const float* xr = x + ((size_t)b * LL + (LL - 1)) * DD;
    __shared__ float sred[4];
    float v[3]; float ss = 0.f;
    for (int j = 0; j < 3; j++) { v[j] = xr[tid + j * 256]; ss += v[j] * v[j]; }
    for (int o = 1; o < 64; o <<= 1) ss += __shfl_xor(ss, o, 64);
    if ((tid & 63) == 0) sred[tid >> 6] = ss;
    __syncthreads();
    float scale = rsqrtf((sred[0] + sred[1] + sred[2] + sred[3]) / (float)DD + 1e-6f);
    for (int j = 0; j < 3; j++) {
        int c = tid + j * 256;
        xn_buf[(size_t)b * DD + c] = v[j] * scale * fnw[c];
    }
}

// ---------------------------------------------------------------- head, stage 2: h1 matvec (coalesced, wave-per-output)
__global__ __launch_bounds__(256) void head_h1_k(const float* __restrict__ xn_buf,
                                                 const float* __restrict__ h1w,
                                                 const float* __restrict__ h1b,
                                                 float* __restrict__ h_buf) {
    int b  = blockIdx.x;
    int o0 = blockIdx.y * 64;
    int tid = threadIdx.x;
    __shared__ float sx[DD];
    for (int c = tid; c < DD; c += 256) sx[c] = xn_buf[(size_t)b * DD + c];
    __syncthreads();
    int wave = tid >> 6, lane = tid & 63;
    for (int j = 0; j < 16; j++) {
        int o = o0 + wave * 16 + j;
        const float* wrow = h1w + (size_t)o * DD;
        float acc = 0.f;
        for (int k = 0; k < 12; k++) {
            int c = lane + 64 * k;
            acc += wrow[c] * sx[c];
        }
        for (int off = 1; off < 64; off <<= 1) acc += __shfl_xor(acc, off, 64);
        if (lane == 0) h_buf[(size_t)b * DD + o] = acc + h1b[o];
    }
}

// ---------------------------------------------------------------- head, stage 3: rmsnorm + gelu + h2 matvec
__global__ __launch_bounds__(256) void head_out_k(const float* __restrict__ h_buf,
                                                  const float* __restrict__ hnw,
                                                  const float* __restrict__ h2w,
                                                  const float* __restrict__ h2b,
                                                  float* __restrict__ out) {
    int b = blockIdx.x;
    int tid = threadIdx.x;
    __shared__ float hh[DD];
    __shared__ float sred[4];
    const float* hr = h_buf + (size_t)b * DD;
    float ss = 0.f;
    for (int c = tid; c < DD; c += 256) { float v = hr[c]; ss += v * v; }
    for (int o = 1; o < 64; o <<= 1) ss += __shfl_xor(ss, o, 64);
    if ((tid & 63) == 0) sred[tid >> 6] = ss;
    __syncthreads();
    float sc = rsqrtf((sred[0] + sred[1] + sred[2] + sred[3]) / (float)DD + 1e-6f);
    for (int c = tid; c < DD; c += 256) {
        float v = hr[c] * sc * hnw[c];
        hh[c] = 0.5f * v * (1.f + erff(v * 0.70710678118f));   // exact gelu
    }
    __syncthreads();
    int w = tid >> 6, lane = tid & 63;
    for (int j = w; j < 10; j += 4) {
        float acc = 0.f;
        const float* wrow = h2w + (size_t)j * DD;
        for (int c = lane; c < DD; c += 64) acc += hh[c] * wrow[c];
        for (int o = 1; o < 64; o <<= 1) acc += __shfl_xor(acc, o, 64);
        if (lane == 0) out[b * 10 + j] = acc + h2b[j];
    }
}

// ----------------------------------------------------------------
extern "C" void kernel_launch(void* const* d_in, const int* in_sizes, int n_in,
                              void* d_out, int out_size, void* d_ws, size_t ws_size,
                              hipStream_t stream) {
    const float* x_in      = (const float*)d_in[0];
    const float* norm_w    = (const float*)d_in[1];
    const float* in_proj_w = (const float*)d_in[2];
    const float* conv_w    = (const float*)d_in[3];
    const float* conv_b    = (const float*)d_in[4];
    const float* x_proj_w  = (const float*)d_in[5];
    const float* dt_proj_w = (const float*)d_in[6];
    const float* dt_proj_b = (const float*)d_in[7];
    const float* A_log     = (const float*)d_in[8];
    const float* D_skip    = (const float*)d_in[9];
    const float* out_proj_w= (const float*)d_in[10];
    const float* fnw       = (const float*)d_in[11];
    const float* h1w       = (const float*)d_in[12];
    const float* h1b       = (const float*)d_in[13];
    const float* hnw       = (const float*)d_in[14];
    const float* h2w       = (const float*)d_in[15];
    const float* h2b       = (const float*)d_in[16];
    float* out = (float*)d_out;

    char* ws = (char*)d_ws;
    size_t off = 0;
    auto alloc = [&](size_t bytes) -> void* {
        void* p = ws + off;
        off += (bytes + 255) & ~(size_t)255;
        return p;
    };
    bf16* w_in  = (bf16*)alloc((size_t)4 * 3072 * 768 * 2);
    bf16* w_xp  = (bf16*)alloc((size_t)4 * NXP * DI * 2);
    bf16* w_dt  = (bf16*)alloc((size_t)4 * DI * DTRANK * 2);
    bf16* w_out = (bf16*)alloc((size_t)4 * DD * DI * 2);
    bf16* xn_bf = (bf16*)alloc((size_t)MROWS * DD * 2);
    bf16* xz_bf = (bf16*)alloc((size_t)MROWS * 2 * DI * 2);
    float* xc_f = (float*)alloc((size_t)MROWS * DI * 4);
    bf16* xc_bf = (bf16*)alloc((size_t)MROWS * DI * 2);
    float* gz_f = (float*)alloc((size_t)MROWS * DI * 4);
    float* xdbl = (float*)alloc((size_t)MROWS * NXP * 4);
    bf16* dt_bf = (bf16*)alloc((size_t)MROWS * DTRANK * 2);
    float* delta= (float*)alloc((size_t)MROWS * DI * 4);
    bf16* y_bf  = (bf16*)alloc((size_t)MROWS * DI * 2);
    float* x_buf= (float*)alloc((size_t)MROWS * DD * 4);
    float* Pbuf = (float*)alloc((size_t)NC * BB * DI * DSTATE * 4);
    float* Sbuf = (float*)alloc((size_t)NC * BB * DI * DSTATE * 4);
    float* xnl  = (float*)alloc((size_t)BB * DD * 4);
    float* hbuf = (float*)alloc((size_t)BB * DD * 4);
    float* xp_part = (float*)alloc((size_t)KSPLIT * MROWS * NXP * 4);

    // convert all weights to bf16 (every call; ws is re-poisoned between calls)
    {
        int n1 = 4 * 3072 * 768;   cvt_k<<<(n1 + 255) / 256, 256, 0, stream>>>(in_proj_w,  w_in,  n1);
        int n2 = 4 * NXP * DI;     cvt_k<<<(n2 + 255) / 256, 256, 0, stream>>>(x_proj_w,   w_xp,  n2);
        int n3 = 4 * DI * DTRANK;  cvt_k<<<(n3 + 255) / 256, 256, 0, stream>>>(dt_proj_w,  w_dt,  n3);
        int n4 = 4 * DD * DI;      cvt_k<<<(n4 + 255) / 256, 256, 0, stream>>>(out_proj_w, w_out, n4);
    }

    for (int i = 0; i < 4; i++) {
        const float* x_src = (i == 0) ? x_in : x_buf;
        // 1. rmsnorm -> bf16
        rmsnorm_k<<<MROWS, 256, 0, stream>>>(x_src, norm_w + i * DD, xn_bf);
        // 2. in_proj: (2048 x 3072) = xn @ in_w^T, bf16 out
        gemm_bt<1><<<dim3(MROWS / 128, 3072 / 128), 256, 0, stream>>>(
            xn_bf, w_in + (size_t)i * 3072 * 768, nullptr, xz_bf, nullptr, nullptr,
            MROWS, 2 * DI, DD);
        // 3. causal conv + silu + silu(z) gate precompute
        conv_silu_k<<<(MROWS * DI + 255) / 256, 256, 0, stream>>>(
            xz_bf, conv_w + (size_t)i * DI * 4, conv_b + (size_t)i * DI, xc_f, xc_bf, gz_f);
        // 4. x_proj split-K (512 blocks) + reduce -> xdbl f32 + compact bf16 dt
        gemm_xp<<<dim3(MROWS / 64, KSPLIT), 256, 0, stream>>>(
            xc_bf, w_xp + (size_t)i * NXP * DI, xp_part);
        xp_reduce_k<<<(MROWS * NXP + 255) / 256, 256, 0, stream>>>(xp_part, xdbl, dt_bf);
        // 5. dt_proj + bias + softplus -> delta
        gemm_bt<2><<<dim3(MROWS / 128, DI / 128), 256, 0, stream>>>(
            dt_bf, w_dt + (size_t)i * DI * DTRANK, delta, nullptr,
            dt_proj_b + (size_t)i * DI, nullptr, MROWS, DI, DTRANK);
        // 6a. chunk-local scans -> (P, S)
        scan1_k<<<dim3(DI / 16, BB, NC), 256, 0, stream>>>(
            delta, xc_f, xdbl, A_log + (size_t)i * DI * DSTATE, Pbuf, Sbuf);
        // 6b. compose + local scan + D-skip + precomputed gate -> y bf16
        scan2_k<<<dim3(DI / 16, BB, NC), 256, 0, stream>>>(
            delta, xc_f, gz_f, xdbl, A_log + (size_t)i * DI * DSTATE,
            D_skip + (size_t)i * DI, Pbuf, Sbuf, y_bf);
        // 7. out_proj + residual -> x_buf
        gemm_bt<3><<<dim3(MROWS / 128, DD / 128), 256, 0, stream>>>(
            y_bf, w_out + (size_t)i * DD * DI, x_buf, nullptr, nullptr, x_src,
            MROWS, DD, DI);
    }

    head_norm_k<<<BB, 256, 0, stream>>>(x_buf, fnw, xnl);
    head_h1_k<<<dim3(BB, DD / 64), 256, 0, stream>>>(xnl, h1w, h1b, hbuf);
    head_out_k<<<BB, 256, 0, stream>>>(hbuf, hnw, h2w, h2b, out);
}

// Round 8
// 810.138 us; speedup vs baseline: 2.5315x; 1.0788x over previous
//
#include <hip/hip_runtime.h>
#include <hip/hip_bf16.h>
#include <math.h>

typedef __bf16 bf16;
typedef __bf16 bf16x8 __attribute__((ext_vector_type(8)));
typedef float floatx4 __attribute__((ext_vector_type(4)));

#define BB 2
#define LL 1024
#define DD 768
#define DI 1536
#define MROWS 2048   // B*L
#define NXP 80       // dt_rank + 2*d_state
#define DTRANK 48
#define DSTATE 16
#define NC 16        // scan chunks
#define CLEN 64      // scan chunk length (NC*CLEN == LL)
#define KSPLIT 16    // x_proj split-K factor (K-seg = 96)
#define OPKS 4       // out_proj split-K factor (K-seg = 384)

// DPP row-reduce over 16 lanes (one DPP row): after shr 1/2/4/8 adds, lane 0
// of each 16-lane row holds the row sum. VALU-pipe only (no DS ops).
__device__ __forceinline__ float row16_sum(float x) {
    float t;
    t = __int_as_float(__builtin_amdgcn_update_dpp(0, __float_as_int(x), 0x111, 0xF, 0xF, true)); x += t;
    t = __int_as_float(__builtin_amdgcn_update_dpp(0, __float_as_int(x), 0x112, 0xF, 0xF, true)); x += t;
    t = __int_as_float(__builtin_amdgcn_update_dpp(0, __float_as_int(x), 0x114, 0xF, 0xF, true)); x += t;
    t = __int_as_float(__builtin_amdgcn_update_dpp(0, __float_as_int(x), 0x118, 0xF, 0xF, true)); x += t;
    return x;
}

// ---------------------------------------------------------------- cvt f32->bf16
__global__ __launch_bounds__(256) void cvt_k(const float* __restrict__ in,
                                             bf16* __restrict__ out, int n) {
    int i = blockIdx.x * 256 + threadIdx.x;
    if (i < n) out[i] = (bf16)in[i];
}

// ---------------------------------------------------------------- rmsnorm -> bf16
__global__ __launch_bounds__(256) void rmsnorm_k(const float* __restrict__ x,
                                                 const float* __restrict__ w,
                                                 bf16* __restrict__ out) {
    int row = blockIdx.x;
    const float* xr = x + (size_t)row * DD;
    int tid = threadIdx.x;
    float v[3]; float ss = 0.f;
    for (int j = 0; j < 3; j++) { v[j] = xr[tid + j * 256]; ss += v[j] * v[j]; }
    for (int o = 1; o < 64; o <<= 1) ss += __shfl_xor(ss, o, 64);
    __shared__ float sred[4];
    if ((tid & 63) == 0) sred[tid >> 6] = ss;
    __syncthreads();
    float scale = rsqrtf((sred[0] + sred[1] + sred[2] + sred[3]) / (float)DD + 1e-6f);
    for (int j = 0; j < 3; j++) {
        int c = tid + j * 256;
        out[(size_t)row * DD + c] = (bf16)(v[j] * scale * w[c]);
    }
}

// ---------------------------------------------------------------- GEMM: C = A @ W^T
// A: M x K bf16 row-major, W: N x K bf16 row-major. M % 128 == 0. N,K guarded.
// MODE 0: store f32 | MODE 1: store bf16 | MODE 2: +bias, softplus, f32
// MODE 3: +resid, f32 | MODE 5: split-K partials f32 (grid.z segments)
template <int MODE>
__global__ __launch_bounds__(256) void gemm_bt(const bf16* __restrict__ A,
                                               const bf16* __restrict__ W,
                                               float* __restrict__ Cf,
                                               bf16* __restrict__ Cb,
                                               const float* __restrict__ bias,
                                               const float* __restrict__ resid,
                                               int M, int N, int K) {
    __shared__ bf16 As[128][40];
    __shared__ bf16 Ws[128][40];
    const int tid  = threadIdx.x;
    const int m0   = blockIdx.x * 128;
    const int n0   = blockIdx.y * 128;
    const int wave = tid >> 6;
    const int lane = tid & 63;
    const int wm   = (wave >> 1) * 64;
    const int wn   = (wave & 1) * 64;
    const int lrow = lane & 15;
    const int quad = lane >> 4;

    int kbeg = 0, kend = K;
    if constexpr (MODE == 5) {
        int kseg = K / gridDim.z;
        kbeg = blockIdx.z * kseg;
        kend = kbeg + kseg;
        Cf  += (size_t)blockIdx.z * M * N;
    }

    floatx4 acc[4][4];
    for (int mi = 0; mi < 4; mi++)
        for (int ni = 0; ni < 4; ni++) acc[mi][ni] = (floatx4){0.f, 0.f, 0.f, 0.f};

    const int r0  = tid >> 2;        // 0..63
    const int r1  = r0 + 64;         // 64..127
    const int seg = (tid & 3) * 8;   // 0,8,16,24

    for (int kb = kbeg; kb < kend; kb += 32) {
        int gk = kb + seg;
        bf16x8 va0, va1, vb0, vb1;
        {
            const bf16* p0 = A + (size_t)(m0 + r0) * K + gk;
            const bf16* p1 = A + (size_t)(m0 + r1) * K + gk;
            if (gk + 8 <= K) { va0 = *(const bf16x8*)p0; va1 = *(const bf16x8*)p1; }
            else {
                for (int j = 0; j < 8; j++) {
                    bool in = (gk + j) < K;
                    va0[j] = in ? p0[j] : (bf16)0.f;
                    va1[j] = in ? p1[j] : (bf16)0.f;
                }
            }
        }
        {
            int gn0 = n0 + r0, gn1 = n0 + r1;
            const bf16* q0 = W + (size_t)gn0 * K + gk;
            const bf16* q1 = W + (size_t)gn1 * K + gk;
            if (gk + 8 <= K) {
                if (gn0 < N) vb0 = *(const bf16x8*)q0; else for (int j = 0; j < 8; j++) vb0[j] = (bf16)0.f;
                if (gn1 < N) vb1 = *(const bf16x8*)q1; else for (int j = 0; j < 8; j++) vb1[j] = (bf16)0.f;
            } else {
                for (int j = 0; j < 8; j++) {
                    bool in = (gk + j) < K;
                    vb0[j] = (in && gn0 < N) ? q0[j] : (bf16)0.f;
                    vb1[j] = (in && gn1 < N) ? q1[j] : (bf16)0.f;
                }
            }
        }
        __syncthreads();   // previous iteration's LDS reads done
        *(bf16x8*)&As[r0][seg] = va0;
        *(bf16x8*)&As[r1][seg] = va1;
        *(bf16x8*)&Ws[r0][seg] = vb0;
        *(bf16x8*)&Ws[r1][seg] = vb1;
        __syncthreads();
        bf16x8 af[4], wf[4];
        for (int mi = 0; mi < 4; mi++) af[mi] = *(const bf16x8*)&As[wm + mi * 16 + lrow][quad * 8];
        for (int ni = 0; ni < 4; ni++) wf[ni] = *(const bf16x8*)&Ws[wn + ni * 16 + lrow][quad * 8];
        for (int mi = 0; mi < 4; mi++)
            for (int ni = 0; ni < 4; ni++)
                acc[mi][ni] = __builtin_amdgcn_mfma_f32_16x16x32_bf16(af[mi], wf[ni], acc[mi][ni], 0, 0, 0);
    }
    // epilogue: D row = quad*4 + r, col = lrow (verified gfx950 C/D layout)
    for (int mi = 0; mi < 4; mi++) {
        int rowb = m0 + wm + mi * 16 + quad * 4;
        for (int ni = 0; ni < 4; ni++) {
            int col = n0 + wn + ni * 16 + lrow;
            if (col >= N) continue;
            for (int r = 0; r < 4; r++) {
                int row = rowb + r;
                float v = acc[mi][ni][r];
                if constexpr (MODE == 2) {
                    v += bias[col];
                    v = (v > 20.f) ? v : log1pf(__expf(v));
                }
                if constexpr (MODE == 3) { v += resid[(size_t)row * N + col]; }
                if constexpr (MODE == 1) Cb[(size_t)row * N + col] = (bf16)v;
                else                     Cf[(size_t)row * N + col] = v;
            }
        }
    }
}

// reduce out_proj split-K partials + residual -> x_buf f32
__global__ __launch_bounds__(256) void op_reduce_k(const float* __restrict__ part,
                                                   const float* __restrict__ resid,
                                                   float* __restrict__ xout) {
    int idx = blockIdx.x * 256 + threadIdx.x;
    if (idx >= MROWS * DD) return;
    float s = resid[idx];
    for (int j = 0; j < OPKS; j++) s += part[(size_t)j * MROWS * DD + idx];
    xout[idx] = s;
}

// ---------------------------------------------------------------- x_proj split-K GEMM
// A: 2048 x 1536 bf16, W: 80 x 1536 bf16 -> part[ks][2048][80] f32.
// Grid (M/64, KSPLIT); each block: 64-row A tile x all 80 cols over a 96-K segment.
__global__ __launch_bounds__(256) void gemm_xp(const bf16* __restrict__ A,
                                               const bf16* __restrict__ W,
                                               float* __restrict__ part) {
    __shared__ bf16 As[64][40];
    __shared__ bf16 Ws[128][40];
    const int tid  = threadIdx.x;
    const int m0   = blockIdx.x * 64;
    const int ks   = blockIdx.y;
    const int k0   = ks * (DI / KSPLIT);   // 96-elem K segment
    const int wave = tid >> 6;
    const int lane = tid & 63;
    const int lrow = lane & 15;
    const int quad = lane >> 4;
    const int wm   = wave * 16;

    floatx4 acc[5];
    for (int ni = 0; ni < 5; ni++) acc[ni] = (floatx4){0.f, 0.f, 0.f, 0.f};

    const int ra  = tid >> 2;        // 0..63
    const int rw1 = ra + 64;         // 64..127
    const int seg = (tid & 3) * 8;

    for (int kb = 0; kb < DI / KSPLIT; kb += 32) {
        int gk = k0 + kb + seg;
        bf16x8 va = *(const bf16x8*)(A + (size_t)(m0 + ra) * DI + gk);
        bf16x8 vw0, vw1;
        if (ra < NXP) vw0 = *(const bf16x8*)(W + (size_t)ra * DI + gk);
        else          for (int j = 0; j < 8; j++) vw0[j] = (bf16)0.f;
        if (rw1 < NXP) vw1 = *(const bf16x8*)(W + (size_t)rw1 * DI + gk);
        else           for (int j = 0; j < 8; j++) vw1[j] = (bf16)0.f;
        __syncthreads();
        *(bf16x8*)&As[ra][seg]  = va;
        *(bf16x8*)&Ws[ra][seg]  = vw0;
        *(bf16x8*)&Ws[rw1][seg] = vw1;
        __syncthreads();
        bf16x8 af = *(const bf16x8*)&As[wm + lrow][quad * 8];
        for (int ni = 0; ni < 5; ni++) {
            bf16x8 wf = *(const bf16x8*)&Ws[ni * 16 + lrow][quad * 8];
            acc[ni] = __builtin_amdgcn_mfma_f32_16x16x32_bf16(af, wf, acc[ni], 0, 0, 0);
        }
    }
    float* pout = part + (size_t)ks * MROWS * NXP;
    for (int ni = 0; ni < 5; ni++) {
        int col = ni * 16 + lrow;                 // 0..79, no guard needed
        for (int r = 0; r < 4; r++) {
            int row = m0 + wm + quad * 4 + r;
            pout[(size_t)row * NXP + col] = acc[ni][r];
        }
    }
}

// reduce split-K partials -> xdbl f32 + compact bf16 dt (cols < DTRANK)
__global__ __launch_bounds__(256) void xp_reduce_k(const float* __restrict__ part,
                                                   float* __restrict__ xdbl,
                                                   bf16* __restrict__ dtbf) {
    int idx = blockIdx.x * 256 + threadIdx.x;
    if (idx >= MROWS * NXP) return;
    float s = 0.f;
    for (int j = 0; j < KSPLIT; j++) s += part[(size_t)j * MROWS * NXP + idx];
    xdbl[idx] = s;
    int m = idx / NXP, c = idx - m * NXP;
    if (c < DTRANK) dtbf[m * DTRANK + c] = (bf16)s;
}

// ---------------------------------------------------------------- causal depthwise conv + silu + gate precompute
__global__ __launch_bounds__(256) void conv_silu_k(const bf16* __restrict__ xz,
                                                   const float* __restrict__ cw,
                                                   const float* __restrict__ cb,
                                                   float* __restrict__ xc,
                                                   bf16* __restrict__ xcb,
                                                   float* __restrict__ gz) {
    int idx = blockIdx.x * 256 + threadIdx.x;
    if (idx >= MROWS * DI) return;
    int d = idx % DI;
    int m = idx / DI;
    int l = m & (LL - 1);
    float acc = cb[d];
    for (int k = 0; k < 4; k++) {
        int lp = l - 3 + k;
        if (lp >= 0) acc += (float)xz[(size_t)(m - 3 + k) * (2 * DI) + d] * cw[d * 4 + k];
    }
    float s = acc / (1.f + __expf(-acc));
    xc[idx]  = s;
    xcb[idx] = (bf16)s;
    // silu(z) gate, hoisted out of the scan's serial loop (saves exp+div per step)
    float zv = (float)xz[(size_t)m * (2 * DI) + DI + d];
    gz[idx] = zv / (1.f + __expf(-zv));
}

// ---------------------------------------------------------------- chunk-parallel selective scan
// Phase 1: per (chunk, b, d-tile): local scan from 0 -> (P, S), P = exp(a*sum(delta)).
__global__ __launch_bounds__(256) void scan1_k(const float* __restrict__ delta,
                                               const float* __restrict__ xc,
                                               const float* __restrict__ xdbl,
                                               const float* __restrict__ A_log,
                                               float* __restrict__ Pbuf,
                                               float* __restrict__ Sbuf) {
    int b  = blockIdx.y;
    int d0 = blockIdx.x * 16;
    int c  = blockIdx.z;
    int tid = threadIdx.x;
    int dl = tid >> 4;
    int n  = tid & 15;
    int d  = d0 + dl;
    float a = -__expf(A_log[d * DSTATE + n]);
    __shared__ float2 sdx[CLEN][16];   // (delta, xc)
    __shared__ float  sb[CLEN][16];
    int l0 = c * CLEN;
    for (int idx = tid; idx < CLEN * 16; idx += 256) {
        int i = idx >> 4, dd = idx & 15;
        size_t row = (size_t)(b * LL + l0 + i);
        sdx[i][dd] = make_float2(delta[row * DI + d0 + dd], xc[row * DI + d0 + dd]);
        sb[i][dd]  = xdbl[row * NXP + DTRANK + dd];   // B-state column dd
    }
    __syncthreads();
    float h = 0.f, sd = 0.f;
    for (int i = 0; i < CLEN; i++) {
        float2 dx = sdx[i][dl];
        float Bv  = sb[i][n];
        h = __expf(dx.x * a) * h + dx.x * Bv * dx.y;
        sd += dx.x;
    }
    size_t o = (((size_t)c * BB + b) * DI + d) * DSTATE + n;
    Pbuf[o] = __expf(a * sd);
    Sbuf[o] = h;
}

// Phase 2: compose h_in from previous chunks' (P,S), re-run local scan, emit y.
__global__ __launch_bounds__(256) void scan2_k(const float* __restrict__ delta,
                                               const float* __restrict__ xc,
                                               const float* __restrict__ gz,
                                               const float* __restrict__ xdbl,
                                               const float* __restrict__ A_log,
                                               const float* __restrict__ Dskip,
                                               const float* __restrict__ Pbuf,
                                               const float* __restrict__ Sbuf,
                                               bf16* __restrict__ ybf) {
    int b  = blockIdx.y;
    int d0 = blockIdx.x * 16;
    int c  = blockIdx.z;
    int tid = threadIdx.x;
    int dl = tid >> 4;
    int n  = tid & 15;
    int d  = d0 + dl;
    float a     = -__expf(A_log[d * DSTATE + n]);
    float dskip = Dskip[d];
    // compose initial state across preceding chunks (<=15 fma, coalesced loads)
    float h = 0.f;
    {
        size_t stride = (size_t)BB * DI * DSTATE;
        size_t base   = ((size_t)b * DI + d) * DSTATE + n;
        for (int j = 0; j < c; j++)
            h = Pbuf[(size_t)j * stride + base] * h + Sbuf[(size_t)j * stride + base];
    }
    __shared__ float4 sdxz[CLEN][16];   // (delta, xc, gz, pad)
    __shared__ float2 sbc2[CLEN][16];   // (B_n, C_n)
    int l0 = c * CLEN;
    for (int idx = tid; idx < CLEN * 16; idx += 256) {
        int i = idx >> 4, dd = idx & 15;
        size_t row = (size_t)(b * LL + l0 + i);
        sdxz[i][dd] = make_float4(delta[row * DI + d0 + dd],
                                  xc[row * DI + d0 + dd],
                                  gz[row * DI + d0 + dd],
                                  0.f);
        sbc2[i][dd] = make_float2(xdbl[row * NXP + DTRANK + dd],
                                  xdbl[row * NXP + DTRANK + DSTATE + dd]);
    }
    __syncthreads();
    for (int i = 0; i < CLEN; i++) {
        float4 dxz = sdxz[i][dl];
        float2 bc  = sbc2[i][n];
        h = __expf(dxz.x * a) * h + dxz.x * bc.x * dxz.y;
        float yp = row16_sum(h * bc.y);   // DPP reduce, lane n==0 gets sum
        if (n == 0) {
            float yv = (yp + dxz.y * dskip) * dxz.z;   // gate precomputed
            ybf[(size_t)(b * LL + l0 + i) * DI + d] = (bf16)yv;
        }
    }
}

// ---------------------------------------------------------------- head, stage 1: final rmsnorm of last token (f32 out)
__global__ __launch_bounds__(256) void head_norm_k(const float* __restrict__ x,
                                                   const float* __restrict__ fnw,
                                                   float* __restrict__ xn_buf) {
    int b = blockIdx.x;
    int tid = threadIdx.x;
    const float* xr = x + ((size_t)b * LL + (LL - 1)) * DD;
    __shared__ float sred[4];
    float v[3]; float ss = 0.f;
    for (int j = 0; j < 3; j++) { v[j] = xr[tid + j * 256]; ss += v[j] * v[j]; }
    for (int o = 1; o < 64; o <<= 1) ss += __shfl_xor(ss, o, 64);
    if ((tid & 63) == 0) sred[tid >> 6] = ss;
    __syncthreads();
    float scale = rsqrtf((sred[0] + sred[1] + sred[2] + sred[3]) / (float)DD + 1e-6f);
    for (int j = 0; j < 3; j++) {
        int c = tid + j * 256;
        xn_buf[(size_t)b * DD + c] = v[j] * scale * fnw[c];
    }
}

// ---------------------------------------------------------------- head, stage 2: h1 matvec (coalesced, wave-per-output)
__global__ __launch_bounds__(256) void head_h1_k(const float* __restrict__ xn_buf,
                                                 const float* __restrict__ h1w,
                                                 const float* __restrict__ h1b,
                                                 float* __restrict__ h_buf) {
    int b  = blockIdx.x;
    int o0 = blockIdx.y * 64;
    int tid = threadIdx.x;
    __shared__ float sx[DD];
    for (int c = tid; c < DD; c += 256) sx[c] = xn_buf[(size_t)b * DD + c];
    __syncthreads();
    int wave = tid >> 6, lane = tid & 63;
    for (int j = 0; j < 16; j++) {
        int o = o0 + wave * 16 + j;
        const float* wrow = h1w + (size_t)o * DD;
        float acc = 0.f;
        for (int k = 0; k < 12; k++) {
            int c = lane + 64 * k;
            acc += wrow[c] * sx[c];
        }
        for (int off = 1; off < 64; off <<= 1) acc += __shfl_xor(acc, off, 64);
        if (lane == 0) h_buf[(size_t)b * DD + o] = acc + h1b[o];
    }
}

// ---------------------------------------------------------------- head, stage 3: rmsnorm + gelu + h2 matvec
__global__ __launch_bounds__(256) void head_out_k(const float* __restrict__ h_buf,
                                                  const float* __restrict__ hnw,
                                                  const float* __restrict__ h2w,
                                                  const float* __restrict__ h2b,
                                                  float* __restrict__ out) {
    int b = blockIdx.x;
    int tid = threadIdx.x;
    __shared__ float hh[DD];
    __shared__ float sred[4];
    const float* hr = h_buf + (size_t)b * DD;
    float ss = 0.f;
    for (int c = tid; c < DD; c += 256) { float v = hr[c]; ss += v * v; }
    for (int o = 1; o < 64; o <<= 1) ss += __shfl_xor(ss, o, 64);
    if ((tid & 63) == 0) sred[tid >> 6] = ss;
    __syncthreads();
    float sc = rsqrtf((sred[0] + sred[1] + sred[2] + sred[3]) / (float)DD + 1e-6f);
    for (int c = tid; c < DD; c += 256) {
        float v = hr[c] * sc * hnw[c];
        hh[c] = 0.5f * v * (1.f + erff(v * 0.70710678118f));   // exact gelu
    }
    __syncthreads();
    int w = tid >> 6, lane = tid & 63;
    for (int j = w; j < 10; j += 4) {
        float acc = 0.f;
        const float* wrow = h2w + (size_t)j * DD;
        for (int c = lane; c < DD; c += 64) acc += hh[c] * wrow[c];
        for (int o = 1; o < 64; o <<= 1) acc += __shfl_xor(acc, o, 64);
        if (lane == 0) out[b * 10 + j] = acc + h2b[j];
    }
}

// ----------------------------------------------------------------
extern "C" void kernel_launch(void* const* d_in, const int* in_sizes, int n_in,
                              void* d_out, int out_size, void* d_ws, size_t ws_size,
                              hipStream_t stream) {
    const float* x_in      = (const float*)d_in[0];
    const float* norm_w    = (const float*)d_in[1];
    const float* in_proj_w = (const float*)d_in[2];
    const float* conv_w    = (const float*)d_in[3];
    const float* conv_b    = (const float*)d_in[4];
    const float* x_proj_w  = (const float*)d_in[5];
    const float* dt_proj_w = (const float*)d_in[6];
    const float* dt_proj_b = (const float*)d_in[7];
    const float* A_log     = (const float*)d_in[8];
    const float* D_skip    = (const float*)d_in[9];
    const float* out_proj_w= (const float*)d_in[10];
    const float* fnw       = (const float*)d_in[11];
    const float* h1w       = (const float*)d_in[12];
    const float* h1b       = (const float*)d_in[13];
    const float* hnw       = (const float*)d_in[14];
    const float* h2w       = (const float*)d_in[15];
    const float* h2b       = (const float*)d_in[16];
    float* out = (float*)d_out;

    char* ws = (char*)d_ws;
    size_t off = 0;
    auto alloc = [&](size_t bytes) -> void* {
        void* p = ws + off;
        off += (bytes + 255) & ~(size_t)255;
        return p;
    };
    bf16* w_in  = (bf16*)alloc((size_t)4 * 3072 * 768 * 2);
    bf16* w_xp  = (bf16*)alloc((size_t)4 * NXP * DI * 2);
    bf16* w_dt  = (bf16*)alloc((size_t)4 * DI * DTRANK * 2);
    bf16* w_out = (bf16*)alloc((size_t)4 * DD * DI * 2);
    bf16* xn_bf = (bf16*)alloc((size_t)MROWS * DD * 2);
    bf16* xz_bf = (bf16*)alloc((size_t)MROWS * 2 * DI * 2);
    float* xc_f = (float*)alloc((size_t)MROWS * DI * 4);
    bf16* xc_bf = (bf16*)alloc((size_t)MROWS * DI * 2);
    float* gz_f = (float*)alloc((size_t)MROWS * DI * 4);
    float* xdbl = (float*)alloc((size_t)MROWS * NXP * 4);
    bf16* dt_bf = (bf16*)alloc((size_t)MROWS * DTRANK * 2);
    float* delta= (float*)alloc((size_t)MROWS * DI * 4);
    bf16* y_bf  = (bf16*)alloc((size_t)MROWS * DI * 2);
    float* x_buf= (float*)alloc((size_t)MROWS * DD * 4);
    float* Pbuf = (float*)alloc((size_t)NC * BB * DI * DSTATE * 4);
    float* Sbuf = (float*)alloc((size_t)NC * BB * DI * DSTATE * 4);
    float* xnl  = (float*)alloc((size_t)BB * DD * 4);
    float* hbuf = (float*)alloc((size_t)BB * DD * 4);
    float* xp_part = (float*)alloc((size_t)KSPLIT * MROWS * NXP * 4);
    float* op_part = (float*)alloc((size_t)OPKS * MROWS * DD * 4);

    // convert all weights to bf16 (every call; ws is re-poisoned between calls)
    {
        int n1 = 4 * 3072 * 768;   cvt_k<<<(n1 + 255) / 256, 256, 0, stream>>>(in_proj_w,  w_in,  n1);
        int n2 = 4 * NXP * DI;     cvt_k<<<(n2 + 255) / 256, 256, 0, stream>>>(x_proj_w,   w_xp,  n2);
        int n3 = 4 * DI * DTRANK;  cvt_k<<<(n3 + 255) / 256, 256, 0, stream>>>(dt_proj_w,  w_dt,  n3);
        int n4 = 4 * DD * DI;      cvt_k<<<(n4 + 255) / 256, 256, 0, stream>>>(out_proj_w, w_out, n4);
    }

    for (int i = 0; i < 4; i++) {
        const float* x_src = (i == 0) ? x_in : x_buf;
        // 1. rmsnorm -> bf16
        rmsnorm_k<<<MROWS, 256, 0, stream>>>(x_src, norm_w + i * DD, xn_bf);
        // 2. in_proj: (2048 x 3072) = xn @ in_w^T, bf16 out
        gemm_bt<1><<<dim3(MROWS / 128, 3072 / 128), 256, 0, stream>>>(
            xn_bf, w_in + (size_t)i * 3072 * 768, nullptr, xz_bf, nullptr, nullptr,
            MROWS, 2 * DI, DD);
        // 3. causal conv + silu + silu(z) gate precompute
        conv_silu_k<<<(MROWS * DI + 255) / 256, 256, 0, stream>>>(
            xz_bf, conv_w + (size_t)i * DI * 4, conv_b + (size_t)i * DI, xc_f, xc_bf, gz_f);
        // 4. x_proj split-K (512 blocks) + reduce -> xdbl f32 + compact bf16 dt
        gemm_xp<<<dim3(MROWS / 64, KSPLIT), 256, 0, stream>>>(
            xc_bf, w_xp + (size_t)i * NXP * DI, xp_part);
        xp_reduce_k<<<(MROWS * NXP + 255) / 256, 256, 0, stream>>>(xp_part, xdbl, dt_bf);
        // 5. dt_proj + bias + softplus -> delta
        gemm_bt<2><<<dim3(MROWS / 128, DI / 128), 256, 0, stream>>>(
            dt_bf, w_dt + (size_t)i * DI * DTRANK, delta, nullptr,
            dt_proj_b + (size_t)i * DI, nullptr, MROWS, DI, DTRANK);
        // 6a. chunk-local scans -> (P, S)
        scan1_k<<<dim3(DI / 16, BB, NC), 256, 0, stream>>>(
            delta, xc_f, xdbl, A_log + (size_t)i * DI * DSTATE, Pbuf, Sbuf);
        // 6b. compose + local scan + D-skip + precomputed gate -> y bf16
        scan2_k<<<dim3(DI / 16, BB, NC), 256, 0, stream>>>(
            delta, xc_f, gz_f, xdbl, A_log + (size_t)i * DI * DSTATE,
            D_skip + (size_t)i * DI, Pbuf, Sbuf, y_bf);
        // 7. out_proj split-K (384 blocks) -> partials, then +residual reduce
        gemm_bt<5><<<dim3(MROWS / 128, DD / 128, OPKS), 256, 0, stream>>>(
            y_bf, w_out + (size_t)i * DD * DI, op_part, nullptr, nullptr, nullptr,
            MROWS, DD, DI);
        op_reduce_k<<<(MROWS * DD + 255) / 256, 256, 0, stream>>>(op_part, x_src, x_buf);
    }

    head_norm_k<<<BB, 256, 0, stream>>>(x_buf, fnw, xnl);
    head_h1_k<<<dim3(BB, DD / 64), 256, 0, stream>>>(xnl, h1w, h1b, hbuf);
    head_out_k<<<BB, 256, 0, stream>>>(hbuf, hnw, h2w, h2b, out);
}

// Round 10
// 797.570 us; speedup vs baseline: 2.5714x; 1.0158x over previous
//
#include <hip/hip_runtime.h>
#include <hip/hip_bf16.h>
#include <math.h>

typedef __bf16 bf16;
typedef __bf16 bf16x8 __attribute__((ext_vector_type(8)));
typedef float floatx4 __attribute__((ext_vector_type(4)));

#define BB 2
#define LL 1024
#define DD 768
#define DI 1536
#define MROWS 2048   // B*L
#define NXP 80       // dt_rank + 2*d_state
#define DTRANK 48
#define DTPAD 64     // dt K padded to 64 for global_load_lds staging
#define DSTATE 16
#define NC 16        // scan chunks
#define CLEN 64      // scan chunk length (NC*CLEN == LL)
#define KSPLIT 16    // x_proj split-K factor (K-seg = 96)
#define OPKS 4       // out_proj split-K factor (K-seg = 384)

// async global->LDS, 16 B per lane; lds dest must be wave-uniform base (+lane*16)
__device__ __forceinline__ void ld16(void* lds, const void* g) {
    __builtin_amdgcn_global_load_lds(
        (const __attribute__((address_space(1))) void*)g,
        (__attribute__((address_space(3))) void*)lds, 16, 0, 0);
}

// drain this wave's outstanding async global_load_lds before signalling barrier.
// REQUIRED: global_load_lds is vmcnt-tracked with no VGPR def — the compiler may
// not emit vmcnt(0) before s_barrier on its own (R9 post-timing divergence).
__device__ __forceinline__ void wait_vm0() {
    asm volatile("s_waitcnt vmcnt(0)" ::: "memory");
}

// DPP row-reduce over 16 lanes (one DPP row): lane 0 of each row gets the sum.
__device__ __forceinline__ float row16_sum(float x) {
    float t;
    t = __int_as_float(__builtin_amdgcn_update_dpp(0, __float_as_int(x), 0x111, 0xF, 0xF, true)); x += t;
    t = __int_as_float(__builtin_amdgcn_update_dpp(0, __float_as_int(x), 0x112, 0xF, 0xF, true)); x += t;
    t = __int_as_float(__builtin_amdgcn_update_dpp(0, __float_as_int(x), 0x114, 0xF, 0xF, true)); x += t;
    t = __int_as_float(__builtin_amdgcn_update_dpp(0, __float_as_int(x), 0x118, 0xF, 0xF, true)); x += t;
    return x;
}

// ---------------------------------------------------------------- cvt f32->bf16
__global__ __launch_bounds__(256) void cvt_k(const float* __restrict__ in,
                                             bf16* __restrict__ out, int n) {
    int i = blockIdx.x * 256 + threadIdx.x;
    if (i < n) out[i] = (bf16)in[i];
}

// cvt dt_proj_w (rows x 48) -> padded (rows x 64), zero cols 48..63
__global__ __launch_bounds__(256) void cvt_dt_k(const float* __restrict__ in,
                                                bf16* __restrict__ out, int n) {
    int i = blockIdx.x * 256 + threadIdx.x;
    if (i >= n) return;
    int row = i >> 6, c = i & 63;
    out[i] = (c < DTRANK) ? (bf16)in[row * DTRANK + c] : (bf16)0.f;
}

// ---------------------------------------------------------------- rmsnorm -> bf16
__global__ __launch_bounds__(256) void rmsnorm_k(const float* __restrict__ x,
                                                 const float* __restrict__ w,
                                                 bf16* __restrict__ out) {
    int row = blockIdx.x;
    const float* xr = x + (size_t)row * DD;
    int tid = threadIdx.x;
    float v[3]; float ss = 0.f;
    for (int j = 0; j < 3; j++) { v[j] = xr[tid + j * 256]; ss += v[j] * v[j]; }
    for (int o = 1; o < 64; o <<= 1) ss += __shfl_xor(ss, o, 64);
    __shared__ float sred[4];
    if ((tid & 63) == 0) sred[tid >> 6] = ss;
    __syncthreads();
    float scale = rsqrtf((sred[0] + sred[1] + sred[2] + sred[3]) / (float)DD + 1e-6f);
    for (int j = 0; j < 3; j++) {
        int c = tid + j * 256;
        out[(size_t)row * DD + c] = (bf16)(v[j] * scale * w[c]);
    }
}

// ---------------------------------------------------------------- GEMM: C = A @ W^T
// A: M x K bf16, W: N x K bf16, both row-major. M%128==0, N%128==0, K%32==0.
// Staging via global_load_lds 16B (unpadded LDS, m97 pattern + explicit vmcnt drain).
// MODE 1: store bf16 | MODE 2: +bias, softplus, f32 | MODE 5: split-K partials f32
template <int MODE>
__global__ __launch_bounds__(256) void gemm_bt(const bf16* __restrict__ A,
                                               const bf16* __restrict__ W,
                                               float* __restrict__ Cf,
                                               bf16* __restrict__ Cb,
                                               const float* __restrict__ bias,
                                               int M, int N, int K) {
    __shared__ bf16 As[128][32];
    __shared__ bf16 Ws[128][32];
    const int tid  = threadIdx.x;
    const int m0   = blockIdx.x * 128;
    const int n0   = blockIdx.y * 128;
    const int wave = tid >> 6;
    const int lane = tid & 63;
    const int wm   = (wave >> 1) * 64;
    const int wn   = (wave & 1) * 64;
    const int lrow = lane & 15;
    const int quad = lane >> 4;

    int kbeg = 0, kend = K;
    if constexpr (MODE == 5) {
        int kseg = K / gridDim.z;
        kbeg = blockIdx.z * kseg;
        kend = kbeg + kseg;
        Cf  += (size_t)blockIdx.z * M * N;
    }

    floatx4 acc[4][4];
    for (int mi = 0; mi < 4; mi++)
        for (int ni = 0; ni < 4; ni++) acc[mi][ni] = (floatx4){0.f, 0.f, 0.f, 0.f};

    const int r0  = tid >> 2;        // 0..63
    const int r1  = r0 + 64;         // 64..127
    const int seg = (tid & 3) * 8;   // 0,8,16,24
    // wave-uniform LDS bases: lane dest = base + lane*16 B == &As[r][seg]
    char* asb0 = (char*)As + wave * 1024;
    char* asb1 = (char*)As + 4096 + wave * 1024;
    char* wsb0 = (char*)Ws + wave * 1024;
    char* wsb1 = (char*)Ws + 4096 + wave * 1024;

    for (int kb = kbeg; kb < kend; kb += 32) {
        int gk = kb + seg;
        __syncthreads();   // previous iteration's LDS reads done
        ld16(asb0, A + (size_t)(m0 + r0) * K + gk);
        ld16(asb1, A + (size_t)(m0 + r1) * K + gk);
        ld16(wsb0, W + (size_t)(n0 + r0) * K + gk);
        ld16(wsb1, W + (size_t)(n0 + r1) * K + gk);
        wait_vm0();        // this wave's async LDS fills landed
        __syncthreads();   // all waves' fills landed -> tiles ready
        bf16x8 af[4], wf[4];
        for (int mi = 0; mi < 4; mi++) af[mi] = *(const bf16x8*)&As[wm + mi * 16 + lrow][quad * 8];
        for (int ni = 0; ni < 4; ni++) wf[ni] = *(const bf16x8*)&Ws[wn + ni * 16 + lrow][quad * 8];
        for (int mi = 0; mi < 4; mi++)
            for (int ni = 0; ni < 4; ni++)
                acc[mi][ni] = __builtin_amdgcn_mfma_f32_16x16x32_bf16(af[mi], wf[ni], acc[mi][ni], 0, 0, 0);
    }
    // epilogue: D row = quad*4 + r, col = lrow (verified gfx950 C/D layout)
    for (int mi = 0; mi < 4; mi++) {
        int rowb = m0 + wm + mi * 16 + quad * 4;
        for (int ni = 0; ni < 4; ni++) {
            int col = n0 + wn + ni * 16 + lrow;
            for (int r = 0; r < 4; r++) {
                int row = rowb + r;
                float v = acc[mi][ni][r];
                if constexpr (MODE == 2) {
                    v += bias[col];
                    v = (v > 20.f) ? v : log1pf(__expf(v));
                }
                if constexpr (MODE == 1) Cb[(size_t)row * N + col] = (bf16)v;
                else                     Cf[(size_t)row * N + col] = v;
            }
        }
    }
}

// reduce out_proj split-K partials + residual -> x_buf f32
__global__ __launch_bounds__(256) void op_reduce_k(const float* __restrict__ part,
                                                   const float* __restrict__ resid,
                                                   float* __restrict__ xout) {
    int idx = blockIdx.x * 256 + threadIdx.x;
    if (idx >= MROWS * DD) return;
    float s = resid[idx];
    for (int j = 0; j < OPKS; j++) s += part[(size_t)j * MROWS * DD + idx];
    xout[idx] = s;
}

// ---------------------------------------------------------------- x_proj split-K GEMM
__global__ __launch_bounds__(256) void gemm_xp(const bf16* __restrict__ A,
                                               const bf16* __restrict__ W,
                                               float* __restrict__ part) {
    __shared__ bf16 As[64][40];
    __shared__ bf16 Ws[128][40];
    const int tid  = threadIdx.x;
    const int m0   = blockIdx.x * 64;
    const int ks   = blockIdx.y;
    const int k0   = ks * (DI / KSPLIT);   // 96-elem K segment
    const int wave = tid >> 6;
    const int lane = tid & 63;
    const int lrow = lane & 15;
    const int quad = lane >> 4;
    const int wm   = wave * 16;

    floatx4 acc[5];
    for (int ni = 0; ni < 5; ni++) acc[ni] = (floatx4){0.f, 0.f, 0.f, 0.f};

    const int ra  = tid >> 2;        // 0..63
    const int rw1 = ra + 64;         // 64..127
    const int seg = (tid & 3) * 8;

    for (int kb = 0; kb < DI / KSPLIT; kb += 32) {
        int gk = k0 + kb + seg;
        bf16x8 va = *(const bf16x8*)(A + (size_t)(m0 + ra) * DI + gk);
        bf16x8 vw0, vw1;
        if (ra < NXP) vw0 = *(const bf16x8*)(W + (size_t)ra * DI + gk);
        else          for (int j = 0; j < 8; j++) vw0[j] = (bf16)0.f;
        if (rw1 < NXP) vw1 = *(const bf16x8*)(W + (size_t)rw1 * DI + gk);
        else           for (int j = 0; j < 8; j++) vw1[j] = (bf16)0.f;
        __syncthreads();
        *(bf16x8*)&As[ra][seg]  = va;
        *(bf16x8*)&Ws[ra][seg]  = vw0;
        *(bf16x8*)&Ws[rw1][seg] = vw1;
        __syncthreads();
        bf16x8 af = *(const bf16x8*)&As[wm + lrow][quad * 8];
        for (int ni = 0; ni < 5; ni++) {
            bf16x8 wf = *(const bf16x8*)&Ws[ni * 16 + lrow][quad * 8];
            acc[ni] = __builtin_amdgcn_mfma_f32_16x16x32_bf16(af, wf, acc[ni], 0, 0, 0);
        }
    }
    float* pout = part + (size_t)ks * MROWS * NXP;
    for (int ni = 0; ni < 5; ni++) {
        int col = ni * 16 + lrow;                 // 0..79
        for (int r = 0; r < 4; r++) {
            int row = m0 + wm + quad * 4 + r;
            pout[(size_t)row * NXP + col] = acc[ni][r];
        }
    }
}

// reduce split-K partials -> xdbl f32 + padded bf16 dt (stride DTPAD, zero tail)
__global__ __launch_bounds__(256) void xp_reduce_k(const float* __restrict__ part,
                                                   float* __restrict__ xdbl,
                                                   bf16* __restrict__ dtbf) {
    int idx = blockIdx.x * 256 + threadIdx.x;
    if (idx >= MROWS * NXP) return;
    float s = 0.f;
    for (int j = 0; j < KSPLIT; j++) s += part[(size_t)j * MROWS * NXP + idx];
    xdbl[idx] = s;
    int m = idx / NXP, c = idx - m * NXP;
    if (c < DTRANK)      dtbf[m * DTPAD + c] = (bf16)s;
    else if (c < DTPAD)  dtbf[m * DTPAD + c] = (bf16)0.f;
}

// ---------------------------------------------------------------- causal depthwise conv + silu + gate precompute
__global__ __launch_bounds__(256) void conv_silu_k(const bf16* __restrict__ xz,
                                                   const float* __restrict__ cw,
                                                   const float* __restrict__ cb,
                                                   float* __restrict__ xc,
                                                   bf16* __restrict__ xcb,
                                                   float* __restrict__ gz) {
    int idx = blockIdx.x * 256 + threadIdx.x;
    if (idx >= MROWS * DI) return;
    int d = idx % DI;
    int m = idx / DI;
    int l = m & (LL - 1);
    float acc = cb[d];
    for (int k = 0; k < 4; k++) {
        int lp = l - 3 + k;
        if (lp >= 0) acc += (float)xz[(size_t)(m - 3 + k) * (2 * DI) + d] * cw[d * 4 + k];
    }
    float s = acc / (1.f + __expf(-acc));
    xc[idx]  = s;
    xcb[idx] = (bf16)s;
    float zv = (float)xz[(size_t)m * (2 * DI) + DI + d];
    gz[idx] = zv / (1.f + __expf(-zv));
}

// ---------------------------------------------------------------- chunk-parallel selective scan
__global__ __launch_bounds__(256) void scan1_k(const float* __restrict__ delta,
                                               const float* __restrict__ xc,
                                               const float* __restrict__ xdbl,
                                               const float* __restrict__ A_log,
                                               float* __restrict__ Pbuf,
                                               float* __restrict__ Sbuf) {
    int b  = blockIdx.y;
    int d0 = blockIdx.x * 16;
    int c  = blockIdx.z;
    int tid = threadIdx.x;
    int dl = tid >> 4;
    int n  = tid & 15;
    int d  = d0 + dl;
    float a = -__expf(A_log[d * DSTATE + n]);
    __shared__ float2 sdx[CLEN][16];   // (delta, xc)
    __shared__ float  sb[CLEN][16];
    int l0 = c * CLEN;
    for (int idx = tid; idx < CLEN * 16; idx += 256) {
        int i = idx >> 4, dd = idx & 15;
        size_t row = (size_t)(b * LL + l0 + i);
        sdx[i][dd] = make_float2(delta[row * DI + d0 + dd], xc[row * DI + d0 + dd]);
        sb[i][dd]  = xdbl[row * NXP + DTRANK + dd];
    }
    __syncthreads();
    float h = 0.f, sd = 0.f;
    for (int i = 0; i < CLEN; i++) {
        float2 dx = sdx[i][dl];
        float Bv  = sb[i][n];
        h = __expf(dx.x * a) * h + dx.x * Bv * dx.y;
        sd += dx.x;
    }
    size_t o = (((size_t)c * BB + b) * DI + d) * DSTATE + n;
    Pbuf[o] = __expf(a * sd);
    Sbuf[o] = h;
}

__global__ __launch_bounds__(256) void scan2_k(const float* __restrict__ delta,
                                               const float* __restrict__ xc,
                                               const float* __restrict__ gz,
                                               const float* __restrict__ xdbl,
                                               const float* __restrict__ A_log,
                                               const float* __restrict__ Dskip,
                                               const float* __restrict__ Pbuf,
                                               const float* __restrict__ Sbuf,
                                               bf16* __restrict__ ybf) {
    int b  = blockIdx.y;
    int d0 = blockIdx.x * 16;
    int c  = blockIdx.z;
    int tid = threadIdx.x;
    int dl = tid >> 4;
    int n  = tid & 15;
    int d  = d0 + dl;
    float a     = -__expf(A_log[d * DSTATE + n]);
    float dskip = Dskip[d];
    float h = 0.f;
    {
        size_t stride = (size_t)BB * DI * DSTATE;
        size_t base   = ((size_t)b * DI + d) * DSTATE + n;
        for (int j = 0; j < c; j++)
            h = Pbuf[(size_t)j * stride + base] * h + Sbuf[(size_t)j * stride + base];
    }
    __shared__ float4 sdxz[CLEN][16];   // (delta, xc, gz, pad)
    __shared__ float2 sbc2[CLEN][16];   // (B_n, C_n)
    int l0 = c * CLEN;
    for (int idx = tid; idx < CLEN * 16; idx += 256) {
        int i = idx >> 4, dd = idx & 15;
        size_t row = (size_t)(b * LL + l0 + i);
        sdxz[i][dd] = make_float4(delta[row * DI + d0 + dd],
                                  xc[row * DI + d0 + dd],
                                  gz[row * DI + d0 + dd],
                                  0.f);
        sbc2[i][dd] = make_float2(xdbl[row * NXP + DTRANK + dd],
                                  xdbl[row * NXP + DTRANK + DSTATE + dd]);
    }
    __syncthreads();
    for (int i = 0; i < CLEN; i++) {
        float4 dxz = sdxz[i][dl];
        float2 bc  = sbc2[i][n];
        h = __expf(dxz.x * a) * h + dxz.x * bc.x * dxz.y;
        float yp = row16_sum(h * bc.y);
        if (n == 0) {
            float yv = (yp + dxz.y * dskip) * dxz.z;
            ybf[(size_t)(b * LL + l0 + i) * DI + d] = (bf16)yv;
        }
    }
}

// ---------------------------------------------------------------- head
__global__ __launch_bounds__(256) void head_norm_k(const float* __restrict__ x,
                                                   const float* __restrict__ fnw,
                                                   float* __restrict__ xn_buf) {
    int b = blockIdx.x;
    int tid = threadIdx.x;
    const float* xr = x + ((size_t)b * LL + (LL - 1)) * DD;
    __shared__ float sred[4];
    float v[3]; float ss = 0.f;
    for (int j = 0; j < 3; j++) { v[j] = xr[tid + j * 256]; ss += v[j] * v[j]; }
    for (int o = 1; o < 64; o <<= 1) ss += __shfl_xor(ss, o, 64);
    if ((tid & 63) == 0) sred[tid >> 6] = ss;
    __syncthreads();
    float scale = rsqrtf((sred[0] + sred[1] + sred[2] + sred[3]) / (float)DD + 1e-6f);
    for (int j = 0; j < 3; j++) {
        int c = tid + j * 256;
        xn_buf[(size_t)b * DD + c] = v[j] * scale * fnw[c];
    }
}

__global__ __launch_bounds__(256) void head_h1_k(const float* __restrict__ xn_buf,
                                                 const float* __restrict__ h1w,
                                                 const float* __restrict__ h1b,
                                                 float* __restrict__ h_buf) {
    int b  = blockIdx.x;
    int o0 = blockIdx.y * 64;
    int tid = threadIdx.x;
    __shared__ float sx[DD];
    for (int c = tid; c < DD; c += 256) sx[c] = xn_buf[(size_t)b * DD + c];
    __syncthreads();
    int wave = tid >> 6, lane = tid & 63;
    for (int j = 0; j < 16; j++) {
        int o = o0 + wave * 16 + j;
        const float* wrow = h1w + (size_t)o * DD;
        float acc = 0.f;
        for (int k = 0; k < 12; k++) {
            int c = lane + 64 * k;
            acc += wrow[c] * sx[c];
        }
        for (int off = 1; off < 64; off <<= 1) acc += __shfl_xor(acc, off, 64);
        if (lane == 0) h_buf[(size_t)b * DD + o] = acc + h1b[o];
    }
}

__global__ __launch_bounds__(256) void head_out_k(const float* __restrict__ h_buf,
                                                  const float* __restrict__ hnw,
                                                  const float* __restrict__ h2w,
                                                  const float* __restrict__ h2b,
                                                  float* __restrict__ out) {
    int b = blockIdx.x;
    int tid = threadIdx.x;
    __shared__ float hh[DD];
    __shared__ float sred[4];
    const float* hr = h_buf + (size_t)b * DD;
    float ss = 0.f;
    for (int c = tid; c < DD; c += 256) { float v = hr[c]; ss += v * v; }
    for (int o = 1; o < 64; o <<= 1) ss += __shfl_xor(ss, o, 64);
    if ((tid & 63) == 0) sred[tid >> 6] = ss;
    __syncthreads();
    float sc = rsqrtf((sred[0] + sred[1] + sred[2] + sred[3]) / (float)DD + 1e-6f);
    for (int c = tid; c < DD; c += 256) {
        float v = hr[c] * sc * hnw[c];
        hh[c] = 0.5f * v * (1.f + erff(v * 0.70710678118f));
    }
    __syncthreads();
    int w = tid >> 6, lane = tid & 63;
    for (int j = w; j < 10; j += 4) {
        float acc = 0.f;
        const float* wrow = h2w + (size_t)j * DD;
        for (int c = lane; c < DD; c += 64) acc += hh[c] * wrow[c];
        for (int o = 1; o < 64; o <<= 1) acc += __shfl_xor(acc, o, 64);
        if (lane == 0) out[b * 10 + j] = acc + h2b[j];
    }
}

// ----------------------------------------------------------------
extern "C" void kernel_launch(void* const* d_in, const int* in_sizes, int n_in,
                              void* d_out, int out_size, void* d_ws, size_t ws_size,
                              hipStream_t stream) {
    const float* x_in      = (const float*)d_in[0];
    const float* norm_w    = (const float*)d_in[1];
    const float* in_proj_w = (const float*)d_in[2];
    const float* conv_w    = (const float*)d_in[3];
    const float* conv_b    = (const float*)d_in[4];
    const float* x_proj_w  = (const float*)d_in[5];
    const float* dt_proj_w = (const float*)d_in[6];
    const float* dt_proj_b = (const float*)d_in[7];
    const float* A_log     = (const float*)d_in[8];
    const float* D_skip    = (const float*)d_in[9];
    const float* out_proj_w= (const float*)d_in[10];
    const float* fnw       = (const float*)d_in[11];
    const float* h1w       = (const float*)d_in[12];
    const float* h1b       = (const float*)d_in[13];
    const float* hnw       = (const float*)d_in[14];
    const float* h2w       = (const float*)d_in[15];
    const float* h2b       = (const float*)d_in[16];
    float* out = (float*)d_out;

    char* ws = (char*)d_ws;
    size_t off = 0;
    auto alloc = [&](size_t bytes) -> void* {
        void* p = ws + off;
        off += (bytes + 255) & ~(size_t)255;
        return p;
    };
    bf16* w_in  = (bf16*)alloc((size_t)4 * 3072 * 768 * 2);
    bf16* w_xp  = (bf16*)alloc((size_t)4 * NXP * DI * 2);
    bf16* w_dt  = (bf16*)alloc((size_t)4 * DI * DTPAD * 2);
    bf16* w_out = (bf16*)alloc((size_t)4 * DD * DI * 2);
    bf16* xn_bf = (bf16*)alloc((size_t)MROWS * DD * 2);
    bf16* xz_bf = (bf16*)alloc((size_t)MROWS * 2 * DI * 2);
    float* xc_f = (float*)alloc((size_t)MROWS * DI * 4);
    bf16* xc_bf = (bf16*)alloc((size_t)MROWS * DI * 2);
    float* gz_f = (float*)alloc((size_t)MROWS * DI * 4);
    float* xdbl = (float*)alloc((size_t)MROWS * NXP * 4);
    bf16* dt_bf = (bf16*)alloc((size_t)MROWS * DTPAD * 2);
    float* delta= (float*)alloc((size_t)MROWS * DI * 4);
    bf16* y_bf  = (bf16*)alloc((size_t)MROWS * DI * 2);
    float* x_buf= (float*)alloc((size_t)MROWS * DD * 4);
    float* Pbuf = (float*)alloc((size_t)NC * BB * DI * DSTATE * 4);
    float* Sbuf = (float*)alloc((size_t)NC * BB * DI * DSTATE * 4);
    float* xnl  = (float*)alloc((size_t)BB * DD * 4);
    float* hbuf = (float*)alloc((size_t)BB * DD * 4);
    float* xp_part = (float*)alloc((size_t)KSPLIT * MROWS * NXP * 4);
    float* op_part = (float*)alloc((size_t)OPKS * MROWS * DD * 4);

    // convert all weights to bf16 (every call; ws is re-poisoned between calls)
    {
        int n1 = 4 * 3072 * 768;   cvt_k<<<(n1 + 255) / 256, 256, 0, stream>>>(in_proj_w,  w_in,  n1);
        int n2 = 4 * NXP * DI;     cvt_k<<<(n2 + 255) / 256, 256, 0, stream>>>(x_proj_w,   w_xp,  n2);
        int n3 = 4 * DI * DTPAD;   cvt_dt_k<<<(n3 + 255) / 256, 256, 0, stream>>>(dt_proj_w, w_dt, n3);
        int n4 = 4 * DD * DI;      cvt_k<<<(n4 + 255) / 256, 256, 0, stream>>>(out_proj_w, w_out, n4);
    }

    for (int i = 0; i < 4; i++) {
        const float* x_src = (i == 0) ? x_in : x_buf;
        // 1. rmsnorm -> bf16
        rmsnorm_k<<<MROWS, 256, 0, stream>>>(x_src, norm_w + i * DD, xn_bf);
        // 2. in_proj: (2048 x 3072), bf16 out
        gemm_bt<1><<<dim3(MROWS / 128, 3072 / 128), 256, 0, stream>>>(
            xn_bf, w_in + (size_t)i * 3072 * 768, nullptr, xz_bf, nullptr,
            MROWS, 2 * DI, DD);
        // 3. causal conv + silu + silu(z) gate precompute
        conv_silu_k<<<(MROWS * DI + 255) / 256, 256, 0, stream>>>(
            xz_bf, conv_w + (size_t)i * DI * 4, conv_b + (size_t)i * DI, xc_f, xc_bf, gz_f);
        // 4. x_proj split-K + reduce -> xdbl f32 + padded bf16 dt
        gemm_xp<<<dim3(MROWS / 64, KSPLIT), 256, 0, stream>>>(
            xc_bf, w_xp + (size_t)i * NXP * DI, xp_part);
        xp_reduce_k<<<(MROWS * NXP + 255) / 256, 256, 0, stream>>>(xp_part, xdbl, dt_bf);
        // 5. dt_proj (K padded to 64) + bias + softplus -> delta
        gemm_bt<2><<<dim3(MROWS / 128, DI / 128), 256, 0, stream>>>(
            dt_bf, w_dt + (size_t)i * DI * DTPAD, delta, nullptr,
            dt_proj_b + (size_t)i * DI, MROWS, DI, DTPAD);
        // 6a. chunk-local scans -> (P, S)
        scan1_k<<<dim3(DI / 16, BB, NC), 256, 0, stream>>>(
            delta, xc_f, xdbl, A_log + (size_t)i * DI * DSTATE, Pbuf, Sbuf);
        // 6b. compose + local scan + D-skip + precomputed gate -> y bf16
        scan2_k<<<dim3(DI / 16, BB, NC), 256, 0, stream>>>(
            delta, xc_f, gz_f, xdbl, A_log + (size_t)i * DI * DSTATE,
            D_skip + (size_t)i * DI, Pbuf, Sbuf, y_bf);
        // 7. out_proj split-K -> partials, then +residual reduce
        gemm_bt<5><<<dim3(MROWS / 128, DD / 128, OPKS), 256, 0, stream>>>(
            y_bf, w_out + (size_t)i * DD * DI, op_part, nullptr, nullptr,
            MROWS, DD, DI);
        op_reduce_k<<<(MROWS * DD + 255) / 256, 256, 0, stream>>>(op_part, x_src, x_buf);
    }

    head_norm_k<<<BB, 256, 0, stream>>>(x_buf, fnw, xnl);
    head_h1_k<<<dim3(BB, DD / 64), 256, 0, stream>>>(xnl, h1w, h1b, hbuf);
    head_out_k<<<BB, 256, 0, stream>>>(hbuf, hnw, h2w, h2b, out);
}

// Round 11
// 747.950 us; speedup vs baseline: 2.7420x; 1.0663x over previous
//
#include <hip/hip_runtime.h>
#include <hip/hip_bf16.h>
#include <math.h>

typedef __bf16 bf16;
typedef __bf16 bf16x4 __attribute__((ext_vector_type(4)));
typedef __bf16 bf16x8 __attribute__((ext_vector_type(8)));
typedef float floatx4 __attribute__((ext_vector_type(4)));

#define BB 2
#define LL 1024
#define DD 768
#define DI 1536
#define MROWS 2048   // B*L
#define NXP 80       // dt_rank + 2*d_state
#define DTRANK 48
#define DTPAD 64     // dt K padded to 64 for global_load_lds staging
#define DSTATE 16
#define NC 16        // scan chunks
#define CLEN 64      // scan chunk length (NC*CLEN == LL)
#define KSPLIT 16    // x_proj split-K factor (K-seg = 96)
#define OPKS 4       // out_proj split-K factor (K-seg = 384)

// async global->LDS, 16 B per lane; lds dest must be wave-uniform base (+lane*16)
__device__ __forceinline__ void ld16(void* lds, const void* g) {
    __builtin_amdgcn_global_load_lds(
        (const __attribute__((address_space(1))) void*)g,
        (__attribute__((address_space(3))) void*)lds, 16, 0, 0);
}

// drain this wave's outstanding async global_load_lds before signalling barrier.
// REQUIRED: global_load_lds is vmcnt-tracked with no VGPR def (R9 divergence).
__device__ __forceinline__ void wait_vm0() {
    asm volatile("s_waitcnt vmcnt(0)" ::: "memory");
}

// DPP row-reduce over 16 lanes (one DPP row): lane 0 of each row gets the sum.
__device__ __forceinline__ float row16_sum(float x) {
    float t;
    t = __int_as_float(__builtin_amdgcn_update_dpp(0, __float_as_int(x), 0x111, 0xF, 0xF, true)); x += t;
    t = __int_as_float(__builtin_amdgcn_update_dpp(0, __float_as_int(x), 0x112, 0xF, 0xF, true)); x += t;
    t = __int_as_float(__builtin_amdgcn_update_dpp(0, __float_as_int(x), 0x114, 0xF, 0xF, true)); x += t;
    t = __int_as_float(__builtin_amdgcn_update_dpp(0, __float_as_int(x), 0x118, 0xF, 0xF, true)); x += t;
    return x;
}

__device__ __forceinline__ float bfbits_lo(unsigned u) { return __int_as_float((u & 0xffffu) << 16); }
__device__ __forceinline__ float bfbits_hi(unsigned u) { return __int_as_float(u & 0xffff0000u); }

// ---------------------------------------------------------------- all weight cvt in one kernel
#define N1 (4 * 3072 * 768)
#define N2 (4 * NXP * DI)
#define N3 (4 * DI * DTPAD)
#define N4 (4 * DD * DI)
__global__ __launch_bounds__(256) void cvt_all_k(const float* __restrict__ in_proj_w,
                                                 const float* __restrict__ x_proj_w,
                                                 const float* __restrict__ dt_proj_w,
                                                 const float* __restrict__ out_proj_w,
                                                 bf16* __restrict__ w_in,
                                                 bf16* __restrict__ w_xp,
                                                 bf16* __restrict__ w_dt,
                                                 bf16* __restrict__ w_out) {
    int i = blockIdx.x * 256 + threadIdx.x;
    if (i < N1) { w_in[i] = (bf16)in_proj_w[i]; return; }
    i -= N1;
    if (i < N2) { w_xp[i] = (bf16)x_proj_w[i]; return; }
    i -= N2;
    if (i < N3) {
        int row = i >> 6, c = i & 63;
        w_dt[i] = (c < DTRANK) ? (bf16)dt_proj_w[row * DTRANK + c] : (bf16)0.f;
        return;
    }
    i -= N3;
    if (i < N4) w_out[i] = (bf16)out_proj_w[i];
}

// ---------------------------------------------------------------- rmsnorm -> bf16 (layer 0 only)
__global__ __launch_bounds__(256) void rmsnorm_k(const float* __restrict__ x,
                                                 const float* __restrict__ w,
                                                 bf16* __restrict__ out) {
    int row = blockIdx.x;
    const float* xr = x + (size_t)row * DD;
    int tid = threadIdx.x;
    float v[3]; float ss = 0.f;
    for (int j = 0; j < 3; j++) { v[j] = xr[tid + j * 256]; ss += v[j] * v[j]; }
    for (int o = 1; o < 64; o <<= 1) ss += __shfl_xor(ss, o, 64);
    __shared__ float sred[4];
    if ((tid & 63) == 0) sred[tid >> 6] = ss;
    __syncthreads();
    float scale = rsqrtf((sred[0] + sred[1] + sred[2] + sred[3]) / (float)DD + 1e-6f);
    for (int j = 0; j < 3; j++) {
        int c = tid + j * 256;
        out[(size_t)row * DD + c] = (bf16)(v[j] * scale * w[c]);
    }
}

// ---------------------------------------------------------------- GEMM: C = A @ W^T
// Staging via global_load_lds 16B (m97 pattern + explicit vmcnt drain).
// MODE 1: store bf16 | MODE 2: +bias, softplus, f32 | MODE 5: split-K partials f32
template <int MODE>
__global__ __launch_bounds__(256) void gemm_bt(const bf16* __restrict__ A,
                                               const bf16* __restrict__ W,
                                               float* __restrict__ Cf,
                                               bf16* __restrict__ Cb,
                                               const float* __restrict__ bias,
                                               int M, int N, int K) {
    __shared__ bf16 As[128][32];
    __shared__ bf16 Ws[128][32];
    const int tid  = threadIdx.x;
    const int m0   = blockIdx.x * 128;
    const int n0   = blockIdx.y * 128;
    const int wave = tid >> 6;
    const int lane = tid & 63;
    const int wm   = (wave >> 1) * 64;
    const int wn   = (wave & 1) * 64;
    const int lrow = lane & 15;
    const int quad = lane >> 4;

    int kbeg = 0, kend = K;
    if constexpr (MODE == 5) {
        int kseg = K / gridDim.z;
        kbeg = blockIdx.z * kseg;
        kend = kbeg + kseg;
        Cf  += (size_t)blockIdx.z * M * N;
    }

    floatx4 acc[4][4];
    for (int mi = 0; mi < 4; mi++)
        for (int ni = 0; ni < 4; ni++) acc[mi][ni] = (floatx4){0.f, 0.f, 0.f, 0.f};

    const int r0  = tid >> 2;        // 0..63
    const int r1  = r0 + 64;         // 64..127
    const int seg = (tid & 3) * 8;   // 0,8,16,24
    char* asb0 = (char*)As + wave * 1024;
    char* asb1 = (char*)As + 4096 + wave * 1024;
    char* wsb0 = (char*)Ws + wave * 1024;
    char* wsb1 = (char*)Ws + 4096 + wave * 1024;

    for (int kb = kbeg; kb < kend; kb += 32) {
        int gk = kb + seg;
        __syncthreads();   // previous iteration's LDS reads done
        ld16(asb0, A + (size_t)(m0 + r0) * K + gk);
        ld16(asb1, A + (size_t)(m0 + r1) * K + gk);
        ld16(wsb0, W + (size_t)(n0 + r0) * K + gk);
        ld16(wsb1, W + (size_t)(n0 + r1) * K + gk);
        wait_vm0();        // this wave's async LDS fills landed
        __syncthreads();   // all waves' fills landed -> tiles ready
        bf16x8 af[4], wf[4];
        for (int mi = 0; mi < 4; mi++) af[mi] = *(const bf16x8*)&As[wm + mi * 16 + lrow][quad * 8];
        for (int ni = 0; ni < 4; ni++) wf[ni] = *(const bf16x8*)&Ws[wn + ni * 16 + lrow][quad * 8];
        for (int mi = 0; mi < 4; mi++)
            for (int ni = 0; ni < 4; ni++)
                acc[mi][ni] = __builtin_amdgcn_mfma_f32_16x16x32_bf16(af[mi], wf[ni], acc[mi][ni], 0, 0, 0);
    }
    for (int mi = 0; mi < 4; mi++) {
        int rowb = m0 + wm + mi * 16 + quad * 4;
        for (int ni = 0; ni < 4; ni++) {
            int col = n0 + wn + ni * 16 + lrow;
            for (int r = 0; r < 4; r++) {
                int row = rowb + r;
                float v = acc[mi][ni][r];
                if constexpr (MODE == 2) {
                    v += bias[col];
                    v = (v > 20.f) ? v : log1pf(__expf(v));
                }
                if constexpr (MODE == 1) Cb[(size_t)row * N + col] = (bf16)v;
                else                     Cf[(size_t)row * N + col] = v;
            }
        }
    }
}

// ---------------------------------------------------------------- out_proj partials + residual + NEXT layer rmsnorm (fused)
__global__ __launch_bounds__(256) void op_reduce_norm_k(const float* __restrict__ part,
                                                        const float* __restrict__ resid,
                                                        const float* __restrict__ nw,
                                                        float* __restrict__ xout,
                                                        bf16* __restrict__ xnb) {
    int row = blockIdx.x;
    int tid = threadIdx.x;
    float v[3]; float ss = 0.f;
    for (int j = 0; j < 3; j++) {
        int c = tid + j * 256;
        size_t idx = (size_t)row * DD + c;
        float s = resid[idx];
        for (int ks = 0; ks < OPKS; ks++) s += part[(size_t)ks * MROWS * DD + idx];
        v[j] = s;
        xout[idx] = s;
        ss += s * s;
    }
    for (int o = 1; o < 64; o <<= 1) ss += __shfl_xor(ss, o, 64);
    __shared__ float sred[4];
    if ((tid & 63) == 0) sred[tid >> 6] = ss;
    __syncthreads();
    float scale = rsqrtf((sred[0] + sred[1] + sred[2] + sred[3]) / (float)DD + 1e-6f);
    for (int j = 0; j < 3; j++) {
        int c = tid + j * 256;
        xnb[(size_t)row * DD + c] = (bf16)(v[j] * scale * nw[c]);
    }
}

// ---------------------------------------------------------------- x_proj split-K GEMM
__global__ __launch_bounds__(256) void gemm_xp(const bf16* __restrict__ A,
                                               const bf16* __restrict__ W,
                                               float* __restrict__ part) {
    __shared__ bf16 As[64][40];
    __shared__ bf16 Ws[128][40];
    const int tid  = threadIdx.x;
    const int m0   = blockIdx.x * 64;
    const int ks   = blockIdx.y;
    const int k0   = ks * (DI / KSPLIT);
    const int wave = tid >> 6;
    const int lane = tid & 63;
    const int lrow = lane & 15;
    const int quad = lane >> 4;
    const int wm   = wave * 16;

    floatx4 acc[5];
    for (int ni = 0; ni < 5; ni++) acc[ni] = (floatx4){0.f, 0.f, 0.f, 0.f};

    const int ra  = tid >> 2;
    const int rw1 = ra + 64;
    const int seg = (tid & 3) * 8;

    for (int kb = 0; kb < DI / KSPLIT; kb += 32) {
        int gk = k0 + kb + seg;
        bf16x8 va = *(const bf16x8*)(A + (size_t)(m0 + ra) * DI + gk);
        bf16x8 vw0, vw1;
        if (ra < NXP) vw0 = *(const bf16x8*)(W + (size_t)ra * DI + gk);
        else          for (int j = 0; j < 8; j++) vw0[j] = (bf16)0.f;
        if (rw1 < NXP) vw1 = *(const bf16x8*)(W + (size_t)rw1 * DI + gk);
        else           for (int j = 0; j < 8; j++) vw1[j] = (bf16)0.f;
        __syncthreads();
        *(bf16x8*)&As[ra][seg]  = va;
        *(bf16x8*)&Ws[ra][seg]  = vw0;
        *(bf16x8*)&Ws[rw1][seg] = vw1;
        __syncthreads();
        bf16x8 af = *(const bf16x8*)&As[wm + lrow][quad * 8];
        for (int ni = 0; ni < 5; ni++) {
            bf16x8 wf = *(const bf16x8*)&Ws[ni * 16 + lrow][quad * 8];
            acc[ni] = __builtin_amdgcn_mfma_f32_16x16x32_bf16(af, wf, acc[ni], 0, 0, 0);
        }
    }
    float* pout = part + (size_t)ks * MROWS * NXP;
    for (int ni = 0; ni < 5; ni++) {
        int col = ni * 16 + lrow;
        for (int r = 0; r < 4; r++) {
            int row = m0 + wm + quad * 4 + r;
            pout[(size_t)row * NXP + col] = acc[ni][r];
        }
    }
}

// reduce split-K partials -> xdbl f32 + padded bf16 dt
__global__ __launch_bounds__(256) void xp_reduce_k(const float* __restrict__ part,
                                                   float* __restrict__ xdbl,
                                                   bf16* __restrict__ dtbf) {
    int idx = blockIdx.x * 256 + threadIdx.x;
    if (idx >= MROWS * NXP) return;
    float s = 0.f;
    for (int j = 0; j < KSPLIT; j++) s += part[(size_t)j * MROWS * NXP + idx];
    xdbl[idx] = s;
    int m = idx / NXP, c = idx - m * NXP;
    if (c < DTRANK)      dtbf[m * DTPAD + c] = (bf16)s;
    else if (c < DTPAD)  dtbf[m * DTPAD + c] = (bf16)0.f;
}

// ---------------------------------------------------------------- causal depthwise conv + silu + gate (4-wide, bf16 outputs only)
__global__ __launch_bounds__(256) void conv_silu_k(const bf16* __restrict__ xz,
                                                   const float* __restrict__ cw,
                                                   const float* __restrict__ cb,
                                                   bf16* __restrict__ xcb,
                                                   bf16* __restrict__ gzb) {
    int t = blockIdx.x * 256 + threadIdx.x;
    if (t >= MROWS * (DI / 4)) return;
    int m = t / (DI / 4);
    int d = (t - m * (DI / 4)) * 4;
    int l = m & (LL - 1);
    float acc[4];
    floatx4 cwv[4];
    for (int q = 0; q < 4; q++) {
        acc[q] = cb[d + q];
        cwv[q] = *(const floatx4*)&cw[(d + q) * 4];
    }
    for (int k = 0; k < 4; k++) {
        int lp = l - 3 + k;
        if (lp >= 0) {
            bf16x4 v = *(const bf16x4*)&xz[(size_t)(m - 3 + k) * (2 * DI) + d];
            for (int q = 0; q < 4; q++) acc[q] += (float)v[q] * cwv[q][k];
        }
    }
    bf16x4 xo, go;
    bf16x4 z4 = *(const bf16x4*)&xz[(size_t)m * (2 * DI) + DI + d];
    for (int q = 0; q < 4; q++) {
        float s = acc[q] / (1.f + __expf(-acc[q]));
        xo[q] = (bf16)s;
        float zv = (float)z4[q];
        go[q] = (bf16)(zv / (1.f + __expf(-zv)));
    }
    *(bf16x4*)&xcb[(size_t)m * DI + d] = xo;
    *(bf16x4*)&gzb[(size_t)m * DI + d] = go;
}

// ---------------------------------------------------------------- chunk-parallel selective scan
// Phase 1: local scan from 0 -> (P, S). LDS: (delta f32 | xc bf16) packed uint2.
__global__ __launch_bounds__(256) void scan1_k(const float* __restrict__ delta,
                                               const bf16* __restrict__ xcb,
                                               const float* __restrict__ xdbl,
                                               const float* __restrict__ A_log,
                                               float* __restrict__ Pbuf,
                                               float* __restrict__ Sbuf) {
    int b  = blockIdx.y;
    int d0 = blockIdx.x * 16;
    int c  = blockIdx.z;
    int tid = threadIdx.x;
    int dl = tid >> 4;
    int n  = tid & 15;
    int d  = d0 + dl;
    float a = -__expf(A_log[d * DSTATE + n]);
    __shared__ uint2 sdx[CLEN][16];   // (.x = delta f32 bits, .y = xc bf16 in low16)
    __shared__ float sb[CLEN][16];
    const unsigned short* xcu = (const unsigned short*)xcb;
    int l0 = c * CLEN;
    for (int idx = tid; idx < CLEN * 16; idx += 256) {
        int i = idx >> 4, dd = idx & 15;
        size_t row = (size_t)(b * LL + l0 + i);
        uint2 v;
        v.x = __float_as_int(delta[row * DI + d0 + dd]);
        v.y = xcu[row * DI + d0 + dd];
        sdx[i][dd] = v;
        sb[i][dd]  = xdbl[row * NXP + DTRANK + dd];
    }
    __syncthreads();
    float h = 0.f, sd = 0.f;
    for (int i = 0; i < CLEN; i++) {
        uint2 v = sdx[i][dl];
        float dv = __int_as_float(v.x);
        float xv = bfbits_lo(v.y);
        float Bv = sb[i][n];
        h = __expf(dv * a) * h + dv * Bv * xv;
        sd += dv;
    }
    size_t o = (((size_t)c * BB + b) * DI + d) * DSTATE + n;
    Pbuf[o] = __expf(a * sd);
    Sbuf[o] = h;
}

// Phase 2: compose h_in, re-run local scan, emit y.
// LDS: (delta f32 | xc bf16 | gz bf16) packed uint2 (b64), (B,C) float2 (b64).
__global__ __launch_bounds__(256) void scan2_k(const float* __restrict__ delta,
                                               const bf16* __restrict__ xcb,
                                               const bf16* __restrict__ gzb,
                                               const float* __restrict__ xdbl,
                                               const float* __restrict__ A_log,
                                               const float* __restrict__ Dskip,
                                               const float* __restrict__ Pbuf,
                                               const float* __restrict__ Sbuf,
                                               bf16* __restrict__ ybf) {
    int b  = blockIdx.y;
    int d0 = blockIdx.x * 16;
    int c  = blockIdx.z;
    int tid = threadIdx.x;
    int dl = tid >> 4;
    int n  = tid & 15;
    int d  = d0 + dl;
    float a     = -__expf(A_log[d * DSTATE + n]);
    float dskip = Dskip[d];
    float h = 0.f;
    {
        size_t stride = (size_t)BB * DI * DSTATE;
        size_t base   = ((size_t)b * DI + d) * DSTATE + n;
        for (int j = 0; j < c; j++)
            h = Pbuf[(size_t)j * stride + base] * h + Sbuf[(size_t)j * stride + base];
    }
    __shared__ uint2  sdxz[CLEN][16];  // (.x = delta bits, .y = xc | gz<<16)
    __shared__ float2 sbc2[CLEN][16];  // (B_n, C_n)
    const unsigned short* xcu = (const unsigned short*)xcb;
    const unsigned short* gzu = (const unsigned short*)gzb;
    int l0 = c * CLEN;
    for (int idx = tid; idx < CLEN * 16; idx += 256) {
        int i = idx >> 4, dd = idx & 15;
        size_t row = (size_t)(b * LL + l0 + i);
        uint2 v;
        v.x = __float_as_int(delta[row * DI + d0 + dd]);
        v.y = (unsigned)xcu[row * DI + d0 + dd] | ((unsigned)gzu[row * DI + d0 + dd] << 16);
        sdxz[i][dd] = v;
        sbc2[i][dd] = make_float2(xdbl[row * NXP + DTRANK + dd],
                                  xdbl[row * NXP + DTRANK + DSTATE + dd]);
    }
    __syncthreads();
    for (int i = 0; i < CLEN; i++) {
        uint2 v = sdxz[i][dl];
        float2 bc = sbc2[i][n];
        float dv = __int_as_float(v.x);
        float xv = bfbits_lo(v.y);
        h = __expf(dv * a) * h + dv * bc.x * xv;
        float yp = row16_sum(h * bc.y);
        if (n == 0) {
            float yv = (yp + xv * dskip) * bfbits_hi(v.y);
            ybf[(size_t)(b * LL + l0 + i) * DI + d] = (bf16)yv;
        }
    }
}

// ---------------------------------------------------------------- head
__global__ __launch_bounds__(256) void head_norm_k(const float* __restrict__ x,
                                                   const float* __restrict__ fnw,
                                                   float* __restrict__ xn_buf) {
    int b = blockIdx.x;
    int tid = threadIdx.x;
    const float* xr = x + ((size_t)b * LL + (LL - 1)) * DD;
    __shared__ float sred[4];
    float v[3]; float ss = 0.f;
    for (int j = 0; j < 3; j++) { v[j] = xr[tid + j * 256]; ss += v[j] * v[j]; }
    for (int o = 1; o < 64; o <<= 1) ss += __shfl_xor(ss, o, 64);
    if ((tid & 63) == 0) sred[tid >> 6] = ss;
    __syncthreads();
    float scale = rsqrtf((sred[0] + sred[1] + sred[2] + sred[3]) / (float)DD + 1e-6f);
    for (int j = 0; j < 3; j++) {
        int c = tid + j * 256;
        xn_buf[(size_t)b * DD + c] = v[j] * scale * fnw[c];
    }
}

__global__ __launch_bounds__(256) void head_h1_k(const float* __restrict__ xn_buf,
                                                 const float* __restrict__ h1w,
                                                 const float* __restrict__ h1b,
                                                 float* __restrict__ h_buf) {
    int b  = blockIdx.x;
    int o0 = blockIdx.y * 64;
    int tid = threadIdx.x;
    __shared__ float sx[DD];
    for (int c = tid; c < DD; c += 256) sx[c] = xn_buf[(size_t)b * DD + c];
    __syncthreads();
    int wave = tid >> 6, lane = tid & 63;
    for (int j = 0; j < 16; j++) {
        int o = o0 + wave * 16 + j;
        const float* wrow = h1w + (size_t)o * DD;
        float acc = 0.f;
        for (int k = 0; k < 12; k++) {
            int c = lane + 64 * k;
            acc += wrow[c] * sx[c];
        }
        for (int off = 1; off < 64; off <<= 1) acc += __shfl_xor(acc, off, 64);
        if (lane == 0) h_buf[(size_t)b * DD + o] = acc + h1b[o];
    }
}

__global__ __launch_bounds__(256) void head_out_k(const float* __restrict__ h_buf,
                                                  const float* __restrict__ hnw,
                                                  const float* __restrict__ h2w,
                                                  const float* __restrict__ h2b,
                                                  float* __restrict__ out) {
    int b = blockIdx.x;
    int tid = threadIdx.x;
    __shared__ float hh[DD];
    __shared__ float sred[4];
    const float* hr = h_buf + (size_t)b * DD;
    float ss = 0.f;
    for (int c = tid; c < DD; c += 256) { float v = hr[c]; ss += v * v; }
    for (int o = 1; o < 64; o <<= 1) ss += __shfl_xor(ss, o, 64);
    if ((tid & 63) == 0) sred[tid >> 6] = ss;
    __syncthreads();
    float sc = rsqrtf((sred[0] + sred[1] + sred[2] + sred[3]) / (float)DD + 1e-6f);
    for (int c = tid; c < DD; c += 256) {
        float v = hr[c] * sc * hnw[c];
        hh[c] = 0.5f * v * (1.f + erff(v * 0.70710678118f));
    }
    __syncthreads();
    int w = tid >> 6, lane = tid & 63;
    for (int j = w; j < 10; j += 4) {
        float acc = 0.f;
        const float* wrow = h2w + (size_t)j * DD;
        for (int c = lane; c < DD; c += 64) acc += hh[c] * wrow[c];
        for (int o = 1; o < 64; o <<= 1) acc += __shfl_xor(acc, o, 64);
        if (lane == 0) out[b * 10 + j] = acc + h2b[j];
    }
}

// ----------------------------------------------------------------
extern "C" void kernel_launch(void* const* d_in, const int* in_sizes, int n_in,
                              void* d_out, int out_size, void* d_ws, size_t ws_size,
                              hipStream_t stream) {
    const float* x_in      = (const float*)d_in[0];
    const float* norm_w    = (const float*)d_in[1];
    const float* in_proj_w = (const float*)d_in[2];
    const float* conv_w    = (const float*)d_in[3];
    const float* conv_b    = (const float*)d_in[4];
    const float* x_proj_w  = (const float*)d_in[5];
    const float* dt_proj_w = (const float*)d_in[6];
    const float* dt_proj_b = (const float*)d_in[7];
    const float* A_log     = (const float*)d_in[8];
    const float* D_skip    = (const float*)d_in[9];
    const float* out_proj_w= (const float*)d_in[10];
    const float* fnw       = (const float*)d_in[11];
    const float* h1w       = (const float*)d_in[12];
    const float* h1b       = (const float*)d_in[13];
    const float* hnw       = (const float*)d_in[14];
    const float* h2w       = (const float*)d_in[15];
    const float* h2b       = (const float*)d_in[16];
    float* out = (float*)d_out;

    char* ws = (char*)d_ws;
    size_t off = 0;
    auto alloc = [&](size_t bytes) -> void* {
        void* p = ws + off;
        off += (bytes + 255) & ~(size_t)255;
        return p;
    };
    bf16* w_in  = (bf16*)alloc((size_t)N1 * 2);
    bf16* w_xp  = (bf16*)alloc((size_t)N2 * 2);
    bf16* w_dt  = (bf16*)alloc((size_t)N3 * 2);
    bf16* w_out = (bf16*)alloc((size_t)N4 * 2);
    bf16* xn_bf = (bf16*)alloc((size_t)MROWS * DD * 2);
    bf16* xz_bf = (bf16*)alloc((size_t)MROWS * 2 * DI * 2);
    bf16* xc_bf = (bf16*)alloc((size_t)MROWS * DI * 2);
    bf16* gz_bf = (bf16*)alloc((size_t)MROWS * DI * 2);
    float* xdbl = (float*)alloc((size_t)MROWS * NXP * 4);
    bf16* dt_bf = (bf16*)alloc((size_t)MROWS * DTPAD * 2);
    float* delta= (float*)alloc((size_t)MROWS * DI * 4);
    bf16* y_bf  = (bf16*)alloc((size_t)MROWS * DI * 2);
    float* x_buf= (float*)alloc((size_t)MROWS * DD * 4);
    float* Pbuf = (float*)alloc((size_t)NC * BB * DI * DSTATE * 4);
    float* Sbuf = (float*)alloc((size_t)NC * BB * DI * DSTATE * 4);
    float* xnl  = (float*)alloc((size_t)BB * DD * 4);
    float* hbuf = (float*)alloc((size_t)BB * DD * 4);
    float* xp_part = (float*)alloc((size_t)KSPLIT * MROWS * NXP * 4);
    float* op_part = (float*)alloc((size_t)OPKS * MROWS * DD * 4);

    // all weight conversions in one launch
    {
        int ntot = N1 + N2 + N3 + N4;
        cvt_all_k<<<(ntot + 255) / 256, 256, 0, stream>>>(
            in_proj_w, x_proj_w, dt_proj_w, out_proj_w, w_in, w_xp, w_dt, w_out);
    }

    for (int i = 0; i < 4; i++) {
        const float* x_src = (i == 0) ? x_in : x_buf;
        // 1. rmsnorm (layer 0 only; later layers get xn_bf from fused op_reduce_norm)
        if (i == 0)
            rmsnorm_k<<<MROWS, 256, 0, stream>>>(x_src, norm_w, xn_bf);
        // 2. in_proj: (2048 x 3072), bf16 out
        gemm_bt<1><<<dim3(MROWS / 128, 3072 / 128), 256, 0, stream>>>(
            xn_bf, w_in + (size_t)i * 3072 * 768, nullptr, xz_bf, nullptr,
            MROWS, 2 * DI, DD);
        // 3. causal conv + silu + silu(z) gate (bf16 outputs)
        conv_silu_k<<<(MROWS * (DI / 4) + 255) / 256, 256, 0, stream>>>(
            xz_bf, conv_w + (size_t)i * DI * 4, conv_b + (size_t)i * DI, xc_bf, gz_bf);
        // 4. x_proj split-K + reduce -> xdbl f32 + padded bf16 dt
        gemm_xp<<<dim3(MROWS / 64, KSPLIT), 256, 0, stream>>>(
            xc_bf, w_xp + (size_t)i * NXP * DI, xp_part);
        xp_reduce_k<<<(MROWS * NXP + 255) / 256, 256, 0, stream>>>(xp_part, xdbl, dt_bf);
        // 5. dt_proj (K padded to 64) + bias + softplus -> delta
        gemm_bt<2><<<dim3(MROWS / 128, DI / 128), 256, 0, stream>>>(
            dt_bf, w_dt + (size_t)i * DI * DTPAD, delta, nullptr,
            dt_proj_b + (size_t)i * DI, MROWS, DI, DTPAD);
        // 6a. chunk-local scans -> (P, S)
        scan1_k<<<dim3(DI / 16, BB, NC), 256, 0, stream>>>(
            delta, xc_bf, xdbl, A_log + (size_t)i * DI * DSTATE, Pbuf, Sbuf);
        // 6b. compose + local scan + D-skip + gate -> y bf16
        scan2_k<<<dim3(DI / 16, BB, NC), 256, 0, stream>>>(
            delta, xc_bf, gz_bf, xdbl, A_log + (size_t)i * DI * DSTATE,
            D_skip + (size_t)i * DI, Pbuf, Sbuf, y_bf);
        // 7. out_proj split-K -> partials; fused reduce + residual + next rmsnorm
        gemm_bt<5><<<dim3(MROWS / 128, DD / 128, OPKS), 256, 0, stream>>>(
            y_bf, w_out + (size_t)i * DD * DI, op_part, nullptr, nullptr,
            MROWS, DD, DI);
        op_reduce_norm_k<<<MROWS, 256, 0, stream>>>(
            op_part, x_src, norm_w + ((i + 1) & 3) * DD, x_buf, xn_bf);
    }

    head_norm_k<<<BB, 256, 0, stream>>>(x_buf, fnw, xnl);
    head_h1_k<<<dim3(BB, DD / 64), 256, 0, stream>>>(xnl, h1w, h1b, hbuf);
    head_out_k<<<BB, 256, 0, stream>>>(hbuf, hnw, h2w, h2b, out);
}

// Round 13
// 742.479 us; speedup vs baseline: 2.7622x; 1.0074x over previous
//
#include <hip/hip_runtime.h>
#include <hip/hip_bf16.h>
#include <math.h>

typedef __bf16 bf16;
typedef __bf16 bf16x4 __attribute__((ext_vector_type(4)));
typedef __bf16 bf16x8 __attribute__((ext_vector_type(8)));
typedef float floatx4 __attribute__((ext_vector_type(4)));

#define BB 2
#define LL 1024
#define DD 768
#define DI 1536
#define MROWS 2048   // B*L
#define NXP 80       // dt_rank + 2*d_state
#define DTRANK 48
#define DTPAD 64     // dt K padded to 64
#define DSTATE 16
#define NC 16        // scan chunks
#define CLEN 64      // scan chunk length (NC*CLEN == LL)
#define KSPLIT 16    // x_proj split-K factor (K-seg = 96)
#define OPKS 4       // out_proj split-K factor (K-seg = 384)
#define LOG2E 1.4426950408889634f

// async global->LDS, 16 B per lane; lds dest must be wave-uniform base (+lane*16)
__device__ __forceinline__ void ld16(void* lds, const void* g) {
    __builtin_amdgcn_global_load_lds(
        (const __attribute__((address_space(1))) void*)g,
        (__attribute__((address_space(3))) void*)lds, 16, 0, 0);
}

// drain this wave's outstanding async global_load_lds before signalling barrier.
// REQUIRED: global_load_lds is vmcnt-tracked with no VGPR def (R9 divergence).
__device__ __forceinline__ void wait_vm0() {
    asm volatile("s_waitcnt vmcnt(0)" ::: "memory");
}

// DPP row-reduce over 16 lanes (one DPP row): lane 0 of each row gets the sum.
__device__ __forceinline__ float row16_sum(float x) {
    float t;
    t = __int_as_float(__builtin_amdgcn_update_dpp(0, __float_as_int(x), 0x111, 0xF, 0xF, true)); x += t;
    t = __int_as_float(__builtin_amdgcn_update_dpp(0, __float_as_int(x), 0x112, 0xF, 0xF, true)); x += t;
    t = __int_as_float(__builtin_amdgcn_update_dpp(0, __float_as_int(x), 0x114, 0xF, 0xF, true)); x += t;
    t = __int_as_float(__builtin_amdgcn_update_dpp(0, __float_as_int(x), 0x118, 0xF, 0xF, true)); x += t;
    return x;
}

__device__ __forceinline__ float bfbits_lo(unsigned u) { return __int_as_float((u & 0xffffu) << 16); }
__device__ __forceinline__ float bfbits_hi(unsigned u) { return __int_as_float(u & 0xffff0000u); }

// ---------------------------------------------------------------- all weight cvt in one kernel
#define N1 (4 * 3072 * 768)
#define N2 (4 * NXP * DI)
#define N3 (4 * DI * DTPAD)
#define N4 (4 * DD * DI)
__global__ __launch_bounds__(256) void cvt_all_k(const float* __restrict__ in_proj_w,
                                                 const float* __restrict__ x_proj_w,
                                                 const float* __restrict__ dt_proj_w,
                                                 const float* __restrict__ out_proj_w,
                                                 bf16* __restrict__ w_in,
                                                 bf16* __restrict__ w_xp,
                                                 bf16* __restrict__ w_dt,
                                                 bf16* __restrict__ w_out) {
    int i = blockIdx.x * 256 + threadIdx.x;
    if (i < N1) { w_in[i] = (bf16)in_proj_w[i]; return; }
    i -= N1;
    if (i < N2) { w_xp[i] = (bf16)x_proj_w[i]; return; }
    i -= N2;
    if (i < N3) {
        int row = i >> 6, c = i & 63;
        w_dt[i] = (c < DTRANK) ? (bf16)dt_proj_w[row * DTRANK + c] : (bf16)0.f;
        return;
    }
    i -= N3;
    if (i < N4) w_out[i] = (bf16)out_proj_w[i];
}

// ---------------------------------------------------------------- rmsnorm -> bf16 (layer 0 only)
__global__ __launch_bounds__(256) void rmsnorm_k(const float* __restrict__ x,
                                                 const float* __restrict__ w,
                                                 bf16* __restrict__ out) {
    int row = blockIdx.x;
    const float* xr = x + (size_t)row * DD;
    int tid = threadIdx.x;
    float v[3]; float ss = 0.f;
    for (int j = 0; j < 3; j++) { v[j] = xr[tid + j * 256]; ss += v[j] * v[j]; }
    for (int o = 1; o < 64; o <<= 1) ss += __shfl_xor(ss, o, 64);
    __shared__ float sred[4];
    if ((tid & 63) == 0) sred[tid >> 6] = ss;
    __syncthreads();
    float scale = rsqrtf((sred[0] + sred[1] + sred[2] + sred[3]) / (float)DD + 1e-6f);
    for (int j = 0; j < 3; j++) {
        int c = tid + j * 256;
        out[(size_t)row * DD + c] = (bf16)(v[j] * scale * w[c]);
    }
}

// ---------------------------------------------------------------- GEMM: C = A @ W^T
// Staging via global_load_lds 16B (m97 pattern + explicit vmcnt drain).
// MODE 1: store bf16 | MODE 5: split-K partials f32
template <int MODE>
__global__ __launch_bounds__(256) void gemm_bt(const bf16* __restrict__ A,
                                               const bf16* __restrict__ W,
                                               float* __restrict__ Cf,
                                               bf16* __restrict__ Cb,
                                               int M, int N, int K) {
    __shared__ bf16 As[128][32];
    __shared__ bf16 Ws[128][32];
    const int tid  = threadIdx.x;
    const int m0   = blockIdx.x * 128;
    const int n0   = blockIdx.y * 128;
    const int wave = tid >> 6;
    const int lane = tid & 63;
    const int wm   = (wave >> 1) * 64;
    const int wn   = (wave & 1) * 64;
    const int lrow = lane & 15;
    const int quad = lane >> 4;

    int kbeg = 0, kend = K;
    if constexpr (MODE == 5) {
        int kseg = K / gridDim.z;
        kbeg = blockIdx.z * kseg;
        kend = kbeg + kseg;
        Cf  += (size_t)blockIdx.z * M * N;
    }

    floatx4 acc[4][4];
    for (int mi = 0; mi < 4; mi++)
        for (int ni = 0; ni < 4; ni++) acc[mi][ni] = (floatx4){0.f, 0.f, 0.f, 0.f};

    const int r0  = tid >> 2;        // 0..63
    const int r1  = r0 + 64;         // 64..127
    const int seg = (tid & 3) * 8;   // 0,8,16,24
    char* asb0 = (char*)As + wave * 1024;
    char* asb1 = (char*)As + 4096 + wave * 1024;
    char* wsb0 = (char*)Ws + wave * 1024;
    char* wsb1 = (char*)Ws + 4096 + wave * 1024;

    for (int kb = kbeg; kb < kend; kb += 32) {
        int gk = kb + seg;
        __syncthreads();   // previous iteration's LDS reads done
        ld16(asb0, A + (size_t)(m0 + r0) * K + gk);
        ld16(asb1, A + (size_t)(m0 + r1) * K + gk);
        ld16(wsb0, W + (size_t)(n0 + r0) * K + gk);
        ld16(wsb1, W + (size_t)(n0 + r1) * K + gk);
        wait_vm0();        // this wave's async LDS fills landed
        __syncthreads();   // all waves' fills landed -> tiles ready
        bf16x8 af[4], wf[4];
        for (int mi = 0; mi < 4; mi++) af[mi] = *(const bf16x8*)&As[wm + mi * 16 + lrow][quad * 8];
        for (int ni = 0; ni < 4; ni++) wf[ni] = *(const bf16x8*)&Ws[wn + ni * 16 + lrow][quad * 8];
        for (int mi = 0; mi < 4; mi++)
            for (int ni = 0; ni < 4; ni++)
                acc[mi][ni] = __builtin_amdgcn_mfma_f32_16x16x32_bf16(af[mi], wf[ni], acc[mi][ni], 0, 0, 0);
    }
    for (int mi = 0; mi < 4; mi++) {
        int rowb = m0 + wm + mi * 16 + quad * 4;
        for (int ni = 0; ni < 4; ni++) {
            int col = n0 + wn + ni * 16 + lrow;
            for (int r = 0; r < 4; r++) {
                int row = rowb + r;
                float v = acc[mi][ni][r];
                if constexpr (MODE == 1) Cb[(size_t)row * N + col] = (bf16)v;
                else                     Cf[(size_t)row * N + col] = v;
            }
        }
    }
}

// ---------------------------------------------------------------- out_proj partials + residual + NEXT layer rmsnorm (fused)
__global__ __launch_bounds__(256) void op_reduce_norm_k(const float* __restrict__ part,
                                                        const float* __restrict__ resid,
                                                        const float* __restrict__ nw,
                                                        float* __restrict__ xout,
                                                        bf16* __restrict__ xnb) {
    int row = blockIdx.x;
    int tid = threadIdx.x;
    float v[3]; float ss = 0.f;
    for (int j = 0; j < 3; j++) {
        int c = tid + j * 256;
        size_t idx = (size_t)row * DD + c;
        float s = resid[idx];
        for (int ks = 0; ks < OPKS; ks++) s += part[(size_t)ks * MROWS * DD + idx];
        v[j] = s;
        xout[idx] = s;
        ss += s * s;
    }
    for (int o = 1; o < 64; o <<= 1) ss += __shfl_xor(ss, o, 64);
    __shared__ float sred[4];
    if ((tid & 63) == 0) sred[tid >> 6] = ss;
    __syncthreads();
    float scale = rsqrtf((sred[0] + sred[1] + sred[2] + sred[3]) / (float)DD + 1e-6f);
    for (int j = 0; j < 3; j++) {
        int c = tid + j * 256;
        xnb[(size_t)row * DD + c] = (bf16)(v[j] * scale * nw[c]);
    }
}

// ---------------------------------------------------------------- x_proj split-K GEMM
__global__ __launch_bounds__(256) void gemm_xp(const bf16* __restrict__ A,
                                               const bf16* __restrict__ W,
                                               float* __restrict__ part) {
    __shared__ bf16 As[64][40];
    __shared__ bf16 Ws[128][40];
    const int tid  = threadIdx.x;
    const int m0   = blockIdx.x * 64;
    const int ks   = blockIdx.y;
    const int k0   = ks * (DI / KSPLIT);
    const int wave = tid >> 6;
    const int lane = tid & 63;
    const int lrow = lane & 15;
    const int quad = lane >> 4;
    const int wm   = wave * 16;

    floatx4 acc[5];
    for (int ni = 0; ni < 5; ni++) acc[ni] = (floatx4){0.f, 0.f, 0.f, 0.f};

    const int ra  = tid >> 2;
    const int rw1 = ra + 64;
    const int seg = (tid & 3) * 8;

    for (int kb = 0; kb < DI / KSPLIT; kb += 32) {
        int gk = k0 + kb + seg;
        bf16x8 va = *(const bf16x8*)(A + (size_t)(m0 + ra) * DI + gk);
        bf16x8 vw0, vw1;
        if (ra < NXP) vw0 = *(const bf16x8*)(W + (size_t)ra * DI + gk);
        else          for (int j = 0; j < 8; j++) vw0[j] = (bf16)0.f;
        if (rw1 < NXP) vw1 = *(const bf16x8*)(W + (size_t)rw1 * DI + gk);
        else           for (int j = 0; j < 8; j++) vw1[j] = (bf16)0.f;
        __syncthreads();
        *(bf16x8*)&As[ra][seg]  = va;
        *(bf16x8*)&Ws[ra][seg]  = vw0;
        *(bf16x8*)&Ws[rw1][seg] = vw1;
        __syncthreads();
        bf16x8 af = *(const bf16x8*)&As[wm + lrow][quad * 8];
        for (int ni = 0; ni < 5; ni++) {
            bf16x8 wf = *(const bf16x8*)&Ws[ni * 16 + lrow][quad * 8];
            acc[ni] = __builtin_amdgcn_mfma_f32_16x16x32_bf16(af, wf, acc[ni], 0, 0, 0);
        }
    }
    float* pout = part + (size_t)ks * MROWS * NXP;
    for (int ni = 0; ni < 5; ni++) {
        int col = ni * 16 + lrow;
        for (int r = 0; r < 4; r++) {
            int row = m0 + wm + quad * 4 + r;
            pout[(size_t)row * NXP + col] = acc[ni][r];
        }
    }
}

// reduce split-K partials -> xdbl f32 + padded bf16 dt
__global__ __launch_bounds__(256) void xp_reduce_k(const float* __restrict__ part,
                                                   float* __restrict__ xdbl,
                                                   bf16* __restrict__ dtbf) {
    int idx = blockIdx.x * 256 + threadIdx.x;
    if (idx >= MROWS * NXP) return;
    float s = 0.f;
    for (int j = 0; j < KSPLIT; j++) s += part[(size_t)j * MROWS * NXP + idx];
    xdbl[idx] = s;
    int m = idx / NXP, c = idx - m * NXP;
    if (c < DTRANK)      dtbf[m * DTPAD + c] = (bf16)s;
    else if (c < DTPAD)  dtbf[m * DTPAD + c] = (bf16)0.f;
}

// ---------------------------------------------------------------- causal depthwise conv + silu + gate (4-wide, bf16 outputs)
__global__ __launch_bounds__(256) void conv_silu_k(const bf16* __restrict__ xz,
                                                   const float* __restrict__ cw,
                                                   const float* __restrict__ cb,
                                                   bf16* __restrict__ xcb,
                                                   bf16* __restrict__ gzb) {
    int t = blockIdx.x * 256 + threadIdx.x;
    if (t >= MROWS * (DI / 4)) return;
    int m = t / (DI / 4);
    int d = (t - m * (DI / 4)) * 4;
    int l = m & (LL - 1);
    float acc[4];
    floatx4 cwv[4];
    for (int q = 0; q < 4; q++) {
        acc[q] = cb[d + q];
        cwv[q] = *(const floatx4*)&cw[(d + q) * 4];
    }
    for (int k = 0; k < 4; k++) {
        int lp = l - 3 + k;
        if (lp >= 0) {
            bf16x4 v = *(const bf16x4*)&xz[(size_t)(m - 3 + k) * (2 * DI) + d];
            for (int q = 0; q < 4; q++) acc[q] += (float)v[q] * cwv[q][k];
        }
    }
    bf16x4 xo, go;
    bf16x4 z4 = *(const bf16x4*)&xz[(size_t)m * (2 * DI) + DI + d];
    for (int q = 0; q < 4; q++) {
        float s = acc[q] / (1.f + __expf(-acc[q]));
        xo[q] = (bf16)s;
        float zv = (float)z4[q];
        go[q] = (bf16)(zv / (1.f + __expf(-zv)));
    }
    *(bf16x4*)&xcb[(size_t)m * DI + d] = xo;
    *(bf16x4*)&gzb[(size_t)m * DI + d] = go;
}

// ---------------------------------------------------------------- chunk-parallel selective scan, dt_proj fused
// Each block computes its own delta[64 l][16 d] tile via MFMA:
//   delta = softplus(dt_tile(64x64) @ w_dt_tile(16x64)^T + bias)
// then runs the scan with delta in LDS (no global delta buffer at all).
// Phase 1: local scan from 0 -> (P, S).
__global__ __launch_bounds__(256) void scan1_k(const bf16* __restrict__ dtb,
                                               const bf16* __restrict__ wdt,
                                               const float* __restrict__ dtbias,
                                               const bf16* __restrict__ xcb,
                                               const float* __restrict__ xdbl,
                                               const float* __restrict__ A_log,
                                               float* __restrict__ Pbuf,
                                               float* __restrict__ Sbuf) {
    int b  = blockIdx.y;
    int d0 = blockIdx.x * 16;
    int c  = blockIdx.z;
    int tid = threadIdx.x;
    int dl = tid >> 4;
    int n  = tid & 15;
    int d  = d0 + dl;
    float a2 = -__expf(A_log[d * DSTATE + n]) * LOG2E;   // exp(a*x) == exp2(a2*x)
    __shared__ bf16 Adt[64][72];       // dt rows (pad 8 -> 2-way-free frag reads)
    __shared__ bf16 Bdt[16][72];       // w_dt rows
    __shared__ float sdelta[64][17];   // pad 17: conflict-free C-layout writes
    __shared__ float sxc[CLEN][16];
    __shared__ float sb[CLEN][16];
    int l0 = c * CLEN;
    {   // stage dt tile: 64 rows x 64 cols
        int r = tid >> 2, s = (tid & 3) * 16;
        size_t row = (size_t)(b * LL + l0 + r);
        *(bf16x8*)&Adt[r][s]     = *(const bf16x8*)&dtb[row * DTPAD + s];
        *(bf16x8*)&Adt[r][s + 8] = *(const bf16x8*)&dtb[row * DTPAD + s + 8];
    }
    if (tid < 128) {   // stage w_dt tile: 16 rows x 64 cols
        int r = tid >> 3, s = (tid & 7) * 8;
        *(bf16x8*)&Bdt[r][s] = *(const bf16x8*)&wdt[(size_t)(d0 + r) * DTPAD + s];
    }
    const unsigned short* xcu = (const unsigned short*)xcb;
    for (int idx = tid; idx < CLEN * 16; idx += 256) {
        int i = idx >> 4, dd = idx & 15;
        size_t row = (size_t)(b * LL + l0 + i);
        sxc[i][dd] = __int_as_float((unsigned)xcu[row * DI + d0 + dd] << 16);
        sb[i][dd]  = xdbl[row * NXP + DTRANK + dd];
    }
    __syncthreads();
    {   // MFMA delta tile + bias + softplus -> sdelta
        int wv = tid >> 6, lane = tid & 63, lr = lane & 15, q = lane >> 4;
        floatx4 dacc = (floatx4){0.f, 0.f, 0.f, 0.f};
        dacc = __builtin_amdgcn_mfma_f32_16x16x32_bf16(
            *(const bf16x8*)&Adt[16 * wv + lr][q * 8],
            *(const bf16x8*)&Bdt[lr][q * 8], dacc, 0, 0, 0);
        dacc = __builtin_amdgcn_mfma_f32_16x16x32_bf16(
            *(const bf16x8*)&Adt[16 * wv + lr][32 + q * 8],
            *(const bf16x8*)&Bdt[lr][32 + q * 8], dacc, 0, 0, 0);
        float bi = dtbias[d0 + lr];
        for (int r = 0; r < 4; r++) {
            float v = dacc[r] + bi;
            v = (v > 20.f) ? v : log1pf(__expf(v));
            sdelta[16 * wv + q * 4 + r][lr] = v;
        }
    }
    __syncthreads();
    float h = 0.f, sd = 0.f;
    for (int i = 0; i < CLEN; i++) {
        float dv = sdelta[i][dl];
        float xv = sxc[i][dl];
        float Bv = sb[i][n];
        h = exp2f(dv * a2) * h + dv * Bv * xv;
        sd += dv;
    }
    size_t o = (((size_t)c * BB + b) * DI + d) * DSTATE + n;
    Pbuf[o] = exp2f(a2 * sd);
    Sbuf[o] = h;
}

// Phase 2: compose h_in, re-run local scan (delta recomputed in-block), emit y.
__global__ __launch_bounds__(256) void scan2_k(const bf16* __restrict__ dtb,
                                               const bf16* __restrict__ wdt,
                                               const float* __restrict__ dtbias,
                                               const bf16* __restrict__ xcb,
                                               const bf16* __restrict__ gzb,
                                               const float* __restrict__ xdbl,
                                               const float* __restrict__ A_log,
                                               const float* __restrict__ Dskip,
                                               const float* __restrict__ Pbuf,
                                               const float* __restrict__ Sbuf,
                                               bf16* __restrict__ ybf) {
    int b  = blockIdx.y;
    int d0 = blockIdx.x * 16;
    int c  = blockIdx.z;
    int tid = threadIdx.x;
    int dl = tid >> 4;
    int n  = tid & 15;
    int d  = d0 + dl;
    float a2    = -__expf(A_log[d * DSTATE + n]) * LOG2E;
    float dskip = Dskip[d];
    float h = 0.f;
    {
        size_t stride = (size_t)BB * DI * DSTATE;
        size_t base   = ((size_t)b * DI + d) * DSTATE + n;
        for (int j = 0; j < c; j++)
            h = Pbuf[(size_t)j * stride + base] * h + Sbuf[(size_t)j * stride + base];
    }
    __shared__ bf16 Adt[64][72];
    __shared__ bf16 Bdt[16][72];
    __shared__ float sdelta[64][17];
    __shared__ unsigned su[CLEN][16];  // xc | gz<<16 (bf16 bits)
    __shared__ float2 sbc2[CLEN][16];  // (B_n, C_n)
    int l0 = c * CLEN;
    {
        int r = tid >> 2, s = (tid & 3) * 16;
        size_t row = (size_t)(b * LL + l0 + r);
        *(bf16x8*)&Adt[r][s]     = *(const bf16x8*)&dtb[row * DTPAD + s];
        *(bf16x8*)&Adt[r][s + 8] = *(const bf16x8*)&dtb[row * DTPAD + s + 8];
    }
    if (tid < 128) {
        int r = tid >> 3, s = (tid & 7) * 8;
        *(bf16x8*)&Bdt[r][s] = *(const bf16x8*)&wdt[(size_t)(d0 + r) * DTPAD + s];
    }
    const unsigned short* xcu = (const unsigned short*)xcb;
    const unsigned short* gzu = (const unsigned short*)gzb;
    for (int idx = tid; idx < CLEN * 16; idx += 256) {
        int i = idx >> 4, dd = idx & 15;
        size_t row = (size_t)(b * LL + l0 + i);
        su[i][dd] = (unsigned)xcu[row * DI + d0 + dd] | ((unsigned)gzu[row * DI + d0 + dd] << 16);
        sbc2[i][dd] = make_float2(xdbl[row * NXP + DTRANK + dd],
                                  xdbl[row * NXP + DTRANK + DSTATE + dd]);
    }
    __syncthreads();
    {
        int wv = tid >> 6, lane = tid & 63, lr = lane & 15, q = lane >> 4;
        floatx4 dacc = (floatx4){0.f, 0.f, 0.f, 0.f};
        dacc = __builtin_amdgcn_mfma_f32_16x16x32_bf16(
            *(const bf16x8*)&Adt[16 * wv + lr][q * 8],
            *(const bf16x8*)&Bdt[lr][q * 8], dacc, 0, 0, 0);
        dacc = __builtin_amdgcn_mfma_f32_16x16x32_bf16(
            *(const bf16x8*)&Adt[16 * wv + lr][32 + q * 8],
            *(const bf16x8*)&Bdt[lr][32 + q * 8], dacc, 0, 0, 0);
        float bi = dtbias[d0 + lr];
        for (int r = 0; r < 4; r++) {
            float v = dacc[r] + bi;
            v = (v > 20.f) ? v : log1pf(__expf(v));
            sdelta[16 * wv + q * 4 + r][lr] = v;
        }
    }
    __syncthreads();
    for (int i = 0; i < CLEN; i++) {
        float dv = sdelta[i][dl];
        unsigned u = su[i][dl];
        float2 bc = sbc2[i][n];
        float xv = bfbits_lo(u);
        h = exp2f(dv * a2) * h + dv * bc.x * xv;
        float yp = row16_sum(h * bc.y);
        if (n == 0) {
            float yv = (yp + xv * dskip) * bfbits_hi(u);
            ybf[(size_t)(b * LL + l0 + i) * DI + d] = (bf16)yv;
        }
    }
}

// ---------------------------------------------------------------- head
__global__ __launch_bounds__(256) void head_norm_k(const float* __restrict__ x,
                                                   const float* __restrict__ fnw,
                                                   float* __restrict__ xn_buf) {
    int b = blockIdx.x;
    int tid = threadIdx.x;
    const float* xr = x + ((size_t)b * LL + (LL - 1)) * DD;
    __shared__ float sred[4];
    float v[3]; float ss = 0.f;
    for (int j = 0; j < 3; j++) { v[j] = xr[tid + j * 256]; ss += v[j] * v[j]; }
    for (int o = 1; o < 64; o <<= 1) ss += __shfl_xor(ss, o, 64);
    if ((tid & 63) == 0) sred[tid >> 6] = ss;
    __syncthreads();
    float scale = rsqrtf((sred[0] + sred[1] + sred[2] + sred[3]) / (float)DD + 1e-6f);
    for (int j = 0; j < 3; j++) {
        int c = tid + j * 256;
        xn_buf[(size_t)b * DD + c] = v[j] * scale * fnw[c];
    }
}

__global__ __launch_bounds__(256) void head_h1_k(const float* __restrict__ xn_buf,
                                                 const float* __restrict__ h1w,
                                                 const float* __restrict__ h1b,
                                                 float* __restrict__ h_buf) {
    int b  = blockIdx.x;
    int o0 = blockIdx.y * 64;
    int tid = threadIdx.x;
    __shared__ float sx[DD];
    for (int c = tid; c < DD; c += 256) sx[c] = xn_buf[(size_t)b * DD + c];
    __syncthreads();
    int wave = tid >> 6, lane = tid & 63;
    for (int j = 0; j < 16; j++) {
        int o = o0 + wave * 16 + j;
        const float* wrow = h1w + (size_t)o * DD;
        float acc = 0.f;
        for (int k = 0; k < 12; k++) {
            int c = lane + 64 * k;
            acc += wrow[c] * sx[c];
        }
        for (int off = 1; off < 64; off <<= 1) acc += __shfl_xor(acc, off, 64);
        if (lane == 0) h_buf[(size_t)b * DD + o] = acc + h1b[o];
    }
}

__global__ __launch_bounds__(256) void head_out_k(const float* __restrict__ h_buf,
                                                  const float* __restrict__ hnw,
                                                  const float* __restrict__ h2w,
                                                  const float* __restrict__ h2b,
                                                  float* __restrict__ out) {
    int b = blockIdx.x;
    int tid = threadIdx.x;
    __shared__ float hh[DD];
    __shared__ float sred[4];
    const float* hr = h_buf + (size_t)b * DD;
    float ss = 0.f;
    for (int c = tid; c < DD; c += 256) { float v = hr[c]; ss += v * v; }
    for (int o = 1; o < 64; o <<= 1) ss += __shfl_xor(ss, o, 64);
    if ((tid & 63) == 0) sred[tid >> 6] = ss;
    __syncthreads();
    float sc = rsqrtf((sred[0] + sred[1] + sred[2] + sred[3]) / (float)DD + 1e-6f);
    for (int c = tid; c < DD; c += 256) {
        float v = hr[c] * sc * hnw[c];
        hh[c] = 0.5f * v * (1.f + erff(v * 0.70710678118f));
    }
    __syncthreads();
    int w = tid >> 6, lane = tid & 63;
    for (int j = w; j < 10; j += 4) {
        float acc = 0.f;
        const float* wrow = h2w + (size_t)j * DD;
        for (int c = lane; c < DD; c += 64) acc += hh[c] * wrow[c];
        for (int o = 1; o < 64; o <<= 1) acc += __shfl_xor(acc, o, 64);
        if (lane == 0) out[b * 10 + j] = acc + h2b[j];
    }
}

// ----------------------------------------------------------------
extern "C" void kernel_launch(void* const* d_in, const int* in_sizes, int n_in,
                              void* d_out, int out_size, void* d_ws, size_t ws_size,
                              hipStream_t stream) {
    const float* x_in      = (const float*)d_in[0];
    const float* norm_w    = (const float*)d_in[1];
    const float* in_proj_w = (const float*)d_in[2];
    const float* conv_w    = (const float*)d_in[3];
    const float* conv_b    = (const float*)d_in[4];
    const float* x_proj_w  = (const float*)d_in[5];
    const float* dt_proj_w = (const float*)d_in[6];
    const float* dt_proj_b = (const float*)d_in[7];
    const float* A_log     = (const float*)d_in[8];
    const float* D_skip    = (const float*)d_in[9];
    const float* out_proj_w= (const float*)d_in[10];
    const float* fnw       = (const float*)d_in[11];
    const float* h1w       = (const float*)d_in[12];
    const float* h1b       = (const float*)d_in[13];
    const float* hnw       = (const float*)d_in[14];
    const float* h2w       = (const float*)d_in[15];
    const float* h2b       = (const float*)d_in[16];
    float* out = (float*)d_out;

    char* ws = (char*)d_ws;
    size_t off = 0;
    auto alloc = [&](size_t bytes) -> void* {
        void* p = ws + off;
        off += (bytes + 255) & ~(size_t)255;
        return p;
    };
    bf16* w_in  = (bf16*)alloc((size_t)N1 * 2);
    bf16* w_xp  = (bf16*)alloc((size_t)N2 * 2);
    bf16* w_dt  = (bf16*)alloc((size_t)N3 * 2);
    bf16* w_out = (bf16*)alloc((size_t)N4 * 2);
    bf16* xn_bf = (bf16*)alloc((size_t)MROWS * DD * 2);
    bf16* xz_bf = (bf16*)alloc((size_t)MROWS * 2 * DI * 2);
    bf16* xc_bf = (bf16*)alloc((size_t)MROWS * DI * 2);
    bf16* gz_bf = (bf16*)alloc((size_t)MROWS * DI * 2);
    float* xdbl = (float*)alloc((size_t)MROWS * NXP * 4);
    bf16* dt_bf = (bf16*)alloc((size_t)MROWS * DTPAD * 2);
    bf16* y_bf  = (bf16*)alloc((size_t)MROWS * DI * 2);
    float* x_buf= (float*)alloc((size_t)MROWS * DD * 4);
    float* Pbuf = (float*)alloc((size_t)NC * BB * DI * DSTATE * 4);
    float* Sbuf = (float*)alloc((size_t)NC * BB * DI * DSTATE * 4);
    float* xnl  = (float*)alloc((size_t)BB * DD * 4);
    float* hbuf = (float*)alloc((size_t)BB * DD * 4);
    float* xp_part = (float*)alloc((size_t)KSPLIT * MROWS * NXP * 4);
    float* op_part = (float*)alloc((size_t)OPKS * MROWS * DD * 4);

    // all weight conversions in one launch
    {
        int ntot = N1 + N2 + N3 + N4;
        cvt_all_k<<<(ntot + 255) / 256, 256, 0, stream>>>(
            in_proj_w, x_proj_w, dt_proj_w, out_proj_w, w_in, w_xp, w_dt, w_out);
    }

    for (int i = 0; i < 4; i++) {
        const float* x_src = (i == 0) ? x_in : x_buf;
        // 1. rmsnorm (layer 0 only; later layers get xn_bf from fused op_reduce_norm)
        if (i == 0)
            rmsnorm_k<<<MROWS, 256, 0, stream>>>(x_src, norm_w, xn_bf);
        // 2. in_proj: (2048 x 3072), bf16 out
        gemm_bt<1><<<dim3(MROWS / 128, 3072 / 128), 256, 0, stream>>>(
            xn_bf, w_in + (size_t)i * 3072 * 768, nullptr, xz_bf,
            MROWS, 2 * DI, DD);
        // 3. causal conv + silu + silu(z) gate (bf16 outputs)
        conv_silu_k<<<(MROWS * (DI / 4) + 255) / 256, 256, 0, stream>>>(
            xz_bf, conv_w + (size_t)i * DI * 4, conv_b + (size_t)i * DI, xc_bf, gz_bf);
        // 4. x_proj split-K + reduce -> xdbl f32 + padded bf16 dt
        gemm_xp<<<dim3(MROWS / 64, KSPLIT), 256, 0, stream>>>(
            xc_bf, w_xp + (size_t)i * NXP * DI, xp_part);
        xp_reduce_k<<<(MROWS * NXP + 255) / 256, 256, 0, stream>>>(xp_part, xdbl, dt_bf);
        // 5a. chunk-local scans (dt_proj fused in-block) -> (P, S)
        scan1_k<<<dim3(DI / 16, BB, NC), 256, 0, stream>>>(
            dt_bf, w_dt + (size_t)i * DI * DTPAD, dt_proj_b + (size_t)i * DI,
            xc_bf, xdbl, A_log + (size_t)i * DI * DSTATE, Pbuf, Sbuf);
        // 5b. compose + local scan (dt_proj fused) + D-skip + gate -> y bf16
        scan2_k<<<dim3(DI / 16, BB, NC), 256, 0, stream>>>(
            dt_bf, w_dt + (size_t)i * DI * DTPAD, dt_proj_b + (size_t)i * DI,
            xc_bf, gz_bf, xdbl, A_log + (size_t)i * DI * DSTATE,
            D_skip + (size_t)i * DI, Pbuf, Sbuf, y_bf);
        // 6. out_proj split-K -> partials; fused reduce + residual + next rmsnorm
        gemm_bt<5><<<dim3(MROWS / 128, DD / 128, OPKS), 256, 0, stream>>>(
            y_bf, w_out + (size_t)i * DD * DI, op_part, nullptr,
            MROWS, DD, DI);
        op_reduce_norm_k<<<MROWS, 256, 0, stream>>>(
            op_part, x_src, norm_w + ((i + 1) & 3) * DD, x_buf, xn_bf);
    }

    head_norm_k<<<BB, 256, 0, stream>>>(x_buf, fnw, xnl);
    head_h1_k<<<dim3(BB, DD / 64), 256, 0, stream>>>(xnl, h1w, h1b, hbuf);
    head_out_k<<<BB, 256, 0, stream>>>(hbuf, hnw, h2w, h2b, out);
}